// Round 1
// baseline (907.551 us; speedup 1.0000x reference)
//
#include <hip/hip_runtime.h>

// ---------------------------------------------------------------------------
// KP_Decoder: hypernet -> (k,v,q) -> attention -> top2 MoE -> combine softmax
// B=32 G=512 N=512 EMB=128 H=8 DK=16 E=8 FH=512 K=2
// All fp32 (vector ALU) this round; structured for later bf16-MFMA swaps.
// ---------------------------------------------------------------------------

#define TPB 256

// ws layout (float offsets)
static constexpr long OFF_MID   = 0;        // 8
static constexpr long OFF_PREFL = 8;        // 8
static constexpr long OFF_WQ    = 64;       // 128x129 = 16512
static constexpr long OFF_WK    = 16576;    // 128x128
static constexpr long OFF_WV    = 32960;    // 128x128
static constexpr long OFF_WC    = 49344;    // 128x128
static constexpr long OFF_QB    = 65728;    // 32x128 qbase
static constexpr long OFF_CNT   = 69824;    // 8 ints
static constexpr long OFF_TOK   = 69888;    // 8*16384 ints
static constexpr long OFF_WGT   = 200960;   // 8*16384 floats
static constexpr long OFF_AO    = 332288;   // 16384x128 attention out
static constexpr long OFF_MH    = 2429440;  // 16384x128 mh
// total = 4,526,592 floats = 18.1 MB

// d_out doubles as scratch: K at +0, V at +2097152 (dead before sc GEMM);
// Y0/Y1 (rank-split MoE outputs) reuse the same two ranges after attention.

// ---------------- hypernet: mid + pref gate logits -------------------------
__global__ __launch_bounds__(256)
void k_hyper(const float* __restrict__ pref, const float* __restrict__ fc1w,
             const float* __restrict__ fc1b, const float* __restrict__ fc2w,
             const float* __restrict__ fc2b, const float* __restrict__ fc3w,
             const float* __restrict__ fc3b, const float* __restrict__ gpw,
             float* __restrict__ ws) {
  __shared__ float h1[256];
  __shared__ float h2[256];
  __shared__ float mid[8];
  const int t = threadIdx.x;
  const float p0 = pref[0], p1 = pref[1];
  h1[t] = fc1w[2*t]*p0 + fc1w[2*t+1]*p1 + fc1b[t];
  __syncthreads();
  float s = 0.f;
  for (int j = 0; j < 256; ++j) s = fmaf(fc2w[t*256+j], h1[j], s);
  h2[t] = s + fc2b[t];
  __syncthreads();
  if (t < 8) {
    float s2 = 0.f;
    for (int j = 0; j < 256; ++j) s2 = fmaf(fc3w[t*256+j], h2[j], s2);
    mid[t] = s2 + fc3b[t];
    ws[OFF_MID + t] = mid[t];
  }
  __syncthreads();
  if (t < 8) {
    float s3 = 0.f;
    for (int i = 0; i < 8; ++i) s3 = fmaf(mid[i], gpw[i*8 + t], s3);
    ws[OFF_PREFL + t] = s3;
  }
}

// ---------------- hypernet heads: Wq/Wk/Wv/Wc ------------------------------
__global__ __launch_bounds__(256)
void k_hyperw(const float* __restrict__ hWq, const float* __restrict__ hWk,
              const float* __restrict__ hWv, const float* __restrict__ hWc,
              float* __restrict__ ws) {
  const int i = blockIdx.x*256 + threadIdx.x;
  const float m0 = ws[0], m1 = ws[1], m2 = ws[2], m3 = ws[3],
              m4 = ws[4], m5 = ws[5], m6 = ws[6], m7 = ws[7];
  if (i < 16512) {
    ws[OFF_WQ + i] = hWq[2*i]*m0 + hWq[2*i+1]*m1;
  } else if (i < 32896) {
    const int j = i - 16512;
    ws[OFF_WK + j] = hWk[2*j]*m2 + hWk[2*j+1]*m3;
  } else if (i < 49280) {
    const int j = i - 32896;
    ws[OFF_WV + j] = hWv[2*j]*m4 + hWv[2*j+1]*m5;
  } else if (i < 65664) {
    const int j = i - 49280;
    ws[OFF_WC + j] = hWc[2*j]*m6 + hWc[2*j+1]*m7;
  }
}

// ---------------- qbase[b][o] = graph[b] . Wq[o,0:128] ---------------------
__global__ __launch_bounds__(128)
void k_qbase(const float* __restrict__ graph, float* __restrict__ ws) {
  __shared__ float g[128];
  const int b = blockIdx.x, t = threadIdx.x;
  g[t] = graph[b*128 + t];
  __syncthreads();
  const float* wq = ws + OFF_WQ + (long)t*129;
  float s = 0.f;
  for (int i = 0; i < 128; ++i) s = fmaf(g[i], wq[i], s);
  ws[OFF_QB + b*128 + t] = s;
}

// ---------------- generic fp32 GEMM, C = A @ B^T, K=128 --------------------
// MODE 0: kv   grid(128,2):   A=enc[16384,128], B={Wk,Wv}, C={K,V}, ldc=128
// MODE 1: mh   grid(128,1):   A=Y0+Y1,          B=Wc,      C=MH,    ldc=128
// MODE 2: sc   grid(4,4,32):  per-b A=mh[b], B=enc[b], C=out[b],    ldc=512
template <int MODE>
__global__ __launch_bounds__(256)
void k_gemm(const float* __restrict__ A, const float* __restrict__ A2,
            const float* __restrict__ B0, const float* __restrict__ B1,
            float* __restrict__ C0, float* __restrict__ C1) {
  constexpr int LDT = 132;
  __shared__ float As[32][LDT];
  __shared__ float Bs[32][LDT];
  const int tid = threadIdx.x;
  const int bx = blockIdx.x;
  const float* Ap;
  const float* Ap2 = nullptr;
  const float* Bp;
  float* Cp;
  int ldc;
  if constexpr (MODE == 0) {
    Ap = A + (long)bx*128*128;
    Bp = blockIdx.y ? B1 : B0;
    Cp = (blockIdx.y ? C1 : C0) + (long)bx*128*128;
    ldc = 128;
  } else if constexpr (MODE == 1) {
    Ap  = A  + (long)bx*128*128;
    Ap2 = A2 + (long)bx*128*128;
    Bp = B0;
    Cp = C0 + (long)bx*128*128;
    ldc = 128;
  } else {
    const long zo = (long)blockIdx.z*512*128;
    Ap = A + zo + (long)bx*128*128;
    Bp = B0 + zo + (long)blockIdx.y*128*128;
    Cp = C0 + (long)blockIdx.z*512*512 + (long)bx*128*512 + (long)blockIdx.y*128;
    ldc = 512;
  }
  float acc[8][8];
#pragma unroll
  for (int i = 0; i < 8; ++i)
#pragma unroll
    for (int j = 0; j < 8; ++j) acc[i][j] = 0.f;
  const int tm = (tid >> 4) * 8;
  const int tn = (tid & 15) * 8;
  for (int kt = 0; kt < 4; ++kt) {
    __syncthreads();
#pragma unroll
    for (int r = 0; r < 4; ++r) {
      const int id = tid + r*256;
      const int m = id >> 3, kq = id & 7;
      float4 av = *(const float4*)(Ap + (long)m*128 + kt*32 + kq*4);
      if constexpr (MODE == 1) {
        const float4 a2 = *(const float4*)(Ap2 + (long)m*128 + kt*32 + kq*4);
        av.x += a2.x; av.y += a2.y; av.z += a2.z; av.w += a2.w;
      }
      As[kq*4+0][m] = av.x; As[kq*4+1][m] = av.y;
      As[kq*4+2][m] = av.z; As[kq*4+3][m] = av.w;
      const float4 bv = *(const float4*)(Bp + (long)m*128 + kt*32 + kq*4);
      Bs[kq*4+0][m] = bv.x; Bs[kq*4+1][m] = bv.y;
      Bs[kq*4+2][m] = bv.z; Bs[kq*4+3][m] = bv.w;
    }
    __syncthreads();
#pragma unroll
    for (int kk = 0; kk < 32; ++kk) {
      float a[8], b[8];
      *(float4*)&a[0] = *(const float4*)&As[kk][tm];
      *(float4*)&a[4] = *(const float4*)&As[kk][tm+4];
      *(float4*)&b[0] = *(const float4*)&Bs[kk][tn];
      *(float4*)&b[4] = *(const float4*)&Bs[kk][tn+4];
#pragma unroll
      for (int i = 0; i < 8; ++i)
#pragma unroll
        for (int j = 0; j < 8; ++j) acc[i][j] = fmaf(a[i], b[j], acc[i][j]);
    }
  }
#pragma unroll
  for (int i = 0; i < 8; ++i) {
    const float4 c0 = {acc[i][0], acc[i][1], acc[i][2], acc[i][3]};
    const float4 c1 = {acc[i][4], acc[i][5], acc[i][6], acc[i][7]};
    *(float4*)(Cp + (long)(tm+i)*ldc + tn)     = c0;
    *(float4*)(Cp + (long)(tm+i)*ldc + tn + 4) = c1;
  }
}

// ---------------- flash attention per (b,h) --------------------------------
__device__ __forceinline__ float dot4f(const float4 a, const float4 b, float s) {
  s = fmaf(a.x, b.x, s); s = fmaf(a.y, b.y, s);
  s = fmaf(a.z, b.z, s); s = fmaf(a.w, b.w, s);
  return s;
}

__global__ __launch_bounds__(256)
void k_attn(const float* __restrict__ Kb, const float* __restrict__ Vb,
            const float* __restrict__ ws, const float* __restrict__ cap,
            const float* __restrict__ mask, float* __restrict__ AO) {
  const int bh = blockIdx.x, b = bh >> 3, h = bh & 7;
  __shared__ float4 ks[512][4];
  __shared__ float4 vs[512][4];
  const int tid = threadIdx.x;
  const float* Kp = Kb + (long)b*512*128 + h*16;
  const float* Vp = Vb + (long)b*512*128 + h*16;
  for (int i = tid; i < 2048; i += 256) {
    const int n = i >> 2, c = i & 3;
    ks[n][c] = *(const float4*)(Kp + (long)n*128 + c*4);
    vs[n][c] = *(const float4*)(Vp + (long)n*128 + c*4);
  }
  float4 qbv[4], wlv[4];
  {
    const float* qbp = ws + OFF_QB + b*128 + h*16;
    const float* wqp = ws + OFF_WQ;
#pragma unroll
    for (int c = 0; c < 4; ++c) {
      qbv[c] = *(const float4*)(qbp + c*4);
      float4 w;
      w.x = wqp[(h*16 + c*4 + 0)*129 + 128];
      w.y = wqp[(h*16 + c*4 + 1)*129 + 128];
      w.z = wqp[(h*16 + c*4 + 2)*129 + 128];
      w.w = wqp[(h*16 + c*4 + 3)*129 + 128];
      wlv[c] = w;
    }
  }
  __syncthreads();
  const int g0 = tid*2;
  const float c0 = cap[b*512 + g0], c1 = cap[b*512 + g0 + 1];
  float4 q0[4], q1[4];
#pragma unroll
  for (int c = 0; c < 4; ++c) {
    q0[c].x = fmaf(c0, wlv[c].x, qbv[c].x); q0[c].y = fmaf(c0, wlv[c].y, qbv[c].y);
    q0[c].z = fmaf(c0, wlv[c].z, qbv[c].z); q0[c].w = fmaf(c0, wlv[c].w, qbv[c].w);
    q1[c].x = fmaf(c1, wlv[c].x, qbv[c].x); q1[c].y = fmaf(c1, wlv[c].y, qbv[c].y);
    q1[c].z = fmaf(c1, wlv[c].z, qbv[c].z); q1[c].w = fmaf(c1, wlv[c].w, qbv[c].w);
  }
  float m0 = -1e30f, m1 = -1e30f, l0 = 0.f, l1 = 0.f;
  float4 a0[4], a1[4];
#pragma unroll
  for (int c = 0; c < 4; ++c) {
    a0[c] = make_float4(0.f, 0.f, 0.f, 0.f);
    a1[c] = make_float4(0.f, 0.f, 0.f, 0.f);
  }
  const float* mr = mask + (long)(b*512 + g0)*512;
  for (int nb = 0; nb < 512; nb += 4) {
    const float4 mk0 = *(const float4*)(mr + nb);
    const float4 mk1 = *(const float4*)(mr + 512 + nb);
#pragma unroll
    for (int u = 0; u < 4; ++u) {
      const int n = nb + u;
      const float4 k0 = ks[n][0], k1 = ks[n][1], k2 = ks[n][2], k3 = ks[n][3];
      float s0 = 0.f, s1 = 0.f;
      s0 = dot4f(q0[0], k0, s0); s0 = dot4f(q0[1], k1, s0);
      s0 = dot4f(q0[2], k2, s0); s0 = dot4f(q0[3], k3, s0);
      s1 = dot4f(q1[0], k0, s1); s1 = dot4f(q1[1], k1, s1);
      s1 = dot4f(q1[2], k2, s1); s1 = dot4f(q1[3], k3, s1);
      s0 = fmaf(s0, 0.25f, (&mk0.x)[u]);
      s1 = fmaf(s1, 0.25f, (&mk1.x)[u]);
      float p0;
      if (s0 > m0) {
        const float sc = __expf(m0 - s0);
        l0 *= sc;
#pragma unroll
        for (int c = 0; c < 4; ++c) {
          a0[c].x *= sc; a0[c].y *= sc; a0[c].z *= sc; a0[c].w *= sc;
        }
        m0 = s0; p0 = 1.f;
      } else p0 = __expf(s0 - m0);
      l0 += p0;
      float p1;
      if (s1 > m1) {
        const float sc = __expf(m1 - s1);
        l1 *= sc;
#pragma unroll
        for (int c = 0; c < 4; ++c) {
          a1[c].x *= sc; a1[c].y *= sc; a1[c].z *= sc; a1[c].w *= sc;
        }
        m1 = s1; p1 = 1.f;
      } else p1 = __expf(s1 - m1);
      l1 += p1;
      const float4 v0 = vs[n][0], v1 = vs[n][1], v2 = vs[n][2], v3 = vs[n][3];
      a0[0].x = fmaf(p0, v0.x, a0[0].x); a0[0].y = fmaf(p0, v0.y, a0[0].y);
      a0[0].z = fmaf(p0, v0.z, a0[0].z); a0[0].w = fmaf(p0, v0.w, a0[0].w);
      a0[1].x = fmaf(p0, v1.x, a0[1].x); a0[1].y = fmaf(p0, v1.y, a0[1].y);
      a0[1].z = fmaf(p0, v1.z, a0[1].z); a0[1].w = fmaf(p0, v1.w, a0[1].w);
      a0[2].x = fmaf(p0, v2.x, a0[2].x); a0[2].y = fmaf(p0, v2.y, a0[2].y);
      a0[2].z = fmaf(p0, v2.z, a0[2].z); a0[2].w = fmaf(p0, v2.w, a0[2].w);
      a0[3].x = fmaf(p0, v3.x, a0[3].x); a0[3].y = fmaf(p0, v3.y, a0[3].y);
      a0[3].z = fmaf(p0, v3.z, a0[3].z); a0[3].w = fmaf(p0, v3.w, a0[3].w);
      a1[0].x = fmaf(p1, v0.x, a1[0].x); a1[0].y = fmaf(p1, v0.y, a1[0].y);
      a1[0].z = fmaf(p1, v0.z, a1[0].z); a1[0].w = fmaf(p1, v0.w, a1[0].w);
      a1[1].x = fmaf(p1, v1.x, a1[1].x); a1[1].y = fmaf(p1, v1.y, a1[1].y);
      a1[1].z = fmaf(p1, v1.z, a1[1].z); a1[1].w = fmaf(p1, v1.w, a1[1].w);
      a1[2].x = fmaf(p1, v2.x, a1[2].x); a1[2].y = fmaf(p1, v2.y, a1[2].y);
      a1[2].z = fmaf(p1, v2.z, a1[2].z); a1[2].w = fmaf(p1, v2.w, a1[2].w);
      a1[3].x = fmaf(p1, v3.x, a1[3].x); a1[3].y = fmaf(p1, v3.y, a1[3].y);
      a1[3].z = fmaf(p1, v3.z, a1[3].z); a1[3].w = fmaf(p1, v3.w, a1[3].w);
    }
  }
  const float inv0 = 1.f / l0, inv1 = 1.f / l1;
  float* o0 = AO + (long)(b*512 + g0)*128 + h*16;
  float* o1 = o0 + 128;
#pragma unroll
  for (int c = 0; c < 4; ++c) {
    float4 w0 = a0[c];
    w0.x *= inv0; w0.y *= inv0; w0.z *= inv0; w0.w *= inv0;
    *(float4*)(o0 + c*4) = w0;
    float4 w1 = a1[c];
    w1.x *= inv1; w1.y *= inv1; w1.z *= inv1; w1.w *= inv1;
    *(float4*)(o1 + c*4) = w1;
  }
}

// ---------------- gating: top-2 + expert lists -----------------------------
__global__ __launch_bounds__(256)
void k_gate(const float* __restrict__ AO, const float* __restrict__ gw,
            float* __restrict__ ws) {
  const int t = blockIdx.x*256 + threadIdx.x;
  const float* x = AO + (long)t*128;
  float lg[8];
  {
    const float* pl = ws + OFF_PREFL;
#pragma unroll
    for (int e = 0; e < 8; ++e) lg[e] = pl[e];
  }
  for (int i = 0; i < 128; i += 4) {
    const float4 xv = *(const float4*)(x + i);
#pragma unroll
    for (int u = 0; u < 4; ++u) {
      const float xi = (&xv.x)[u];
      const float4 ga = *(const float4*)(gw + (i+u)*8);
      const float4 gb = *(const float4*)(gw + (i+u)*8 + 4);
      lg[0] = fmaf(xi, ga.x, lg[0]); lg[1] = fmaf(xi, ga.y, lg[1]);
      lg[2] = fmaf(xi, ga.z, lg[2]); lg[3] = fmaf(xi, ga.w, lg[3]);
      lg[4] = fmaf(xi, gb.x, lg[4]); lg[5] = fmaf(xi, gb.y, lg[5]);
      lg[6] = fmaf(xi, gb.z, lg[6]); lg[7] = fmaf(xi, gb.w, lg[7]);
    }
  }
  int i0 = 0; float v0 = lg[0];
#pragma unroll
  for (int e = 1; e < 8; ++e) if (lg[e] > v0) { v0 = lg[e]; i0 = e; }
  int i1 = -1; float v1 = -1e30f;
#pragma unroll
  for (int e = 0; e < 8; ++e) if (e != i0 && lg[e] > v1) { v1 = lg[e]; i1 = e; }
  const float e1 = __expf(v1 - v0);
  const float w0 = 1.f / (1.f + e1);
  const float w1 = 1.f - w0;
  int* cnt = (int*)(ws + OFF_CNT);
  int* tokp = (int*)(ws + OFF_TOK);
  float* wgtp = ws + OFF_WGT;
  const int s0 = atomicAdd(&cnt[i0], 1);
  tokp[i0*16384 + s0] = t;             // rank 0
  wgtp[i0*16384 + s0] = w0;
  const int s1 = atomicAdd(&cnt[i1], 1);
  tokp[i1*16384 + s1] = t | (1 << 30); // rank 1
  wgtp[i1*16384 + s1] = w1;
}

// ---------------- MoE experts: per (expert, 64-token chunk) ----------------
__global__ __launch_bounds__(256)
void k_moe(const float* __restrict__ AO, const float* __restrict__ ew1,
           const float* __restrict__ eb1, const float* __restrict__ ew2,
           const float* __restrict__ eb2, float* __restrict__ ws,
           float* __restrict__ Y0, float* __restrict__ Y1) {
  const int e = blockIdx.y;
  const int ce = ((const int*)(ws + OFF_CNT))[e];
  const int base = blockIdx.x * 64;
  if (base >= ce) return;
  const int nt = min(64, ce - base);
  __shared__ float Xs[128][68];   // [i][t]
  __shared__ float Hs[128][68];   // [f][t]
  __shared__ float Ws[32][132];   // staged weight k-tile, [k][f or o]
  __shared__ int stok[64];
  __shared__ float swgt[64];
  const int tid = threadIdx.x;
  if (tid < 64) {
    if (tid < nt) {
      stok[tid] = ((const int*)(ws + OFF_TOK))[e*16384 + base + tid];
      swgt[tid] = (ws + OFF_WGT)[e*16384 + base + tid];
    } else { stok[tid] = -1; swgt[tid] = 0.f; }
  }
  __syncthreads();
#pragma unroll
  for (int r = 0; r < 8; ++r) {
    const int id = tid + r*256;
    const int t = id >> 5, c = id & 31;
    const int pk = stok[t];
    float4 xv = make_float4(0.f, 0.f, 0.f, 0.f);
    if (pk >= 0) xv = *(const float4*)(AO + (long)(pk & 0x3FFFFFFF)*128 + c*4);
    Xs[c*4+0][t] = xv.x; Xs[c*4+1][t] = xv.y;
    Xs[c*4+2][t] = xv.z; Xs[c*4+3][t] = xv.w;
  }
  const int tm = (tid >> 4) * 4;   // token micro rows (4)
  const int tf = (tid & 15) * 8;   // f / o micro cols (8)
  float yacc[4][8];
#pragma unroll
  for (int i = 0; i < 4; ++i)
#pragma unroll
    for (int j = 0; j < 8; ++j) yacc[i][j] = 0.f;

  for (int fc = 0; fc < 4; ++fc) {
    float hacc[4][8];
#pragma unroll
    for (int i = 0; i < 4; ++i)
#pragma unroll
      for (int j = 0; j < 8; ++j) hacc[i][j] = 0.f;
    // GEMM1: H[t][f] = X[t][i] . W1[f][i], f in this 128-chunk
    for (int kt = 0; kt < 4; ++kt) {
      __syncthreads();
#pragma unroll
      for (int r = 0; r < 4; ++r) {
        const int id = tid + r*256;
        const int f = id >> 3, kq = id & 7;
        const float4 wv = *(const float4*)(ew1 + ((long)(e*512 + fc*128 + f))*128 + kt*32 + kq*4);
        Ws[kq*4+0][f] = wv.x; Ws[kq*4+1][f] = wv.y;
        Ws[kq*4+2][f] = wv.z; Ws[kq*4+3][f] = wv.w;
      }
      __syncthreads();
#pragma unroll
      for (int kk = 0; kk < 32; ++kk) {
        float xa[4], wb[8];
        *(float4*)&xa[0] = *(const float4*)&Xs[kt*32+kk][tm];
        *(float4*)&wb[0] = *(const float4*)&Ws[kk][tf];
        *(float4*)&wb[4] = *(const float4*)&Ws[kk][tf+4];
#pragma unroll
        for (int i = 0; i < 4; ++i)
#pragma unroll
          for (int j = 0; j < 8; ++j) hacc[i][j] = fmaf(xa[i], wb[j], hacc[i][j]);
      }
    }
    __syncthreads();
#pragma unroll
    for (int i = 0; i < 4; ++i)
#pragma unroll
      for (int j = 0; j < 8; ++j) {
        const float hv = hacc[i][j] + eb1[e*512 + fc*128 + tf + j];
        Hs[tf+j][tm+i] = fmaxf(hv, 0.f);
      }
    // GEMM2: Y[t][o] += H[t][f] . W2[o][f] over this f-chunk
    for (int kt = 0; kt < 4; ++kt) {
      __syncthreads();
#pragma unroll
      for (int r = 0; r < 4; ++r) {
        const int id = tid + r*256;
        const int o = id >> 3, kq = id & 7;
        const float4 wv = *(const float4*)(ew2 + ((long)(e*128 + o))*512 + fc*128 + kt*32 + kq*4);
        Ws[kq*4+0][o] = wv.x; Ws[kq*4+1][o] = wv.y;
        Ws[kq*4+2][o] = wv.z; Ws[kq*4+3][o] = wv.w;
      }
      __syncthreads();
#pragma unroll
      for (int kk = 0; kk < 32; ++kk) {
        float ha[4], wb[8];
        *(float4*)&ha[0] = *(const float4*)&Hs[kt*32+kk][tm];
        *(float4*)&wb[0] = *(const float4*)&Ws[kk][tf];
        *(float4*)&wb[4] = *(const float4*)&Ws[kk][tf+4];
#pragma unroll
        for (int i = 0; i < 4; ++i)
#pragma unroll
          for (int j = 0; j < 8; ++j) yacc[i][j] = fmaf(ha[i], wb[j], yacc[i][j]);
      }
    }
  }
  // write: Y{rank}[token] = w * (y + b2)
#pragma unroll
  for (int i = 0; i < 4; ++i) {
    const int t = tm + i;
    if (t < nt) {
      const int pk = stok[t];
      const int tk = pk & 0x3FFFFFFF;
      const int rk = pk >> 30;
      const float w = swgt[t];
      float* Yp = (rk ? Y1 : Y0) + (long)tk*128 + tf;
      float4 c0, c1;
      c0.x = (yacc[i][0] + eb2[e*128 + tf + 0]) * w;
      c0.y = (yacc[i][1] + eb2[e*128 + tf + 1]) * w;
      c0.z = (yacc[i][2] + eb2[e*128 + tf + 2]) * w;
      c0.w = (yacc[i][3] + eb2[e*128 + tf + 3]) * w;
      c1.x = (yacc[i][4] + eb2[e*128 + tf + 4]) * w;
      c1.y = (yacc[i][5] + eb2[e*128 + tf + 5]) * w;
      c1.z = (yacc[i][6] + eb2[e*128 + tf + 6]) * w;
      c1.w = (yacc[i][7] + eb2[e*128 + tf + 7]) * w;
      *(float4*)(Yp)     = c0;
      *(float4*)(Yp + 4) = c1;
    }
  }
}

// ---------------- final: probs = softmax(10*tanh(sc/sqrt(128)) + mask) -----
__global__ __launch_bounds__(256)
void k_softmax(float* __restrict__ out, const float* __restrict__ mask) {
  const long row = (long)blockIdx.x*4 + (threadIdx.x >> 6);
  const int l = threadIdx.x & 63;
  float4* r = (float4*)(out + row*512);
  const float4* mr = (const float4*)(mask + row*512);
  const float4 x0 = r[l], x1 = r[64 + l];
  const float4 m0 = mr[l], m1 = mr[64 + l];
  const float is = (float)(10.0 / 11.313708498984761);
  float li[8];
  li[0] = 10.f*tanhf(x0.x*(1.f/11.313708498984761f)) + m0.x;
  li[1] = 10.f*tanhf(x0.y*(1.f/11.313708498984761f)) + m0.y;
  li[2] = 10.f*tanhf(x0.z*(1.f/11.313708498984761f)) + m0.z;
  li[3] = 10.f*tanhf(x0.w*(1.f/11.313708498984761f)) + m0.w;
  li[4] = 10.f*tanhf(x1.x*(1.f/11.313708498984761f)) + m1.x;
  li[5] = 10.f*tanhf(x1.y*(1.f/11.313708498984761f)) + m1.y;
  li[6] = 10.f*tanhf(x1.z*(1.f/11.313708498984761f)) + m1.z;
  li[7] = 10.f*tanhf(x1.w*(1.f/11.313708498984761f)) + m1.w;
  (void)is;
  float mx = li[0];
#pragma unroll
  for (int u = 1; u < 8; ++u) mx = fmaxf(mx, li[u]);
#pragma unroll
  for (int o = 1; o < 64; o <<= 1) mx = fmaxf(mx, __shfl_xor(mx, o));
  float ev[8], s = 0.f;
#pragma unroll
  for (int u = 0; u < 8; ++u) { ev[u] = __expf(li[u] - mx); s += ev[u]; }
#pragma unroll
  for (int o = 1; o < 64; o <<= 1) s += __shfl_xor(s, o);
  const float inv = 1.f / s;
  float4 y0, y1;
  y0.x = ev[0]*inv; y0.y = ev[1]*inv; y0.z = ev[2]*inv; y0.w = ev[3]*inv;
  y1.x = ev[4]*inv; y1.y = ev[5]*inv; y1.z = ev[6]*inv; y1.w = ev[7]*inv;
  r[l] = y0; r[64 + l] = y1;
}

// ---------------------------------------------------------------------------
extern "C" void kernel_launch(void* const* d_in, const int* in_sizes, int n_in,
                              void* d_out, int out_size, void* d_ws, size_t ws_size,
                              hipStream_t stream) {
  (void)in_sizes; (void)n_in; (void)out_size; (void)ws_size;
  const float* pref  = (const float*)d_in[0];
  const float* graph = (const float*)d_in[1];
  const float* cap   = (const float*)d_in[2];
  const float* enc   = (const float*)d_in[3];
  const float* mask  = (const float*)d_in[4];
  const float* fc1w  = (const float*)d_in[5];
  const float* fc1b  = (const float*)d_in[6];
  const float* fc2w  = (const float*)d_in[7];
  const float* fc2b  = (const float*)d_in[8];
  const float* fc3w  = (const float*)d_in[9];
  const float* fc3b  = (const float*)d_in[10];
  const float* hWq   = (const float*)d_in[11];
  const float* hWk   = (const float*)d_in[12];
  const float* hWv   = (const float*)d_in[13];
  const float* hWc   = (const float*)d_in[14];
  const float* gw    = (const float*)d_in[15];
  const float* gpw   = (const float*)d_in[16];
  const float* ew1   = (const float*)d_in[17];
  const float* eb1   = (const float*)d_in[18];
  const float* ew2   = (const float*)d_in[19];
  const float* eb2   = (const float*)d_in[20];
  float* ws  = (float*)d_ws;
  float* out = (float*)d_out;
  // d_out scratch ranges (dead before they are overwritten by sc GEMM):
  float* Kbuf = out;              // 2097152 floats
  float* Vbuf = out + 2097152;    // 2097152 floats
  float* Y0   = out;              // reuse after attention
  float* Y1   = out + 2097152;

  hipMemsetAsync((char*)d_ws + OFF_CNT*sizeof(float), 0, 8*sizeof(int), stream);
  k_hyper<<<1, 256, 0, stream>>>(pref, fc1w, fc1b, fc2w, fc2b, fc3w, fc3b, gpw, ws);
  k_hyperw<<<257, 256, 0, stream>>>(hWq, hWk, hWv, hWc, ws);
  k_qbase<<<32, 128, 0, stream>>>(graph, ws);
  k_gemm<0><<<dim3(128, 2), 256, 0, stream>>>(enc, nullptr, ws + OFF_WK, ws + OFF_WV, Kbuf, Vbuf);
  k_attn<<<256, 256, 0, stream>>>(Kbuf, Vbuf, ws, cap, mask, ws + OFF_AO);
  k_gate<<<64, 256, 0, stream>>>(ws + OFF_AO, gw, ws);
  k_moe<<<dim3(256, 8), 256, 0, stream>>>(ws + OFF_AO, ew1, eb1, ew2, eb2, ws, Y0, Y1);
  k_gemm<1><<<dim3(128, 1), 256, 0, stream>>>(Y0, Y1, ws + OFF_WC, nullptr, ws + OFF_MH, nullptr);
  k_gemm<2><<<dim3(4, 4, 32), 256, 0, stream>>>(ws + OFF_MH, nullptr, enc, nullptr, out, nullptr);
  k_softmax<<<4096, 256, 0, stream>>>(out, mask);
}

// Round 2
// 532.744 us; speedup vs baseline: 1.7035x; 1.7035x over previous
//
#include <hip/hip_runtime.h>

// ---------------------------------------------------------------------------
// KP_Decoder: hypernet -> (k,v,q) -> attention -> top2 MoE -> combine softmax
// B=32 G=512 N=512 EMB=128 H=8 DK=16 E=8 FH=512 K=2
// All fp32 (vector ALU) this round; structured for later bf16-MFMA swaps.
// R2: k_gate block-aggregated routing (32768 global atomics -> 512).
// ---------------------------------------------------------------------------

#define TPB 256

// ws layout (float offsets)
static constexpr long OFF_MID   = 0;        // 8
static constexpr long OFF_PREFL = 8;        // 8
static constexpr long OFF_WQ    = 64;       // 128x129 = 16512
static constexpr long OFF_WK    = 16576;    // 128x128
static constexpr long OFF_WV    = 32960;    // 128x128
static constexpr long OFF_WC    = 49344;    // 128x128
static constexpr long OFF_QB    = 65728;    // 32x128 qbase
static constexpr long OFF_CNT   = 69824;    // 8 ints
static constexpr long OFF_TOK   = 69888;    // 8*16384 ints
static constexpr long OFF_WGT   = 200960;   // 8*16384 floats
static constexpr long OFF_AO    = 332288;   // 16384x128 attention out
static constexpr long OFF_MH    = 2429440;  // 16384x128 mh
// total = 4,526,592 floats = 18.1 MB

// d_out doubles as scratch: K at +0, V at +2097152 (dead before sc GEMM);
// Y0/Y1 (rank-split MoE outputs) reuse the same two ranges after attention.

// ---------------- hypernet: mid + pref gate logits -------------------------
__global__ __launch_bounds__(256)
void k_hyper(const float* __restrict__ pref, const float* __restrict__ fc1w,
             const float* __restrict__ fc1b, const float* __restrict__ fc2w,
             const float* __restrict__ fc2b, const float* __restrict__ fc3w,
             const float* __restrict__ fc3b, const float* __restrict__ gpw,
             float* __restrict__ ws) {
  __shared__ float h1[256];
  __shared__ float h2[256];
  __shared__ float mid[8];
  const int t = threadIdx.x;
  const float p0 = pref[0], p1 = pref[1];
  h1[t] = fc1w[2*t]*p0 + fc1w[2*t+1]*p1 + fc1b[t];
  __syncthreads();
  float s = 0.f;
  for (int j = 0; j < 256; ++j) s = fmaf(fc2w[t*256+j], h1[j], s);
  h2[t] = s + fc2b[t];
  __syncthreads();
  if (t < 8) {
    float s2 = 0.f;
    for (int j = 0; j < 256; ++j) s2 = fmaf(fc3w[t*256+j], h2[j], s2);
    mid[t] = s2 + fc3b[t];
    ws[OFF_MID + t] = mid[t];
  }
  __syncthreads();
  if (t < 8) {
    float s3 = 0.f;
    for (int i = 0; i < 8; ++i) s3 = fmaf(mid[i], gpw[i*8 + t], s3);
    ws[OFF_PREFL + t] = s3;
  }
}

// ---------------- hypernet heads: Wq/Wk/Wv/Wc ------------------------------
__global__ __launch_bounds__(256)
void k_hyperw(const float* __restrict__ hWq, const float* __restrict__ hWk,
              const float* __restrict__ hWv, const float* __restrict__ hWc,
              float* __restrict__ ws) {
  const int i = blockIdx.x*256 + threadIdx.x;
  const float m0 = ws[0], m1 = ws[1], m2 = ws[2], m3 = ws[3],
              m4 = ws[4], m5 = ws[5], m6 = ws[6], m7 = ws[7];
  if (i < 16512) {
    ws[OFF_WQ + i] = hWq[2*i]*m0 + hWq[2*i+1]*m1;
  } else if (i < 32896) {
    const int j = i - 16512;
    ws[OFF_WK + j] = hWk[2*j]*m2 + hWk[2*j+1]*m3;
  } else if (i < 49280) {
    const int j = i - 32896;
    ws[OFF_WV + j] = hWv[2*j]*m4 + hWv[2*j+1]*m5;
  } else if (i < 65664) {
    const int j = i - 49280;
    ws[OFF_WC + j] = hWc[2*j]*m6 + hWc[2*j+1]*m7;
  }
}

// ---------------- qbase[b][o] = graph[b] . Wq[o,0:128] ---------------------
__global__ __launch_bounds__(128)
void k_qbase(const float* __restrict__ graph, float* __restrict__ ws) {
  __shared__ float g[128];
  const int b = blockIdx.x, t = threadIdx.x;
  g[t] = graph[b*128 + t];
  __syncthreads();
  const float* wq = ws + OFF_WQ + (long)t*129;
  float s = 0.f;
  for (int i = 0; i < 128; ++i) s = fmaf(g[i], wq[i], s);
  ws[OFF_QB + b*128 + t] = s;
}

// ---------------- generic fp32 GEMM, C = A @ B^T, K=128 --------------------
// MODE 0: kv   grid(128,2):   A=enc[16384,128], B={Wk,Wv}, C={K,V}, ldc=128
// MODE 1: mh   grid(128,1):   A=Y0+Y1,          B=Wc,      C=MH,    ldc=128
// MODE 2: sc   grid(4,4,32):  per-b A=mh[b], B=enc[b], C=out[b],    ldc=512
template <int MODE>
__global__ __launch_bounds__(256)
void k_gemm(const float* __restrict__ A, const float* __restrict__ A2,
            const float* __restrict__ B0, const float* __restrict__ B1,
            float* __restrict__ C0, float* __restrict__ C1) {
  constexpr int LDT = 132;
  __shared__ float As[32][LDT];
  __shared__ float Bs[32][LDT];
  const int tid = threadIdx.x;
  const int bx = blockIdx.x;
  const float* Ap;
  const float* Ap2 = nullptr;
  const float* Bp;
  float* Cp;
  int ldc;
  if constexpr (MODE == 0) {
    Ap = A + (long)bx*128*128;
    Bp = blockIdx.y ? B1 : B0;
    Cp = (blockIdx.y ? C1 : C0) + (long)bx*128*128;
    ldc = 128;
  } else if constexpr (MODE == 1) {
    Ap  = A  + (long)bx*128*128;
    Ap2 = A2 + (long)bx*128*128;
    Bp = B0;
    Cp = C0 + (long)bx*128*128;
    ldc = 128;
  } else {
    const long zo = (long)blockIdx.z*512*128;
    Ap = A + zo + (long)bx*128*128;
    Bp = B0 + zo + (long)blockIdx.y*128*128;
    Cp = C0 + (long)blockIdx.z*512*512 + (long)bx*128*512 + (long)blockIdx.y*128;
    ldc = 512;
  }
  float acc[8][8];
#pragma unroll
  for (int i = 0; i < 8; ++i)
#pragma unroll
    for (int j = 0; j < 8; ++j) acc[i][j] = 0.f;
  const int tm = (tid >> 4) * 8;
  const int tn = (tid & 15) * 8;
  for (int kt = 0; kt < 4; ++kt) {
    __syncthreads();
#pragma unroll
    for (int r = 0; r < 4; ++r) {
      const int id = tid + r*256;
      const int m = id >> 3, kq = id & 7;
      float4 av = *(const float4*)(Ap + (long)m*128 + kt*32 + kq*4);
      if constexpr (MODE == 1) {
        const float4 a2 = *(const float4*)(Ap2 + (long)m*128 + kt*32 + kq*4);
        av.x += a2.x; av.y += a2.y; av.z += a2.z; av.w += a2.w;
      }
      As[kq*4+0][m] = av.x; As[kq*4+1][m] = av.y;
      As[kq*4+2][m] = av.z; As[kq*4+3][m] = av.w;
      const float4 bv = *(const float4*)(Bp + (long)m*128 + kt*32 + kq*4);
      Bs[kq*4+0][m] = bv.x; Bs[kq*4+1][m] = bv.y;
      Bs[kq*4+2][m] = bv.z; Bs[kq*4+3][m] = bv.w;
    }
    __syncthreads();
#pragma unroll
    for (int kk = 0; kk < 32; ++kk) {
      float a[8], b[8];
      *(float4*)&a[0] = *(const float4*)&As[kk][tm];
      *(float4*)&a[4] = *(const float4*)&As[kk][tm+4];
      *(float4*)&b[0] = *(const float4*)&Bs[kk][tn];
      *(float4*)&b[4] = *(const float4*)&Bs[kk][tn+4];
#pragma unroll
      for (int i = 0; i < 8; ++i)
#pragma unroll
        for (int j = 0; j < 8; ++j) acc[i][j] = fmaf(a[i], b[j], acc[i][j]);
    }
  }
#pragma unroll
  for (int i = 0; i < 8; ++i) {
    const float4 c0 = {acc[i][0], acc[i][1], acc[i][2], acc[i][3]};
    const float4 c1 = {acc[i][4], acc[i][5], acc[i][6], acc[i][7]};
    *(float4*)(Cp + (long)(tm+i)*ldc + tn)     = c0;
    *(float4*)(Cp + (long)(tm+i)*ldc + tn + 4) = c1;
  }
}

// ---------------- flash attention per (b,h) --------------------------------
__device__ __forceinline__ float dot4f(const float4 a, const float4 b, float s) {
  s = fmaf(a.x, b.x, s); s = fmaf(a.y, b.y, s);
  s = fmaf(a.z, b.z, s); s = fmaf(a.w, b.w, s);
  return s;
}

__global__ __launch_bounds__(256)
void k_attn(const float* __restrict__ Kb, const float* __restrict__ Vb,
            const float* __restrict__ ws, const float* __restrict__ cap,
            const float* __restrict__ mask, float* __restrict__ AO) {
  const int bh = blockIdx.x, b = bh >> 3, h = bh & 7;
  __shared__ float4 ks[512][4];
  __shared__ float4 vs[512][4];
  const int tid = threadIdx.x;
  const float* Kp = Kb + (long)b*512*128 + h*16;
  const float* Vp = Vb + (long)b*512*128 + h*16;
  for (int i = tid; i < 2048; i += 256) {
    const int n = i >> 2, c = i & 3;
    ks[n][c] = *(const float4*)(Kp + (long)n*128 + c*4);
    vs[n][c] = *(const float4*)(Vp + (long)n*128 + c*4);
  }
  float4 qbv[4], wlv[4];
  {
    const float* qbp = ws + OFF_QB + b*128 + h*16;
    const float* wqp = ws + OFF_WQ;
#pragma unroll
    for (int c = 0; c < 4; ++c) {
      qbv[c] = *(const float4*)(qbp + c*4);
      float4 w;
      w.x = wqp[(h*16 + c*4 + 0)*129 + 128];
      w.y = wqp[(h*16 + c*4 + 1)*129 + 128];
      w.z = wqp[(h*16 + c*4 + 2)*129 + 128];
      w.w = wqp[(h*16 + c*4 + 3)*129 + 128];
      wlv[c] = w;
    }
  }
  __syncthreads();
  const int g0 = tid*2;
  const float c0 = cap[b*512 + g0], c1 = cap[b*512 + g0 + 1];
  float4 q0[4], q1[4];
#pragma unroll
  for (int c = 0; c < 4; ++c) {
    q0[c].x = fmaf(c0, wlv[c].x, qbv[c].x); q0[c].y = fmaf(c0, wlv[c].y, qbv[c].y);
    q0[c].z = fmaf(c0, wlv[c].z, qbv[c].z); q0[c].w = fmaf(c0, wlv[c].w, qbv[c].w);
    q1[c].x = fmaf(c1, wlv[c].x, qbv[c].x); q1[c].y = fmaf(c1, wlv[c].y, qbv[c].y);
    q1[c].z = fmaf(c1, wlv[c].z, qbv[c].z); q1[c].w = fmaf(c1, wlv[c].w, qbv[c].w);
  }
  float m0 = -1e30f, m1 = -1e30f, l0 = 0.f, l1 = 0.f;
  float4 a0[4], a1[4];
#pragma unroll
  for (int c = 0; c < 4; ++c) {
    a0[c] = make_float4(0.f, 0.f, 0.f, 0.f);
    a1[c] = make_float4(0.f, 0.f, 0.f, 0.f);
  }
  const float* mr = mask + (long)(b*512 + g0)*512;
  for (int nb = 0; nb < 512; nb += 4) {
    const float4 mk0 = *(const float4*)(mr + nb);
    const float4 mk1 = *(const float4*)(mr + 512 + nb);
#pragma unroll
    for (int u = 0; u < 4; ++u) {
      const int n = nb + u;
      const float4 k0 = ks[n][0], k1 = ks[n][1], k2 = ks[n][2], k3 = ks[n][3];
      float s0 = 0.f, s1 = 0.f;
      s0 = dot4f(q0[0], k0, s0); s0 = dot4f(q0[1], k1, s0);
      s0 = dot4f(q0[2], k2, s0); s0 = dot4f(q0[3], k3, s0);
      s1 = dot4f(q1[0], k0, s1); s1 = dot4f(q1[1], k1, s1);
      s1 = dot4f(q1[2], k2, s1); s1 = dot4f(q1[3], k3, s1);
      s0 = fmaf(s0, 0.25f, (&mk0.x)[u]);
      s1 = fmaf(s1, 0.25f, (&mk1.x)[u]);
      float p0;
      if (s0 > m0) {
        const float sc = __expf(m0 - s0);
        l0 *= sc;
#pragma unroll
        for (int c = 0; c < 4; ++c) {
          a0[c].x *= sc; a0[c].y *= sc; a0[c].z *= sc; a0[c].w *= sc;
        }
        m0 = s0; p0 = 1.f;
      } else p0 = __expf(s0 - m0);
      l0 += p0;
      float p1;
      if (s1 > m1) {
        const float sc = __expf(m1 - s1);
        l1 *= sc;
#pragma unroll
        for (int c = 0; c < 4; ++c) {
          a1[c].x *= sc; a1[c].y *= sc; a1[c].z *= sc; a1[c].w *= sc;
        }
        m1 = s1; p1 = 1.f;
      } else p1 = __expf(s1 - m1);
      l1 += p1;
      const float4 v0 = vs[n][0], v1 = vs[n][1], v2 = vs[n][2], v3 = vs[n][3];
      a0[0].x = fmaf(p0, v0.x, a0[0].x); a0[0].y = fmaf(p0, v0.y, a0[0].y);
      a0[0].z = fmaf(p0, v0.z, a0[0].z); a0[0].w = fmaf(p0, v0.w, a0[0].w);
      a0[1].x = fmaf(p0, v1.x, a0[1].x); a0[1].y = fmaf(p0, v1.y, a0[1].y);
      a0[1].z = fmaf(p0, v1.z, a0[1].z); a0[1].w = fmaf(p0, v1.w, a0[1].w);
      a0[2].x = fmaf(p0, v2.x, a0[2].x); a0[2].y = fmaf(p0, v2.y, a0[2].y);
      a0[2].z = fmaf(p0, v2.z, a0[2].z); a0[2].w = fmaf(p0, v2.w, a0[2].w);
      a0[3].x = fmaf(p0, v3.x, a0[3].x); a0[3].y = fmaf(p0, v3.y, a0[3].y);
      a0[3].z = fmaf(p0, v3.z, a0[3].z); a0[3].w = fmaf(p0, v3.w, a0[3].w);
      a1[0].x = fmaf(p1, v0.x, a1[0].x); a1[0].y = fmaf(p1, v0.y, a1[0].y);
      a1[0].z = fmaf(p1, v0.z, a1[0].z); a1[0].w = fmaf(p1, v0.w, a1[0].w);
      a1[1].x = fmaf(p1, v1.x, a1[1].x); a1[1].y = fmaf(p1, v1.y, a1[1].y);
      a1[1].z = fmaf(p1, v1.z, a1[1].z); a1[1].w = fmaf(p1, v1.w, a1[1].w);
      a1[2].x = fmaf(p1, v2.x, a1[2].x); a1[2].y = fmaf(p1, v2.y, a1[2].y);
      a1[2].z = fmaf(p1, v2.z, a1[2].z); a1[2].w = fmaf(p1, v2.w, a1[2].w);
      a1[3].x = fmaf(p1, v3.x, a1[3].x); a1[3].y = fmaf(p1, v3.y, a1[3].y);
      a1[3].z = fmaf(p1, v3.z, a1[3].z); a1[3].w = fmaf(p1, v3.w, a1[3].w);
    }
  }
  const float inv0 = 1.f / l0, inv1 = 1.f / l1;
  float* o0 = AO + (long)(b*512 + g0)*128 + h*16;
  float* o1 = o0 + 128;
#pragma unroll
  for (int c = 0; c < 4; ++c) {
    float4 w0 = a0[c];
    w0.x *= inv0; w0.y *= inv0; w0.z *= inv0; w0.w *= inv0;
    *(float4*)(o0 + c*4) = w0;
    float4 w1 = a1[c];
    w1.x *= inv1; w1.y *= inv1; w1.z *= inv1; w1.w *= inv1;
    *(float4*)(o1 + c*4) = w1;
  }
}

// ---------------- gating: top-2 + expert lists (block-aggregated) ----------
__global__ __launch_bounds__(256)
void k_gate(const float* __restrict__ AO, const float* __restrict__ gw,
            float* __restrict__ ws) {
  const int tid = threadIdx.x;
  const int t = blockIdx.x*256 + tid;
  const float* x = AO + (long)t*128;
  float lg[8];
  {
    const float* pl = ws + OFF_PREFL;
#pragma unroll
    for (int e = 0; e < 8; ++e) lg[e] = pl[e];
  }
  for (int i = 0; i < 128; i += 4) {
    const float4 xv = *(const float4*)(x + i);
#pragma unroll
    for (int u = 0; u < 4; ++u) {
      const float xi = (&xv.x)[u];
      const float4 ga = *(const float4*)(gw + (i+u)*8);
      const float4 gb = *(const float4*)(gw + (i+u)*8 + 4);
      lg[0] = fmaf(xi, ga.x, lg[0]); lg[1] = fmaf(xi, ga.y, lg[1]);
      lg[2] = fmaf(xi, ga.z, lg[2]); lg[3] = fmaf(xi, ga.w, lg[3]);
      lg[4] = fmaf(xi, gb.x, lg[4]); lg[5] = fmaf(xi, gb.y, lg[5]);
      lg[6] = fmaf(xi, gb.z, lg[6]); lg[7] = fmaf(xi, gb.w, lg[7]);
    }
  }
  int i0 = 0; float v0 = lg[0];
#pragma unroll
  for (int e = 1; e < 8; ++e) if (lg[e] > v0) { v0 = lg[e]; i0 = e; }
  int i1 = -1; float v1 = -1e30f;
#pragma unroll
  for (int e = 0; e < 8; ++e) if (e != i0 && lg[e] > v1) { v1 = lg[e]; i1 = e; }
  const float e1 = __expf(v1 - v0);
  const float w0 = 1.f / (1.f + e1);
  const float w1 = 1.f - w0;
  // --- block-aggregated list append: LDS positions + 8 global atomics ---
  __shared__ int bcnt[8];
  __shared__ int gbase[8];
  if (tid < 8) bcnt[tid] = 0;
  __syncthreads();
  const int p0 = atomicAdd(&bcnt[i0], 1);
  const int p1 = atomicAdd(&bcnt[i1], 1);
  __syncthreads();
  if (tid < 8) {
    int* cnt = (int*)(ws + OFF_CNT);
    gbase[tid] = (bcnt[tid] > 0) ? atomicAdd(&cnt[tid], bcnt[tid]) : 0;
  }
  __syncthreads();
  int* tokp = (int*)(ws + OFF_TOK);
  float* wgtp = ws + OFF_WGT;
  const int s0 = gbase[i0] + p0;
  tokp[i0*16384 + s0] = t;             // rank 0
  wgtp[i0*16384 + s0] = w0;
  const int s1 = gbase[i1] + p1;
  tokp[i1*16384 + s1] = t | (1 << 30); // rank 1
  wgtp[i1*16384 + s1] = w1;
}

// ---------------- MoE experts: per (expert, 64-token chunk) ----------------
__global__ __launch_bounds__(256)
void k_moe(const float* __restrict__ AO, const float* __restrict__ ew1,
           const float* __restrict__ eb1, const float* __restrict__ ew2,
           const float* __restrict__ eb2, float* __restrict__ ws,
           float* __restrict__ Y0, float* __restrict__ Y1) {
  const int e = blockIdx.y;
  const int ce = ((const int*)(ws + OFF_CNT))[e];
  const int base = blockIdx.x * 64;
  if (base >= ce) return;
  const int nt = min(64, ce - base);
  __shared__ float Xs[128][68];   // [i][t]
  __shared__ float Hs[128][68];   // [f][t]
  __shared__ float Ws[32][132];   // staged weight k-tile, [k][f or o]
  __shared__ int stok[64];
  __shared__ float swgt[64];
  const int tid = threadIdx.x;
  if (tid < 64) {
    if (tid < nt) {
      stok[tid] = ((const int*)(ws + OFF_TOK))[e*16384 + base + tid];
      swgt[tid] = (ws + OFF_WGT)[e*16384 + base + tid];
    } else { stok[tid] = -1; swgt[tid] = 0.f; }
  }
  __syncthreads();
#pragma unroll
  for (int r = 0; r < 8; ++r) {
    const int id = tid + r*256;
    const int t = id >> 5, c = id & 31;
    const int pk = stok[t];
    float4 xv = make_float4(0.f, 0.f, 0.f, 0.f);
    if (pk >= 0) xv = *(const float4*)(AO + (long)(pk & 0x3FFFFFFF)*128 + c*4);
    Xs[c*4+0][t] = xv.x; Xs[c*4+1][t] = xv.y;
    Xs[c*4+2][t] = xv.z; Xs[c*4+3][t] = xv.w;
  }
  const int tm = (tid >> 4) * 4;   // token micro rows (4)
  const int tf = (tid & 15) * 8;   // f / o micro cols (8)
  float yacc[4][8];
#pragma unroll
  for (int i = 0; i < 4; ++i)
#pragma unroll
    for (int j = 0; j < 8; ++j) yacc[i][j] = 0.f;

  for (int fc = 0; fc < 4; ++fc) {
    float hacc[4][8];
#pragma unroll
    for (int i = 0; i < 4; ++i)
#pragma unroll
      for (int j = 0; j < 8; ++j) hacc[i][j] = 0.f;
    // GEMM1: H[t][f] = X[t][i] . W1[f][i], f in this 128-chunk
    for (int kt = 0; kt < 4; ++kt) {
      __syncthreads();
#pragma unroll
      for (int r = 0; r < 4; ++r) {
        const int id = tid + r*256;
        const int f = id >> 3, kq = id & 7;
        const float4 wv = *(const float4*)(ew1 + ((long)(e*512 + fc*128 + f))*128 + kt*32 + kq*4);
        Ws[kq*4+0][f] = wv.x; Ws[kq*4+1][f] = wv.y;
        Ws[kq*4+2][f] = wv.z; Ws[kq*4+3][f] = wv.w;
      }
      __syncthreads();
#pragma unroll
      for (int kk = 0; kk < 32; ++kk) {
        float xa[4], wb[8];
        *(float4*)&xa[0] = *(const float4*)&Xs[kt*32+kk][tm];
        *(float4*)&wb[0] = *(const float4*)&Ws[kk][tf];
        *(float4*)&wb[4] = *(const float4*)&Ws[kk][tf+4];
#pragma unroll
        for (int i = 0; i < 4; ++i)
#pragma unroll
          for (int j = 0; j < 8; ++j) hacc[i][j] = fmaf(xa[i], wb[j], hacc[i][j]);
      }
    }
    __syncthreads();
#pragma unroll
    for (int i = 0; i < 4; ++i)
#pragma unroll
      for (int j = 0; j < 8; ++j) {
        const float hv = hacc[i][j] + eb1[e*512 + fc*128 + tf + j];
        Hs[tf+j][tm+i] = fmaxf(hv, 0.f);
      }
    // GEMM2: Y[t][o] += H[t][f] . W2[o][f] over this f-chunk
    for (int kt = 0; kt < 4; ++kt) {
      __syncthreads();
#pragma unroll
      for (int r = 0; r < 4; ++r) {
        const int id = tid + r*256;
        const int o = id >> 3, kq = id & 7;
        const float4 wv = *(const float4*)(ew2 + ((long)(e*128 + o))*512 + fc*128 + kt*32 + kq*4);
        Ws[kq*4+0][o] = wv.x; Ws[kq*4+1][o] = wv.y;
        Ws[kq*4+2][o] = wv.z; Ws[kq*4+3][o] = wv.w;
      }
      __syncthreads();
#pragma unroll
      for (int kk = 0; kk < 32; ++kk) {
        float ha[4], wb[8];
        *(float4*)&ha[0] = *(const float4*)&Hs[kt*32+kk][tm];
        *(float4*)&wb[0] = *(const float4*)&Ws[kk][tf];
        *(float4*)&wb[4] = *(const float4*)&Ws[kk][tf+4];
#pragma unroll
        for (int i = 0; i < 4; ++i)
#pragma unroll
          for (int j = 0; j < 8; ++j) yacc[i][j] = fmaf(ha[i], wb[j], yacc[i][j]);
      }
    }
  }
  // write: Y{rank}[token] = w * (y + b2)
#pragma unroll
  for (int i = 0; i < 4; ++i) {
    const int t = tm + i;
    if (t < nt) {
      const int pk = stok[t];
      const int tk = pk & 0x3FFFFFFF;
      const int rk = pk >> 30;
      const float w = swgt[t];
      float* Yp = (rk ? Y1 : Y0) + (long)tk*128 + tf;
      float4 c0, c1;
      c0.x = (yacc[i][0] + eb2[e*128 + tf + 0]) * w;
      c0.y = (yacc[i][1] + eb2[e*128 + tf + 1]) * w;
      c0.z = (yacc[i][2] + eb2[e*128 + tf + 2]) * w;
      c0.w = (yacc[i][3] + eb2[e*128 + tf + 3]) * w;
      c1.x = (yacc[i][4] + eb2[e*128 + tf + 4]) * w;
      c1.y = (yacc[i][5] + eb2[e*128 + tf + 5]) * w;
      c1.z = (yacc[i][6] + eb2[e*128 + tf + 6]) * w;
      c1.w = (yacc[i][7] + eb2[e*128 + tf + 7]) * w;
      *(float4*)(Yp)     = c0;
      *(float4*)(Yp + 4) = c1;
    }
  }
}

// ---------------- final: probs = softmax(10*tanh(sc/sqrt(128)) + mask) -----
__global__ __launch_bounds__(256)
void k_softmax(float* __restrict__ out, const float* __restrict__ mask) {
  const long row = (long)blockIdx.x*4 + (threadIdx.x >> 6);
  const int l = threadIdx.x & 63;
  float4* r = (float4*)(out + row*512);
  const float4* mr = (const float4*)(mask + row*512);
  const float4 x0 = r[l], x1 = r[64 + l];
  const float4 m0 = mr[l], m1 = mr[64 + l];
  float li[8];
  li[0] = 10.f*tanhf(x0.x*(1.f/11.313708498984761f)) + m0.x;
  li[1] = 10.f*tanhf(x0.y*(1.f/11.313708498984761f)) + m0.y;
  li[2] = 10.f*tanhf(x0.z*(1.f/11.313708498984761f)) + m0.z;
  li[3] = 10.f*tanhf(x0.w*(1.f/11.313708498984761f)) + m0.w;
  li[4] = 10.f*tanhf(x1.x*(1.f/11.313708498984761f)) + m1.x;
  li[5] = 10.f*tanhf(x1.y*(1.f/11.313708498984761f)) + m1.y;
  li[6] = 10.f*tanhf(x1.z*(1.f/11.313708498984761f)) + m1.z;
  li[7] = 10.f*tanhf(x1.w*(1.f/11.313708498984761f)) + m1.w;
  float mx = li[0];
#pragma unroll
  for (int u = 1; u < 8; ++u) mx = fmaxf(mx, li[u]);
#pragma unroll
  for (int o = 1; o < 64; o <<= 1) mx = fmaxf(mx, __shfl_xor(mx, o));
  float ev[8], s = 0.f;
#pragma unroll
  for (int u = 0; u < 8; ++u) { ev[u] = __expf(li[u] - mx); s += ev[u]; }
#pragma unroll
  for (int o = 1; o < 64; o <<= 1) s += __shfl_xor(s, o);
  const float inv = 1.f / s;
  float4 y0, y1;
  y0.x = ev[0]*inv; y0.y = ev[1]*inv; y0.z = ev[2]*inv; y0.w = ev[3]*inv;
  y1.x = ev[4]*inv; y1.y = ev[5]*inv; y1.z = ev[6]*inv; y1.w = ev[7]*inv;
  r[l] = y0; r[64 + l] = y1;
}

// ---------------------------------------------------------------------------
extern "C" void kernel_launch(void* const* d_in, const int* in_sizes, int n_in,
                              void* d_out, int out_size, void* d_ws, size_t ws_size,
                              hipStream_t stream) {
  (void)in_sizes; (void)n_in; (void)out_size; (void)ws_size;
  const float* pref  = (const float*)d_in[0];
  const float* graph = (const float*)d_in[1];
  const float* cap   = (const float*)d_in[2];
  const float* enc   = (const float*)d_in[3];
  const float* mask  = (const float*)d_in[4];
  const float* fc1w  = (const float*)d_in[5];
  const float* fc1b  = (const float*)d_in[6];
  const float* fc2w  = (const float*)d_in[7];
  const float* fc2b  = (const float*)d_in[8];
  const float* fc3w  = (const float*)d_in[9];
  const float* fc3b  = (const float*)d_in[10];
  const float* hWq   = (const float*)d_in[11];
  const float* hWk   = (const float*)d_in[12];
  const float* hWv   = (const float*)d_in[13];
  const float* hWc   = (const float*)d_in[14];
  const float* gw    = (const float*)d_in[15];
  const float* gpw   = (const float*)d_in[16];
  const float* ew1   = (const float*)d_in[17];
  const float* eb1   = (const float*)d_in[18];
  const float* ew2   = (const float*)d_in[19];
  const float* eb2   = (const float*)d_in[20];
  float* ws  = (float*)d_ws;
  float* out = (float*)d_out;
  // d_out scratch ranges (dead before they are overwritten by sc GEMM):
  float* Kbuf = out;              // 2097152 floats
  float* Vbuf = out + 2097152;    // 2097152 floats
  float* Y0   = out;              // reuse after attention
  float* Y1   = out + 2097152;

  hipMemsetAsync((char*)d_ws + OFF_CNT*sizeof(float), 0, 8*sizeof(int), stream);
  k_hyper<<<1, 256, 0, stream>>>(pref, fc1w, fc1b, fc2w, fc2b, fc3w, fc3b, gpw, ws);
  k_hyperw<<<257, 256, 0, stream>>>(hWq, hWk, hWv, hWc, ws);
  k_qbase<<<32, 128, 0, stream>>>(graph, ws);
  k_gemm<0><<<dim3(128, 2), 256, 0, stream>>>(enc, nullptr, ws + OFF_WK, ws + OFF_WV, Kbuf, Vbuf);
  k_attn<<<256, 256, 0, stream>>>(Kbuf, Vbuf, ws, cap, mask, ws + OFF_AO);
  k_gate<<<64, 256, 0, stream>>>(ws + OFF_AO, gw, ws);
  k_moe<<<dim3(256, 8), 256, 0, stream>>>(ws + OFF_AO, ew1, eb1, ew2, eb2, ws, Y0, Y1);
  k_gemm<1><<<dim3(128, 1), 256, 0, stream>>>(Y0, Y1, ws + OFF_WC, nullptr, ws + OFF_MH, nullptr);
  k_gemm<2><<<dim3(4, 4, 32), 256, 0, stream>>>(ws + OFF_MH, nullptr, enc, nullptr, out, nullptr);
  k_softmax<<<4096, 256, 0, stream>>>(out, mask);
}

// Round 3
// 297.490 us; speedup vs baseline: 3.0507x; 1.7908x over previous
//
#include <hip/hip_runtime.h>

// ---------------------------------------------------------------------------
// KP_Decoder: hypernet -> (k,v,q) -> attention -> top2 MoE -> combine softmax
// B=32 G=512 N=512 EMB=128 H=8 DK=16 E=8 FH=512 K=2
// R2: k_gate block-aggregated routing (32768 global atomics -> 512).
// R3: k_moe rewritten as bf16 MFMA (16x16x32), XOR-swizzled LDS, 67.5KB LDS.
// ---------------------------------------------------------------------------

typedef __attribute__((ext_vector_type(8))) __bf16 bf16x8;
typedef __attribute__((ext_vector_type(4))) float f32x4;

// ws layout (float offsets)
static constexpr long OFF_MID   = 0;        // 8
static constexpr long OFF_PREFL = 8;        // 8
static constexpr long OFF_WQ    = 64;       // 128x129 = 16512
static constexpr long OFF_WK    = 16576;    // 128x128
static constexpr long OFF_WV    = 32960;    // 128x128
static constexpr long OFF_WC    = 49344;    // 128x128
static constexpr long OFF_QB    = 65728;    // 32x128 qbase
static constexpr long OFF_CNT   = 69824;    // 8 ints
static constexpr long OFF_TOK   = 69888;    // 8*16384 ints
static constexpr long OFF_WGT   = 200960;   // 8*16384 floats
static constexpr long OFF_AO    = 332288;   // 16384x128 attention out
static constexpr long OFF_MH    = 2429440;  // 16384x128 mh
// total = 4,526,592 floats = 18.1 MB

// d_out (8.4M floats) doubles as scratch:
//   K at +0, V at +2M (dead before sc GEMM); Y0/Y1 reuse the same ranges.
//   ew1b (bf16) at +4M floats, ew2b (bf16) at +4.25M floats (dead at sc GEMM).

__device__ __forceinline__ unsigned f2bf(float x) {
  union { float f; unsigned u; } v; v.f = x;
  return ((v.u + 0x7FFFu + ((v.u >> 16) & 1u)) >> 16) & 0xFFFFu;
}

// ---------------- hypernet: mid + pref gate logits -------------------------
__global__ __launch_bounds__(256)
void k_hyper(const float* __restrict__ pref, const float* __restrict__ fc1w,
             const float* __restrict__ fc1b, const float* __restrict__ fc2w,
             const float* __restrict__ fc2b, const float* __restrict__ fc3w,
             const float* __restrict__ fc3b, const float* __restrict__ gpw,
             float* __restrict__ ws) {
  __shared__ float h1[256];
  __shared__ float h2[256];
  __shared__ float mid[8];
  const int t = threadIdx.x;
  const float p0 = pref[0], p1 = pref[1];
  h1[t] = fc1w[2*t]*p0 + fc1w[2*t+1]*p1 + fc1b[t];
  __syncthreads();
  float s = 0.f;
  for (int j = 0; j < 256; ++j) s = fmaf(fc2w[t*256+j], h1[j], s);
  h2[t] = s + fc2b[t];
  __syncthreads();
  if (t < 8) {
    float s2 = 0.f;
    for (int j = 0; j < 256; ++j) s2 = fmaf(fc3w[t*256+j], h2[j], s2);
    mid[t] = s2 + fc3b[t];
    ws[OFF_MID + t] = mid[t];
  }
  __syncthreads();
  if (t < 8) {
    float s3 = 0.f;
    for (int i = 0; i < 8; ++i) s3 = fmaf(mid[i], gpw[i*8 + t], s3);
    ws[OFF_PREFL + t] = s3;
  }
}

// ---------------- hypernet heads: Wq/Wk/Wv/Wc ------------------------------
__global__ __launch_bounds__(256)
void k_hyperw(const float* __restrict__ hWq, const float* __restrict__ hWk,
              const float* __restrict__ hWv, const float* __restrict__ hWc,
              float* __restrict__ ws) {
  const int i = blockIdx.x*256 + threadIdx.x;
  const float m0 = ws[0], m1 = ws[1], m2 = ws[2], m3 = ws[3],
              m4 = ws[4], m5 = ws[5], m6 = ws[6], m7 = ws[7];
  if (i < 16512) {
    ws[OFF_WQ + i] = hWq[2*i]*m0 + hWq[2*i+1]*m1;
  } else if (i < 32896) {
    const int j = i - 16512;
    ws[OFF_WK + j] = hWk[2*j]*m2 + hWk[2*j+1]*m3;
  } else if (i < 49280) {
    const int j = i - 32896;
    ws[OFF_WV + j] = hWv[2*j]*m4 + hWv[2*j+1]*m5;
  } else if (i < 65664) {
    const int j = i - 49280;
    ws[OFF_WC + j] = hWc[2*j]*m6 + hWc[2*j+1]*m7;
  }
}

// ---------------- weight bf16 conversion for MoE ---------------------------
__global__ __launch_bounds__(256)
void k_cvt(const float* __restrict__ ew1, const float* __restrict__ ew2,
           unsigned short* __restrict__ w1b, unsigned short* __restrict__ w2b) {
  const int i = blockIdx.x*256 + threadIdx.x;   // one float4 per thread
  const int h = 131072;                          // 524288/4
  const float4 v = (i < h) ? *(const float4*)(ew1 + (long)i*4)
                           : *(const float4*)(ew2 + (long)(i-h)*4);
  uint2 p;
  p.x = f2bf(v.x) | (f2bf(v.y) << 16);
  p.y = f2bf(v.z) | (f2bf(v.w) << 16);
  unsigned short* dst = (i < h) ? (w1b + (long)i*4) : (w2b + (long)(i-h)*4);
  *(uint2*)dst = p;
}

// ---------------- qbase[b][o] = graph[b] . Wq[o,0:128] ---------------------
__global__ __launch_bounds__(128)
void k_qbase(const float* __restrict__ graph, float* __restrict__ ws) {
  __shared__ float g[128];
  const int b = blockIdx.x, t = threadIdx.x;
  g[t] = graph[b*128 + t];
  __syncthreads();
  const float* wq = ws + OFF_WQ + (long)t*129;
  float s = 0.f;
  for (int i = 0; i < 128; ++i) s = fmaf(g[i], wq[i], s);
  ws[OFF_QB + b*128 + t] = s;
}

// ---------------- generic fp32 GEMM, C = A @ B^T, K=128 --------------------
template <int MODE>
__global__ __launch_bounds__(256)
void k_gemm(const float* __restrict__ A, const float* __restrict__ A2,
            const float* __restrict__ B0, const float* __restrict__ B1,
            float* __restrict__ C0, float* __restrict__ C1) {
  constexpr int LDT = 132;
  __shared__ float As[32][LDT];
  __shared__ float Bs[32][LDT];
  const int tid = threadIdx.x;
  const int bx = blockIdx.x;
  const float* Ap;
  const float* Ap2 = nullptr;
  const float* Bp;
  float* Cp;
  int ldc;
  if constexpr (MODE == 0) {
    Ap = A + (long)bx*128*128;
    Bp = blockIdx.y ? B1 : B0;
    Cp = (blockIdx.y ? C1 : C0) + (long)bx*128*128;
    ldc = 128;
  } else if constexpr (MODE == 1) {
    Ap  = A  + (long)bx*128*128;
    Ap2 = A2 + (long)bx*128*128;
    Bp = B0;
    Cp = C0 + (long)bx*128*128;
    ldc = 128;
  } else {
    const long zo = (long)blockIdx.z*512*128;
    Ap = A + zo + (long)bx*128*128;
    Bp = B0 + zo + (long)blockIdx.y*128*128;
    Cp = C0 + (long)blockIdx.z*512*512 + (long)bx*128*512 + (long)blockIdx.y*128;
    ldc = 512;
  }
  float acc[8][8];
#pragma unroll
  for (int i = 0; i < 8; ++i)
#pragma unroll
    for (int j = 0; j < 8; ++j) acc[i][j] = 0.f;
  const int tm = (tid >> 4) * 8;
  const int tn = (tid & 15) * 8;
  for (int kt = 0; kt < 4; ++kt) {
    __syncthreads();
#pragma unroll
    for (int r = 0; r < 4; ++r) {
      const int id = tid + r*256;
      const int m = id >> 3, kq = id & 7;
      float4 av = *(const float4*)(Ap + (long)m*128 + kt*32 + kq*4);
      if constexpr (MODE == 1) {
        const float4 a2 = *(const float4*)(Ap2 + (long)m*128 + kt*32 + kq*4);
        av.x += a2.x; av.y += a2.y; av.z += a2.z; av.w += a2.w;
      }
      As[kq*4+0][m] = av.x; As[kq*4+1][m] = av.y;
      As[kq*4+2][m] = av.z; As[kq*4+3][m] = av.w;
      const float4 bv = *(const float4*)(Bp + (long)m*128 + kt*32 + kq*4);
      Bs[kq*4+0][m] = bv.x; Bs[kq*4+1][m] = bv.y;
      Bs[kq*4+2][m] = bv.z; Bs[kq*4+3][m] = bv.w;
    }
    __syncthreads();
#pragma unroll
    for (int kk = 0; kk < 32; ++kk) {
      float a[8], b[8];
      *(float4*)&a[0] = *(const float4*)&As[kk][tm];
      *(float4*)&a[4] = *(const float4*)&As[kk][tm+4];
      *(float4*)&b[0] = *(const float4*)&Bs[kk][tn];
      *(float4*)&b[4] = *(const float4*)&Bs[kk][tn+4];
#pragma unroll
      for (int i = 0; i < 8; ++i)
#pragma unroll
        for (int j = 0; j < 8; ++j) acc[i][j] = fmaf(a[i], b[j], acc[i][j]);
    }
  }
#pragma unroll
  for (int i = 0; i < 8; ++i) {
    const float4 c0 = {acc[i][0], acc[i][1], acc[i][2], acc[i][3]};
    const float4 c1 = {acc[i][4], acc[i][5], acc[i][6], acc[i][7]};
    *(float4*)(Cp + (long)(tm+i)*ldc + tn)     = c0;
    *(float4*)(Cp + (long)(tm+i)*ldc + tn + 4) = c1;
  }
}

// ---------------- flash attention per (b,h) --------------------------------
__device__ __forceinline__ float dot4f(const float4 a, const float4 b, float s) {
  s = fmaf(a.x, b.x, s); s = fmaf(a.y, b.y, s);
  s = fmaf(a.z, b.z, s); s = fmaf(a.w, b.w, s);
  return s;
}

__global__ __launch_bounds__(256)
void k_attn(const float* __restrict__ Kb, const float* __restrict__ Vb,
            const float* __restrict__ ws, const float* __restrict__ cap,
            const float* __restrict__ mask, float* __restrict__ AO) {
  const int bh = blockIdx.x, b = bh >> 3, h = bh & 7;
  __shared__ float4 ks[512][4];
  __shared__ float4 vs[512][4];
  const int tid = threadIdx.x;
  const float* Kp = Kb + (long)b*512*128 + h*16;
  const float* Vp = Vb + (long)b*512*128 + h*16;
  for (int i = tid; i < 2048; i += 256) {
    const int n = i >> 2, c = i & 3;
    ks[n][c] = *(const float4*)(Kp + (long)n*128 + c*4);
    vs[n][c] = *(const float4*)(Vp + (long)n*128 + c*4);
  }
  float4 qbv[4], wlv[4];
  {
    const float* qbp = ws + OFF_QB + b*128 + h*16;
    const float* wqp = ws + OFF_WQ;
#pragma unroll
    for (int c = 0; c < 4; ++c) {
      qbv[c] = *(const float4*)(qbp + c*4);
      float4 w;
      w.x = wqp[(h*16 + c*4 + 0)*129 + 128];
      w.y = wqp[(h*16 + c*4 + 1)*129 + 128];
      w.z = wqp[(h*16 + c*4 + 2)*129 + 128];
      w.w = wqp[(h*16 + c*4 + 3)*129 + 128];
      wlv[c] = w;
    }
  }
  __syncthreads();
  const int g0 = tid*2;
  const float c0 = cap[b*512 + g0], c1 = cap[b*512 + g0 + 1];
  float4 q0[4], q1[4];
#pragma unroll
  for (int c = 0; c < 4; ++c) {
    q0[c].x = fmaf(c0, wlv[c].x, qbv[c].x); q0[c].y = fmaf(c0, wlv[c].y, qbv[c].y);
    q0[c].z = fmaf(c0, wlv[c].z, qbv[c].z); q0[c].w = fmaf(c0, wlv[c].w, qbv[c].w);
    q1[c].x = fmaf(c1, wlv[c].x, qbv[c].x); q1[c].y = fmaf(c1, wlv[c].y, qbv[c].y);
    q1[c].z = fmaf(c1, wlv[c].z, qbv[c].z); q1[c].w = fmaf(c1, wlv[c].w, qbv[c].w);
  }
  float m0 = -1e30f, m1 = -1e30f, l0 = 0.f, l1 = 0.f;
  float4 a0[4], a1[4];
#pragma unroll
  for (int c = 0; c < 4; ++c) {
    a0[c] = make_float4(0.f, 0.f, 0.f, 0.f);
    a1[c] = make_float4(0.f, 0.f, 0.f, 0.f);
  }
  const float* mr = mask + (long)(b*512 + g0)*512;
  for (int nb = 0; nb < 512; nb += 4) {
    const float4 mk0 = *(const float4*)(mr + nb);
    const float4 mk1 = *(const float4*)(mr + 512 + nb);
#pragma unroll
    for (int u = 0; u < 4; ++u) {
      const int n = nb + u;
      const float4 k0 = ks[n][0], k1 = ks[n][1], k2 = ks[n][2], k3 = ks[n][3];
      float s0 = 0.f, s1 = 0.f;
      s0 = dot4f(q0[0], k0, s0); s0 = dot4f(q0[1], k1, s0);
      s0 = dot4f(q0[2], k2, s0); s0 = dot4f(q0[3], k3, s0);
      s1 = dot4f(q1[0], k0, s1); s1 = dot4f(q1[1], k1, s1);
      s1 = dot4f(q1[2], k2, s1); s1 = dot4f(q1[3], k3, s1);
      s0 = fmaf(s0, 0.25f, (&mk0.x)[u]);
      s1 = fmaf(s1, 0.25f, (&mk1.x)[u]);
      float p0;
      if (s0 > m0) {
        const float sc = __expf(m0 - s0);
        l0 *= sc;
#pragma unroll
        for (int c = 0; c < 4; ++c) {
          a0[c].x *= sc; a0[c].y *= sc; a0[c].z *= sc; a0[c].w *= sc;
        }
        m0 = s0; p0 = 1.f;
      } else p0 = __expf(s0 - m0);
      l0 += p0;
      float p1;
      if (s1 > m1) {
        const float sc = __expf(m1 - s1);
        l1 *= sc;
#pragma unroll
        for (int c = 0; c < 4; ++c) {
          a1[c].x *= sc; a1[c].y *= sc; a1[c].z *= sc; a1[c].w *= sc;
        }
        m1 = s1; p1 = 1.f;
      } else p1 = __expf(s1 - m1);
      l1 += p1;
      const float4 v0 = vs[n][0], v1 = vs[n][1], v2 = vs[n][2], v3 = vs[n][3];
      a0[0].x = fmaf(p0, v0.x, a0[0].x); a0[0].y = fmaf(p0, v0.y, a0[0].y);
      a0[0].z = fmaf(p0, v0.z, a0[0].z); a0[0].w = fmaf(p0, v0.w, a0[0].w);
      a0[1].x = fmaf(p0, v1.x, a0[1].x); a0[1].y = fmaf(p0, v1.y, a0[1].y);
      a0[1].z = fmaf(p0, v1.z, a0[1].z); a0[1].w = fmaf(p0, v1.w, a0[1].w);
      a0[2].x = fmaf(p0, v2.x, a0[2].x); a0[2].y = fmaf(p0, v2.y, a0[2].y);
      a0[2].z = fmaf(p0, v2.z, a0[2].z); a0[2].w = fmaf(p0, v2.w, a0[2].w);
      a0[3].x = fmaf(p0, v3.x, a0[3].x); a0[3].y = fmaf(p0, v3.y, a0[3].y);
      a0[3].z = fmaf(p0, v3.z, a0[3].z); a0[3].w = fmaf(p0, v3.w, a0[3].w);
      a1[0].x = fmaf(p1, v0.x, a1[0].x); a1[0].y = fmaf(p1, v0.y, a1[0].y);
      a1[0].z = fmaf(p1, v0.z, a1[0].z); a1[0].w = fmaf(p1, v0.w, a1[0].w);
      a1[1].x = fmaf(p1, v1.x, a1[1].x); a1[1].y = fmaf(p1, v1.y, a1[1].y);
      a1[1].z = fmaf(p1, v1.z, a1[1].z); a1[1].w = fmaf(p1, v1.w, a1[1].w);
      a1[2].x = fmaf(p1, v2.x, a1[2].x); a1[2].y = fmaf(p1, v2.y, a1[2].y);
      a1[2].z = fmaf(p1, v2.z, a1[2].z); a1[2].w = fmaf(p1, v2.w, a1[2].w);
      a1[3].x = fmaf(p1, v3.x, a1[3].x); a1[3].y = fmaf(p1, v3.y, a1[3].y);
      a1[3].z = fmaf(p1, v3.z, a1[3].z); a1[3].w = fmaf(p1, v3.w, a1[3].w);
    }
  }
  const float inv0 = 1.f / l0, inv1 = 1.f / l1;
  float* o0 = AO + (long)(b*512 + g0)*128 + h*16;
  float* o1 = o0 + 128;
#pragma unroll
  for (int c = 0; c < 4; ++c) {
    float4 w0 = a0[c];
    w0.x *= inv0; w0.y *= inv0; w0.z *= inv0; w0.w *= inv0;
    *(float4*)(o0 + c*4) = w0;
    float4 w1 = a1[c];
    w1.x *= inv1; w1.y *= inv1; w1.z *= inv1; w1.w *= inv1;
    *(float4*)(o1 + c*4) = w1;
  }
}

// ---------------- gating: top-2 + expert lists (block-aggregated) ----------
__global__ __launch_bounds__(256)
void k_gate(const float* __restrict__ AO, const float* __restrict__ gw,
            float* __restrict__ ws) {
  const int tid = threadIdx.x;
  const int t = blockIdx.x*256 + tid;
  const float* x = AO + (long)t*128;
  float lg[8];
  {
    const float* pl = ws + OFF_PREFL;
#pragma unroll
    for (int e = 0; e < 8; ++e) lg[e] = pl[e];
  }
  for (int i = 0; i < 128; i += 4) {
    const float4 xv = *(const float4*)(x + i);
#pragma unroll
    for (int u = 0; u < 4; ++u) {
      const float xi = (&xv.x)[u];
      const float4 ga = *(const float4*)(gw + (i+u)*8);
      const float4 gb = *(const float4*)(gw + (i+u)*8 + 4);
      lg[0] = fmaf(xi, ga.x, lg[0]); lg[1] = fmaf(xi, ga.y, lg[1]);
      lg[2] = fmaf(xi, ga.z, lg[2]); lg[3] = fmaf(xi, ga.w, lg[3]);
      lg[4] = fmaf(xi, gb.x, lg[4]); lg[5] = fmaf(xi, gb.y, lg[5]);
      lg[6] = fmaf(xi, gb.z, lg[6]); lg[7] = fmaf(xi, gb.w, lg[7]);
    }
  }
  int i0 = 0; float v0 = lg[0];
#pragma unroll
  for (int e = 1; e < 8; ++e) if (lg[e] > v0) { v0 = lg[e]; i0 = e; }
  int i1 = -1; float v1 = -1e30f;
#pragma unroll
  for (int e = 0; e < 8; ++e) if (e != i0 && lg[e] > v1) { v1 = lg[e]; i1 = e; }
  const float e1 = __expf(v1 - v0);
  const float w0 = 1.f / (1.f + e1);
  const float w1 = 1.f - w0;
  __shared__ int bcnt[8];
  __shared__ int gbase[8];
  if (tid < 8) bcnt[tid] = 0;
  __syncthreads();
  const int p0 = atomicAdd(&bcnt[i0], 1);
  const int p1 = atomicAdd(&bcnt[i1], 1);
  __syncthreads();
  if (tid < 8) {
    int* cnt = (int*)(ws + OFF_CNT);
    gbase[tid] = (bcnt[tid] > 0) ? atomicAdd(&cnt[tid], bcnt[tid]) : 0;
  }
  __syncthreads();
  int* tokp = (int*)(ws + OFF_TOK);
  float* wgtp = ws + OFF_WGT;
  const int s0 = gbase[i0] + p0;
  tokp[i0*16384 + s0] = t;             // rank 0
  wgtp[i0*16384 + s0] = w0;
  const int s1 = gbase[i1] + p1;
  tokp[i1*16384 + s1] = t | (1 << 30); // rank 1
  wgtp[i1*16384 + s1] = w1;
}

// ---------------- MoE experts: bf16 MFMA, per (expert, 64-token chunk) -----
// GEMM1': D[f][m] = W1[f][i] . X[m][i]  -> Hs[m][f] (relu, bf16)
// GEMM2': D[o][m] = W2[o][f] . H[m][f]  -> Y[token][o]
// All LDS tiles row-major, 256B rows, XOR swizzle byte ^= (row&7)<<4.
__device__ __forceinline__ bf16x8 ld_frag(const unsigned short* base, int row, int bytecol) {
  const int addr = row*256 + (bytecol ^ ((row & 7) << 4));
  return *(const bf16x8*)((const char*)base + addr);
}

__global__ __launch_bounds__(256)
void k_moe(const float* __restrict__ AO,
           const unsigned short* __restrict__ w1b,
           const unsigned short* __restrict__ w2b,
           const float* __restrict__ eb1, const float* __restrict__ eb2,
           float* __restrict__ ws,
           float* __restrict__ Y0, float* __restrict__ Y1) {
  const int e = blockIdx.y;
  const int ce = ((const int*)(ws + OFF_CNT))[e];
  const int base = blockIdx.x * 64;
  if (base >= ce) return;
  const int nt = min(64, ce - base);

  __shared__ unsigned short Xs[64*128];    // 16KB
  __shared__ unsigned short Wts[128*128];  // 32KB (W1 chunk / W2 chunk)
  __shared__ unsigned short Hs[64*128];    // 16KB
  __shared__ float seb1[512];
  __shared__ float seb2[128];
  __shared__ int   stok[64];
  __shared__ float swgt[64];

  const int tid = threadIdx.x;
  if (tid < 64) {
    if (tid < nt) {
      stok[tid] = ((const int*)(ws + OFF_TOK))[e*16384 + base + tid];
      swgt[tid] = (ws + OFF_WGT)[e*16384 + base + tid];
    } else { stok[tid] = -1; swgt[tid] = 0.f; }
  }
  for (int i = tid; i < 512; i += 256) seb1[i] = eb1[e*512 + i];
  if (tid < 128) seb2[tid] = eb2[e*128 + tid];
  __syncthreads();

  // gather X (fp32 -> bf16), swizzled ds_write_b64
#pragma unroll
  for (int r8 = 0; r8 < 8; ++r8) {
    const int id = tid + r8*256;          // 0..2047
    const int r = id >> 5, c = id & 31;   // row, float4-chunk
    const int pk = stok[r];
    float4 xv = make_float4(0.f, 0.f, 0.f, 0.f);
    if (pk >= 0) xv = *(const float4*)(AO + (long)(pk & 0x3FFFFFFF)*128 + c*4);
    uint2 pkd;
    pkd.x = f2bf(xv.x) | (f2bf(xv.y) << 16);
    pkd.y = f2bf(xv.z) | (f2bf(xv.w) << 16);
    const int bc = (c*8) ^ ((r & 7) << 4);
    *(uint2*)((char*)Xs + r*256 + bc) = pkd;
  }

  const int w  = tid >> 6;   // wave 0..3
  const int l  = tid & 63;
  const int lq = l >> 4;     // quarter
  const int lr = l & 15;

  f32x4 yacc[2][4];
#pragma unroll
  for (int a = 0; a < 2; ++a)
#pragma unroll
    for (int m = 0; m < 4; ++m) yacc[a][m] = (f32x4){0.f, 0.f, 0.f, 0.f};

  for (int fc = 0; fc < 4; ++fc) {
    __syncthreads();   // (a) prev GEMM2 done reading Wts/Hs
    // stage W1 chunk [128 f][128 i]
    {
      const long wb = (long)(e*512 + fc*128) * 128;
#pragma unroll
      for (int s = 0; s < 8; ++s) {
        const int id = tid + s*256;           // 0..2047
        const int fr = id >> 4, c16 = id & 15;
        const uint4 v = *(const uint4*)(w1b + wb + (long)fr*128 + c16*8);
        *(uint4*)((char*)Wts + fr*256 + ((c16*16) ^ ((fr & 7) << 4))) = v;
      }
    }
    __syncthreads();   // (b) W1 staged, X staged (first iter)
    // GEMM1': hacc[fbi][mb]
    f32x4 hacc[2][4];
#pragma unroll
    for (int a = 0; a < 2; ++a)
#pragma unroll
      for (int m = 0; m < 4; ++m) hacc[a][m] = (f32x4){0.f, 0.f, 0.f, 0.f};
#pragma unroll
    for (int ks = 0; ks < 4; ++ks) {
      const int bcol = ks*64 + lq*16;
      const bf16x8 a0 = ld_frag(Wts, (2*w  )*16 + lr, bcol);
      const bf16x8 a1 = ld_frag(Wts, (2*w+1)*16 + lr, bcol);
      const bf16x8 b0 = ld_frag(Xs,  0*16 + lr, bcol);
      const bf16x8 b1 = ld_frag(Xs,  1*16 + lr, bcol);
      const bf16x8 b2 = ld_frag(Xs,  2*16 + lr, bcol);
      const bf16x8 b3 = ld_frag(Xs,  3*16 + lr, bcol);
      hacc[0][0] = __builtin_amdgcn_mfma_f32_16x16x32_bf16(a0, b0, hacc[0][0], 0, 0, 0);
      hacc[0][1] = __builtin_amdgcn_mfma_f32_16x16x32_bf16(a0, b1, hacc[0][1], 0, 0, 0);
      hacc[0][2] = __builtin_amdgcn_mfma_f32_16x16x32_bf16(a0, b2, hacc[0][2], 0, 0, 0);
      hacc[0][3] = __builtin_amdgcn_mfma_f32_16x16x32_bf16(a0, b3, hacc[0][3], 0, 0, 0);
      hacc[1][0] = __builtin_amdgcn_mfma_f32_16x16x32_bf16(a1, b0, hacc[1][0], 0, 0, 0);
      hacc[1][1] = __builtin_amdgcn_mfma_f32_16x16x32_bf16(a1, b1, hacc[1][1], 0, 0, 0);
      hacc[1][2] = __builtin_amdgcn_mfma_f32_16x16x32_bf16(a1, b2, hacc[1][2], 0, 0, 0);
      hacc[1][3] = __builtin_amdgcn_mfma_f32_16x16x32_bf16(a1, b3, hacc[1][3], 0, 0, 0);
    }
    __syncthreads();   // (c) all waves done reading Wts
    // write Hs[m][f] (bias+relu+bf16), and stage W2 chunk into Wts
#pragma unroll
    for (int fbi = 0; fbi < 2; ++fbi) {
      const int fb = (2*w + fbi)*16 + lq*4;   // f local base (j=0..3)
      const float4 bia = *(const float4*)&seb1[fc*128 + fb];
#pragma unroll
      for (int mb = 0; mb < 4; ++mb) {
        const int m = mb*16 + lr;
        const float h0 = fmaxf(hacc[fbi][mb][0] + bia.x, 0.f);
        const float h1 = fmaxf(hacc[fbi][mb][1] + bia.y, 0.f);
        const float h2 = fmaxf(hacc[fbi][mb][2] + bia.z, 0.f);
        const float h3 = fmaxf(hacc[fbi][mb][3] + bia.w, 0.f);
        uint2 p;
        p.x = f2bf(h0) | (f2bf(h1) << 16);
        p.y = f2bf(h2) | (f2bf(h3) << 16);
        const int bc = (fb*2) ^ ((m & 7) << 4);
        *(uint2*)((char*)Hs + m*256 + bc) = p;
      }
    }
    {
      const long wb = (long)(e*128) * 512 + fc*128;
#pragma unroll
      for (int s = 0; s < 8; ++s) {
        const int id = tid + s*256;
        const int orr = id >> 4, c16 = id & 15;
        const uint4 v = *(const uint4*)(w2b + wb + (long)orr*512 + c16*8);
        *(uint4*)((char*)Wts + orr*256 + ((c16*16) ^ ((orr & 7) << 4))) = v;
      }
    }
    __syncthreads();   // (d) Hs + W2 ready
    // GEMM2': yacc[obi][mb] += W2 . H
#pragma unroll
    for (int ks = 0; ks < 4; ++ks) {
      const int bcol = ks*64 + lq*16;
      const bf16x8 a0 = ld_frag(Wts, (2*w  )*16 + lr, bcol);
      const bf16x8 a1 = ld_frag(Wts, (2*w+1)*16 + lr, bcol);
      const bf16x8 b0 = ld_frag(Hs,  0*16 + lr, bcol);
      const bf16x8 b1 = ld_frag(Hs,  1*16 + lr, bcol);
      const bf16x8 b2 = ld_frag(Hs,  2*16 + lr, bcol);
      const bf16x8 b3 = ld_frag(Hs,  3*16 + lr, bcol);
      yacc[0][0] = __builtin_amdgcn_mfma_f32_16x16x32_bf16(a0, b0, yacc[0][0], 0, 0, 0);
      yacc[0][1] = __builtin_amdgcn_mfma_f32_16x16x32_bf16(a0, b1, yacc[0][1], 0, 0, 0);
      yacc[0][2] = __builtin_amdgcn_mfma_f32_16x16x32_bf16(a0, b2, yacc[0][2], 0, 0, 0);
      yacc[0][3] = __builtin_amdgcn_mfma_f32_16x16x32_bf16(a0, b3, yacc[0][3], 0, 0, 0);
      yacc[1][0] = __builtin_amdgcn_mfma_f32_16x16x32_bf16(a1, b0, yacc[1][0], 0, 0, 0);
      yacc[1][1] = __builtin_amdgcn_mfma_f32_16x16x32_bf16(a1, b1, yacc[1][1], 0, 0, 0);
      yacc[1][2] = __builtin_amdgcn_mfma_f32_16x16x32_bf16(a1, b2, yacc[1][2], 0, 0, 0);
      yacc[1][3] = __builtin_amdgcn_mfma_f32_16x16x32_bf16(a1, b3, yacc[1][3], 0, 0, 0);
    }
  }
  // epilogue: Y[token][o] = (y + b2) * wgt, float4 stores
#pragma unroll
  for (int obi = 0; obi < 2; ++obi) {
    const int ob = (2*w + obi)*16 + lq*4;
    const float4 b2 = *(const float4*)&seb2[ob];
#pragma unroll
    for (int mb = 0; mb < 4; ++mb) {
      const int tl = mb*16 + lr;
      if (tl < nt) {
        const int pk = stok[tl];
        const int tk = pk & 0x3FFFFFFF;
        const float wgt = swgt[tl];
        float* Yp = ((pk >> 30) ? Y1 : Y0) + (long)tk*128 + ob;
        float4 o;
        o.x = (yacc[obi][mb][0] + b2.x) * wgt;
        o.y = (yacc[obi][mb][1] + b2.y) * wgt;
        o.z = (yacc[obi][mb][2] + b2.z) * wgt;
        o.w = (yacc[obi][mb][3] + b2.w) * wgt;
        *(float4*)Yp = o;
      }
    }
  }
}

// ---------------- final: probs = softmax(10*tanh(sc/sqrt(128)) + mask) -----
__global__ __launch_bounds__(256)
void k_softmax(float* __restrict__ out, const float* __restrict__ mask) {
  const long row = (long)blockIdx.x*4 + (threadIdx.x >> 6);
  const int l = threadIdx.x & 63;
  float4* r = (float4*)(out + row*512);
  const float4* mr = (const float4*)(mask + row*512);
  const float4 x0 = r[l], x1 = r[64 + l];
  const float4 m0 = mr[l], m1 = mr[64 + l];
  float li[8];
  li[0] = 10.f*tanhf(x0.x*(1.f/11.313708498984761f)) + m0.x;
  li[1] = 10.f*tanhf(x0.y*(1.f/11.313708498984761f)) + m0.y;
  li[2] = 10.f*tanhf(x0.z*(1.f/11.313708498984761f)) + m0.z;
  li[3] = 10.f*tanhf(x0.w*(1.f/11.313708498984761f)) + m0.w;
  li[4] = 10.f*tanhf(x1.x*(1.f/11.313708498984761f)) + m1.x;
  li[5] = 10.f*tanhf(x1.y*(1.f/11.313708498984761f)) + m1.y;
  li[6] = 10.f*tanhf(x1.z*(1.f/11.313708498984761f)) + m1.z;
  li[7] = 10.f*tanhf(x1.w*(1.f/11.313708498984761f)) + m1.w;
  float mx = li[0];
#pragma unroll
  for (int u = 1; u < 8; ++u) mx = fmaxf(mx, li[u]);
#pragma unroll
  for (int o = 1; o < 64; o <<= 1) mx = fmaxf(mx, __shfl_xor(mx, o));
  float ev[8], s = 0.f;
#pragma unroll
  for (int u = 0; u < 8; ++u) { ev[u] = __expf(li[u] - mx); s += ev[u]; }
#pragma unroll
  for (int o = 1; o < 64; o <<= 1) s += __shfl_xor(s, o);
  const float inv = 1.f / s;
  float4 y0, y1;
  y0.x = ev[0]*inv; y0.y = ev[1]*inv; y0.z = ev[2]*inv; y0.w = ev[3]*inv;
  y1.x = ev[4]*inv; y1.y = ev[5]*inv; y1.z = ev[6]*inv; y1.w = ev[7]*inv;
  r[l] = y0; r[64 + l] = y1;
}

// ---------------------------------------------------------------------------
extern "C" void kernel_launch(void* const* d_in, const int* in_sizes, int n_in,
                              void* d_out, int out_size, void* d_ws, size_t ws_size,
                              hipStream_t stream) {
  (void)in_sizes; (void)n_in; (void)out_size; (void)ws_size;
  const float* pref  = (const float*)d_in[0];
  const float* graph = (const float*)d_in[1];
  const float* cap   = (const float*)d_in[2];
  const float* enc   = (const float*)d_in[3];
  const float* mask  = (const float*)d_in[4];
  const float* fc1w  = (const float*)d_in[5];
  const float* fc1b  = (const float*)d_in[6];
  const float* fc2w  = (const float*)d_in[7];
  const float* fc2b  = (const float*)d_in[8];
  const float* fc3w  = (const float*)d_in[9];
  const float* fc3b  = (const float*)d_in[10];
  const float* hWq   = (const float*)d_in[11];
  const float* hWk   = (const float*)d_in[12];
  const float* hWv   = (const float*)d_in[13];
  const float* hWc   = (const float*)d_in[14];
  const float* gw    = (const float*)d_in[15];
  const float* gpw   = (const float*)d_in[16];
  const float* ew1   = (const float*)d_in[17];
  const float* eb1   = (const float*)d_in[18];
  const float* ew2   = (const float*)d_in[19];
  const float* eb2   = (const float*)d_in[20];
  float* ws  = (float*)d_ws;
  float* out = (float*)d_out;
  // d_out scratch ranges (dead before sc GEMM overwrites all of d_out):
  float* Kbuf = out;                                   // [0, 2M)
  float* Vbuf = out + 2097152;                         // [2M, 4M)
  float* Y0   = out;                                   // reuse after attention
  float* Y1   = out + 2097152;
  unsigned short* ew1b = (unsigned short*)(out + 4194304);  // 1MB bf16
  unsigned short* ew2b = (unsigned short*)(out + 4456448);  // 1MB bf16

  hipMemsetAsync((char*)d_ws + OFF_CNT*sizeof(float), 0, 8*sizeof(int), stream);
  k_cvt<<<1024, 256, 0, stream>>>(ew1, ew2, ew1b, ew2b);
  k_hyper<<<1, 256, 0, stream>>>(pref, fc1w, fc1b, fc2w, fc2b, fc3w, fc3b, gpw, ws);
  k_hyperw<<<257, 256, 0, stream>>>(hWq, hWk, hWv, hWc, ws);
  k_qbase<<<32, 128, 0, stream>>>(graph, ws);
  k_gemm<0><<<dim3(128, 2), 256, 0, stream>>>(enc, nullptr, ws + OFF_WK, ws + OFF_WV, Kbuf, Vbuf);
  k_attn<<<256, 256, 0, stream>>>(Kbuf, Vbuf, ws, cap, mask, ws + OFF_AO);
  k_gate<<<64, 256, 0, stream>>>(ws + OFF_AO, gw, ws);
  k_moe<<<dim3(256, 8), 256, 0, stream>>>(ws + OFF_AO, ew1b, ew2b, eb1, eb2, ws, Y0, Y1);
  k_gemm<1><<<dim3(128, 1), 256, 0, stream>>>(Y0, Y1, ws + OFF_WC, nullptr, ws + OFF_MH, nullptr);
  k_gemm<2><<<dim3(4, 4, 32), 256, 0, stream>>>(ws + OFF_MH, nullptr, enc, nullptr, out, nullptr);
  k_softmax<<<4096, 256, 0, stream>>>(out, mask);
}

// Round 4
// 203.186 us; speedup vs baseline: 4.4666x; 1.4641x over previous
//
#include <hip/hip_runtime.h>

// ---------------------------------------------------------------------------
// KP_Decoder: hypernet -> (k,v,q) -> attention -> top2 MoE -> combine softmax
// B=32 G=512 N=512 EMB=128 H=8 DK=16 E=8 FH=512 K=2
// R2: k_gate block-aggregated routing.
// R3: k_moe bf16 MFMA (16x16x32), XOR-swizzled LDS.
// R4: k_attn bf16 MFMA flash attention (S^T orientation), XCD-aware mapping.
// ---------------------------------------------------------------------------

typedef __attribute__((ext_vector_type(8))) __bf16 bf16x8;
typedef __attribute__((ext_vector_type(4))) float f32x4;

// ws layout (float offsets)
static constexpr long OFF_MID   = 0;        // 8
static constexpr long OFF_PREFL = 8;        // 8
static constexpr long OFF_WQ    = 64;       // 128x129 = 16512
static constexpr long OFF_WK    = 16576;    // 128x128
static constexpr long OFF_WV    = 32960;    // 128x128
static constexpr long OFF_WC    = 49344;    // 128x128
static constexpr long OFF_QB    = 65728;    // 32x128 qbase
static constexpr long OFF_CNT   = 69824;    // 8 ints
static constexpr long OFF_TOK   = 69888;    // 8*16384 ints
static constexpr long OFF_WGT   = 200960;   // 8*16384 floats
static constexpr long OFF_AO    = 332288;   // 16384x128 attention out
static constexpr long OFF_MH    = 2429440;  // 16384x128 mh
// total = 4,526,592 floats = 18.1 MB

__device__ __forceinline__ unsigned f2bf(float x) {
  union { float f; unsigned u; } v; v.f = x;
  return ((v.u + 0x7FFFu + ((v.u >> 16) & 1u)) >> 16) & 0xFFFFu;
}

// ---------------- hypernet: mid + pref gate logits -------------------------
__global__ __launch_bounds__(256)
void k_hyper(const float* __restrict__ pref, const float* __restrict__ fc1w,
             const float* __restrict__ fc1b, const float* __restrict__ fc2w,
             const float* __restrict__ fc2b, const float* __restrict__ fc3w,
             const float* __restrict__ fc3b, const float* __restrict__ gpw,
             float* __restrict__ ws) {
  __shared__ float h1[256];
  __shared__ float h2[256];
  __shared__ float mid[8];
  const int t = threadIdx.x;
  const float p0 = pref[0], p1 = pref[1];
  h1[t] = fc1w[2*t]*p0 + fc1w[2*t+1]*p1 + fc1b[t];
  __syncthreads();
  float s = 0.f;
  for (int j = 0; j < 256; ++j) s = fmaf(fc2w[t*256+j], h1[j], s);
  h2[t] = s + fc2b[t];
  __syncthreads();
  if (t < 8) {
    float s2 = 0.f;
    for (int j = 0; j < 256; ++j) s2 = fmaf(fc3w[t*256+j], h2[j], s2);
    mid[t] = s2 + fc3b[t];
    ws[OFF_MID + t] = mid[t];
  }
  __syncthreads();
  if (t < 8) {
    float s3 = 0.f;
    for (int i = 0; i < 8; ++i) s3 = fmaf(mid[i], gpw[i*8 + t], s3);
    ws[OFF_PREFL + t] = s3;
  }
}

// ---------------- hypernet heads: Wq/Wk/Wv/Wc ------------------------------
__global__ __launch_bounds__(256)
void k_hyperw(const float* __restrict__ hWq, const float* __restrict__ hWk,
              const float* __restrict__ hWv, const float* __restrict__ hWc,
              float* __restrict__ ws) {
  const int i = blockIdx.x*256 + threadIdx.x;
  const float m0 = ws[0], m1 = ws[1], m2 = ws[2], m3 = ws[3],
              m4 = ws[4], m5 = ws[5], m6 = ws[6], m7 = ws[7];
  if (i < 16512) {
    ws[OFF_WQ + i] = hWq[2*i]*m0 + hWq[2*i+1]*m1;
  } else if (i < 32896) {
    const int j = i - 16512;
    ws[OFF_WK + j] = hWk[2*j]*m2 + hWk[2*j+1]*m3;
  } else if (i < 49280) {
    const int j = i - 32896;
    ws[OFF_WV + j] = hWv[2*j]*m4 + hWv[2*j+1]*m5;
  } else if (i < 65664) {
    const int j = i - 49280;
    ws[OFF_WC + j] = hWc[2*j]*m6 + hWc[2*j+1]*m7;
  }
}

// ---------------- weight bf16 conversion for MoE ---------------------------
__global__ __launch_bounds__(256)
void k_cvt(const float* __restrict__ ew1, const float* __restrict__ ew2,
           unsigned short* __restrict__ w1b, unsigned short* __restrict__ w2b) {
  const int i = blockIdx.x*256 + threadIdx.x;
  const int h = 131072;
  const float4 v = (i < h) ? *(const float4*)(ew1 + (long)i*4)
                           : *(const float4*)(ew2 + (long)(i-h)*4);
  uint2 p;
  p.x = f2bf(v.x) | (f2bf(v.y) << 16);
  p.y = f2bf(v.z) | (f2bf(v.w) << 16);
  unsigned short* dst = (i < h) ? (w1b + (long)i*4) : (w2b + (long)(i-h)*4);
  *(uint2*)dst = p;
}

// ---------------- qbase[b][o] = graph[b] . Wq[o,0:128] ---------------------
__global__ __launch_bounds__(128)
void k_qbase(const float* __restrict__ graph, float* __restrict__ ws) {
  __shared__ float g[128];
  const int b = blockIdx.x, t = threadIdx.x;
  g[t] = graph[b*128 + t];
  __syncthreads();
  const float* wq = ws + OFF_WQ + (long)t*129;
  float s = 0.f;
  for (int i = 0; i < 128; ++i) s = fmaf(g[i], wq[i], s);
  ws[OFF_QB + b*128 + t] = s;
}

// ---------------- generic fp32 GEMM, C = A @ B^T, K=128 --------------------
template <int MODE>
__global__ __launch_bounds__(256)
void k_gemm(const float* __restrict__ A, const float* __restrict__ A2,
            const float* __restrict__ B0, const float* __restrict__ B1,
            float* __restrict__ C0, float* __restrict__ C1) {
  constexpr int LDT = 132;
  __shared__ float As[32][LDT];
  __shared__ float Bs[32][LDT];
  const int tid = threadIdx.x;
  const int bx = blockIdx.x;
  const float* Ap;
  const float* Ap2 = nullptr;
  const float* Bp;
  float* Cp;
  int ldc;
  if constexpr (MODE == 0) {
    Ap = A + (long)bx*128*128;
    Bp = blockIdx.y ? B1 : B0;
    Cp = (blockIdx.y ? C1 : C0) + (long)bx*128*128;
    ldc = 128;
  } else if constexpr (MODE == 1) {
    Ap  = A  + (long)bx*128*128;
    Ap2 = A2 + (long)bx*128*128;
    Bp = B0;
    Cp = C0 + (long)bx*128*128;
    ldc = 128;
  } else {
    const long zo = (long)blockIdx.z*512*128;
    Ap = A + zo + (long)bx*128*128;
    Bp = B0 + zo + (long)blockIdx.y*128*128;
    Cp = C0 + (long)blockIdx.z*512*512 + (long)bx*128*512 + (long)blockIdx.y*128;
    ldc = 512;
  }
  float acc[8][8];
#pragma unroll
  for (int i = 0; i < 8; ++i)
#pragma unroll
    for (int j = 0; j < 8; ++j) acc[i][j] = 0.f;
  const int tm = (tid >> 4) * 8;
  const int tn = (tid & 15) * 8;
  for (int kt = 0; kt < 4; ++kt) {
    __syncthreads();
#pragma unroll
    for (int r = 0; r < 4; ++r) {
      const int id = tid + r*256;
      const int m = id >> 3, kq = id & 7;
      float4 av = *(const float4*)(Ap + (long)m*128 + kt*32 + kq*4);
      if constexpr (MODE == 1) {
        const float4 a2 = *(const float4*)(Ap2 + (long)m*128 + kt*32 + kq*4);
        av.x += a2.x; av.y += a2.y; av.z += a2.z; av.w += a2.w;
      }
      As[kq*4+0][m] = av.x; As[kq*4+1][m] = av.y;
      As[kq*4+2][m] = av.z; As[kq*4+3][m] = av.w;
      const float4 bv = *(const float4*)(Bp + (long)m*128 + kt*32 + kq*4);
      Bs[kq*4+0][m] = bv.x; Bs[kq*4+1][m] = bv.y;
      Bs[kq*4+2][m] = bv.z; Bs[kq*4+3][m] = bv.w;
    }
    __syncthreads();
#pragma unroll
    for (int kk = 0; kk < 32; ++kk) {
      float a[8], b[8];
      *(float4*)&a[0] = *(const float4*)&As[kk][tm];
      *(float4*)&a[4] = *(const float4*)&As[kk][tm+4];
      *(float4*)&b[0] = *(const float4*)&Bs[kk][tn];
      *(float4*)&b[4] = *(const float4*)&Bs[kk][tn+4];
#pragma unroll
      for (int i = 0; i < 8; ++i)
#pragma unroll
        for (int j = 0; j < 8; ++j) acc[i][j] = fmaf(a[i], b[j], acc[i][j]);
    }
  }
#pragma unroll
  for (int i = 0; i < 8; ++i) {
    const float4 c0 = {acc[i][0], acc[i][1], acc[i][2], acc[i][3]};
    const float4 c1 = {acc[i][4], acc[i][5], acc[i][6], acc[i][7]};
    *(float4*)(Cp + (long)(tm+i)*ldc + tn)     = c0;
    *(float4*)(Cp + (long)(tm+i)*ldc + tn + 4) = c1;
  }
}

// ---------------- MFMA flash attention per (b,h) ---------------------------
// S^T = mfma(K-frag, Q-frag): D[n][q], DK padded 16->32 with zero frags.
// Online softmax in S^T layout: per lane ONE q-row (q = lane&15), 4 consec n.
// PV: out^T[d][q] = mfma(Vt-frag, P-frag); Vt = V transposed in LDS.
__global__ __launch_bounds__(256)
void k_attn(const float* __restrict__ Kb, const float* __restrict__ Vb,
            const float* __restrict__ ws, const float* __restrict__ cap,
            const float* __restrict__ mask, float* __restrict__ AO) {
  const int bid = blockIdx.x;
  const int b = bid & 31, h = bid >> 5;   // XCD-aware: L2 keeps mask[b] for 4 b's
  __shared__ unsigned short Kbf[512*24];  // [n][24] pitch, 24.0 KB
  __shared__ unsigned short Vt[16*536];   // [d][536] pitch, 16.75 KB
  __shared__ unsigned short Ps[4*16*136]; // per-wave [16 q][136], 17 KB
  const int tid = threadIdx.x;
  const float* Kp = Kb + (long)b*512*128 + h*16;
  const float* Vp = Vb + (long)b*512*128 + h*16;
#pragma unroll
  for (int it = 0; it < 8; ++it) {
    const int i = tid + it*256;
    const int n = i >> 2, c = i & 3;
    const float4 kv = *(const float4*)(Kp + (long)n*128 + c*4);
    const float4 vv = *(const float4*)(Vp + (long)n*128 + c*4);
    uint2 kp;
    kp.x = f2bf(kv.x) | (f2bf(kv.y) << 16);
    kp.y = f2bf(kv.z) | (f2bf(kv.w) << 16);
    *(uint2*)(Kbf + n*24 + c*4) = kp;
    Vt[(c*4+0)*536 + n] = (unsigned short)f2bf(vv.x);
    Vt[(c*4+1)*536 + n] = (unsigned short)f2bf(vv.y);
    Vt[(c*4+2)*536 + n] = (unsigned short)f2bf(vv.z);
    Vt[(c*4+3)*536 + n] = (unsigned short)f2bf(vv.w);
  }
  const int w = tid >> 6, l = tid & 63;
  const int lq = l >> 4, lr = l & 15;
  // per-lane Q constants for dk = lq*8+j (valid lq<2)
  float qb8[8], wl8[8];
  if (lq < 2) {
    const float* qbp = ws + OFF_QB + b*128 + h*16 + lq*8;
    const float* wqp = ws + OFF_WQ;
#pragma unroll
    for (int j = 0; j < 8; ++j) {
      qb8[j] = qbp[j];
      wl8[j] = wqp[(h*16 + lq*8 + j)*129 + 128];
    }
  }
  unsigned short* Pw = Ps + w*16*136;
  __syncthreads();
  const float SC = 0.25f;
  const int wrow0 = w*128;
  for (int qb = 0; qb < 8; ++qb) {
    const int grow = wrow0 + qb*16 + lr;   // this lane's q-row
    // B-frag: Q[q=lr][dk]
    bf16x8 qf;
    {
      union { uint4 u; bf16x8 v; } cv;
      cv.u = make_uint4(0u, 0u, 0u, 0u);
      if (lq < 2) {
        const float cp = cap[b*512 + grow];
        float qv[8];
#pragma unroll
        for (int j = 0; j < 8; ++j) qv[j] = (qb8[j] + cp*wl8[j]) * SC;
        cv.u.x = f2bf(qv[0]) | (f2bf(qv[1]) << 16);
        cv.u.y = f2bf(qv[2]) | (f2bf(qv[3]) << 16);
        cv.u.z = f2bf(qv[4]) | (f2bf(qv[5]) << 16);
        cv.u.w = f2bf(qv[6]) | (f2bf(qv[7]) << 16);
      }
      qf = cv.v;
    }
    float m = -3.0e38f, lsum = 0.f;
    f32x4 oacc = {0.f, 0.f, 0.f, 0.f};
    const float* mrow = mask + ((long)(b*512 + grow))*512 + lq*4;
    for (int ch = 0; ch < 4; ++ch) {
      const int n0 = ch*128;
      f32x4 s[8];
#pragma unroll
      for (int nb = 0; nb < 8; ++nb) {
        bf16x8 kf;
        {
          union { uint4 u; bf16x8 v; } cv;
          cv.u = make_uint4(0u, 0u, 0u, 0u);
          if (lq < 2) cv.u = *(const uint4*)(Kbf + (n0 + nb*16 + lr)*24 + lq*8);
          kf = cv.v;
        }
        s[nb] = __builtin_amdgcn_mfma_f32_16x16x32_bf16(
            kf, qf, (f32x4){0.f, 0.f, 0.f, 0.f}, 0, 0, 0);
        const float4 mk = *(const float4*)(mrow + n0 + nb*16);
        s[nb][0] += mk.x; s[nb][1] += mk.y; s[nb][2] += mk.z; s[nb][3] += mk.w;
      }
      // chunk max (in-lane 32 values -> cross lq groups)
      f32x4 mx = s[0];
#pragma unroll
      for (int nb = 1; nb < 8; ++nb) {
        mx[0] = fmaxf(mx[0], s[nb][0]); mx[1] = fmaxf(mx[1], s[nb][1]);
        mx[2] = fmaxf(mx[2], s[nb][2]); mx[3] = fmaxf(mx[3], s[nb][3]);
      }
      float cm = fmaxf(fmaxf(mx[0], mx[1]), fmaxf(mx[2], mx[3]));
      cm = fmaxf(cm, __shfl_xor(cm, 16));
      cm = fmaxf(cm, __shfl_xor(cm, 32));
      const float nm = fmaxf(m, cm);
      const float rs = __expf(m - nm);
      lsum *= rs;
      oacc[0] *= rs; oacc[1] *= rs; oacc[2] *= rs; oacc[3] *= rs;
      m = nm;
      float ls = 0.f;
#pragma unroll
      for (int nb = 0; nb < 8; ++nb) {
        const float p0 = __expf(s[nb][0] - m);
        const float p1 = __expf(s[nb][1] - m);
        const float p2 = __expf(s[nb][2] - m);
        const float p3 = __expf(s[nb][3] - m);
        ls += (p0 + p1) + (p2 + p3);
        uint2 pp;
        asm("v_cvt_pk_bf16_f32 %0, %1, %2" : "=v"(pp.x) : "v"(p0), "v"(p1));
        asm("v_cvt_pk_bf16_f32 %0, %1, %2" : "=v"(pp.y) : "v"(p2), "v"(p3));
        *(uint2*)(Pw + lr*136 + nb*16 + lq*4) = pp;
      }
      lsum += ls;
      // PV: oacc[d][q] += Vt . P  (contract 128 n in 4 K=32 steps)
#pragma unroll
      for (int ks = 0; ks < 4; ++ks) {
        const bf16x8 va = *(const bf16x8*)(Vt + lr*536 + n0 + ks*32 + lq*8);
        const bf16x8 pb = *(const bf16x8*)(Pw + lr*136 + ks*32 + lq*8);
        oacc = __builtin_amdgcn_mfma_f32_16x16x32_bf16(va, pb, oacc, 0, 0, 0);
      }
    }
    lsum += __shfl_xor(lsum, 16);
    lsum += __shfl_xor(lsum, 32);
    const float inv = 1.f / lsum;
    float4 o;
    o.x = oacc[0]*inv; o.y = oacc[1]*inv; o.z = oacc[2]*inv; o.w = oacc[3]*inv;
    *(float4*)(AO + (long)(b*512 + grow)*128 + h*16 + lq*4) = o;
  }
}

// ---------------- gating: top-2 + expert lists (block-aggregated) ----------
__global__ __launch_bounds__(256)
void k_gate(const float* __restrict__ AO, const float* __restrict__ gw,
            float* __restrict__ ws) {
  const int tid = threadIdx.x;
  const int t = blockIdx.x*256 + tid;
  const float* x = AO + (long)t*128;
  float lg[8];
  {
    const float* pl = ws + OFF_PREFL;
#pragma unroll
    for (int e = 0; e < 8; ++e) lg[e] = pl[e];
  }
  for (int i = 0; i < 128; i += 4) {
    const float4 xv = *(const float4*)(x + i);
#pragma unroll
    for (int u = 0; u < 4; ++u) {
      const float xi = (&xv.x)[u];
      const float4 ga = *(const float4*)(gw + (i+u)*8);
      const float4 gb = *(const float4*)(gw + (i+u)*8 + 4);
      lg[0] = fmaf(xi, ga.x, lg[0]); lg[1] = fmaf(xi, ga.y, lg[1]);
      lg[2] = fmaf(xi, ga.z, lg[2]); lg[3] = fmaf(xi, ga.w, lg[3]);
      lg[4] = fmaf(xi, gb.x, lg[4]); lg[5] = fmaf(xi, gb.y, lg[5]);
      lg[6] = fmaf(xi, gb.z, lg[6]); lg[7] = fmaf(xi, gb.w, lg[7]);
    }
  }
  int i0 = 0; float v0 = lg[0];
#pragma unroll
  for (int e = 1; e < 8; ++e) if (lg[e] > v0) { v0 = lg[e]; i0 = e; }
  int i1 = -1; float v1 = -1e30f;
#pragma unroll
  for (int e = 0; e < 8; ++e) if (e != i0 && lg[e] > v1) { v1 = lg[e]; i1 = e; }
  const float e1 = __expf(v1 - v0);
  const float w0 = 1.f / (1.f + e1);
  const float w1 = 1.f - w0;
  __shared__ int bcnt[8];
  __shared__ int gbase[8];
  if (tid < 8) bcnt[tid] = 0;
  __syncthreads();
  const int p0 = atomicAdd(&bcnt[i0], 1);
  const int p1 = atomicAdd(&bcnt[i1], 1);
  __syncthreads();
  if (tid < 8) {
    int* cnt = (int*)(ws + OFF_CNT);
    gbase[tid] = (bcnt[tid] > 0) ? atomicAdd(&cnt[tid], bcnt[tid]) : 0;
  }
  __syncthreads();
  int* tokp = (int*)(ws + OFF_TOK);
  float* wgtp = ws + OFF_WGT;
  const int s0 = gbase[i0] + p0;
  tokp[i0*16384 + s0] = t;             // rank 0
  wgtp[i0*16384 + s0] = w0;
  const int s1 = gbase[i1] + p1;
  tokp[i1*16384 + s1] = t | (1 << 30); // rank 1
  wgtp[i1*16384 + s1] = w1;
}

// ---------------- MoE experts: bf16 MFMA, per (expert, 64-token chunk) -----
__device__ __forceinline__ bf16x8 ld_frag(const unsigned short* base, int row, int bytecol) {
  const int addr = row*256 + (bytecol ^ ((row & 7) << 4));
  return *(const bf16x8*)((const char*)base + addr);
}

__global__ __launch_bounds__(256)
void k_moe(const float* __restrict__ AO,
           const unsigned short* __restrict__ w1b,
           const unsigned short* __restrict__ w2b,
           const float* __restrict__ eb1, const float* __restrict__ eb2,
           float* __restrict__ ws,
           float* __restrict__ Y0, float* __restrict__ Y1) {
  const int e = blockIdx.y;
  const int ce = ((const int*)(ws + OFF_CNT))[e];
  const int base = blockIdx.x * 64;
  if (base >= ce) return;
  const int nt = min(64, ce - base);

  __shared__ unsigned short Xs[64*128];
  __shared__ unsigned short Wts[128*128];
  __shared__ unsigned short Hs[64*128];
  __shared__ float seb1[512];
  __shared__ float seb2[128];
  __shared__ int   stok[64];
  __shared__ float swgt[64];

  const int tid = threadIdx.x;
  if (tid < 64) {
    if (tid < nt) {
      stok[tid] = ((const int*)(ws + OFF_TOK))[e*16384 + base + tid];
      swgt[tid] = (ws + OFF_WGT)[e*16384 + base + tid];
    } else { stok[tid] = -1; swgt[tid] = 0.f; }
  }
  for (int i = tid; i < 512; i += 256) seb1[i] = eb1[e*512 + i];
  if (tid < 128) seb2[tid] = eb2[e*128 + tid];
  __syncthreads();

#pragma unroll
  for (int r8 = 0; r8 < 8; ++r8) {
    const int id = tid + r8*256;
    const int r = id >> 5, c = id & 31;
    const int pk = stok[r];
    float4 xv = make_float4(0.f, 0.f, 0.f, 0.f);
    if (pk >= 0) xv = *(const float4*)(AO + (long)(pk & 0x3FFFFFFF)*128 + c*4);
    uint2 pkd;
    pkd.x = f2bf(xv.x) | (f2bf(xv.y) << 16);
    pkd.y = f2bf(xv.z) | (f2bf(xv.w) << 16);
    const int bc = (c*8) ^ ((r & 7) << 4);
    *(uint2*)((char*)Xs + r*256 + bc) = pkd;
  }

  const int w  = tid >> 6;
  const int l  = tid & 63;
  const int lq = l >> 4;
  const int lr = l & 15;

  f32x4 yacc[2][4];
#pragma unroll
  for (int a = 0; a < 2; ++a)
#pragma unroll
    for (int m = 0; m < 4; ++m) yacc[a][m] = (f32x4){0.f, 0.f, 0.f, 0.f};

  for (int fc = 0; fc < 4; ++fc) {
    __syncthreads();
    {
      const long wb = (long)(e*512 + fc*128) * 128;
#pragma unroll
      for (int s = 0; s < 8; ++s) {
        const int id = tid + s*256;
        const int fr = id >> 4, c16 = id & 15;
        const uint4 v = *(const uint4*)(w1b + wb + (long)fr*128 + c16*8);
        *(uint4*)((char*)Wts + fr*256 + ((c16*16) ^ ((fr & 7) << 4))) = v;
      }
    }
    __syncthreads();
    f32x4 hacc[2][4];
#pragma unroll
    for (int a = 0; a < 2; ++a)
#pragma unroll
      for (int m = 0; m < 4; ++m) hacc[a][m] = (f32x4){0.f, 0.f, 0.f, 0.f};
#pragma unroll
    for (int ks = 0; ks < 4; ++ks) {
      const int bcol = ks*64 + lq*16;
      const bf16x8 a0 = ld_frag(Wts, (2*w  )*16 + lr, bcol);
      const bf16x8 a1 = ld_frag(Wts, (2*w+1)*16 + lr, bcol);
      const bf16x8 b0 = ld_frag(Xs,  0*16 + lr, bcol);
      const bf16x8 b1 = ld_frag(Xs,  1*16 + lr, bcol);
      const bf16x8 b2 = ld_frag(Xs,  2*16 + lr, bcol);
      const bf16x8 b3 = ld_frag(Xs,  3*16 + lr, bcol);
      hacc[0][0] = __builtin_amdgcn_mfma_f32_16x16x32_bf16(a0, b0, hacc[0][0], 0, 0, 0);
      hacc[0][1] = __builtin_amdgcn_mfma_f32_16x16x32_bf16(a0, b1, hacc[0][1], 0, 0, 0);
      hacc[0][2] = __builtin_amdgcn_mfma_f32_16x16x32_bf16(a0, b2, hacc[0][2], 0, 0, 0);
      hacc[0][3] = __builtin_amdgcn_mfma_f32_16x16x32_bf16(a0, b3, hacc[0][3], 0, 0, 0);
      hacc[1][0] = __builtin_amdgcn_mfma_f32_16x16x32_bf16(a1, b0, hacc[1][0], 0, 0, 0);
      hacc[1][1] = __builtin_amdgcn_mfma_f32_16x16x32_bf16(a1, b1, hacc[1][1], 0, 0, 0);
      hacc[1][2] = __builtin_amdgcn_mfma_f32_16x16x32_bf16(a1, b2, hacc[1][2], 0, 0, 0);
      hacc[1][3] = __builtin_amdgcn_mfma_f32_16x16x32_bf16(a1, b3, hacc[1][3], 0, 0, 0);
    }
    __syncthreads();
#pragma unroll
    for (int fbi = 0; fbi < 2; ++fbi) {
      const int fb = (2*w + fbi)*16 + lq*4;
      const float4 bia = *(const float4*)&seb1[fc*128 + fb];
#pragma unroll
      for (int mb = 0; mb < 4; ++mb) {
        const int m = mb*16 + lr;
        const float h0 = fmaxf(hacc[fbi][mb][0] + bia.x, 0.f);
        const float h1 = fmaxf(hacc[fbi][mb][1] + bia.y, 0.f);
        const float h2 = fmaxf(hacc[fbi][mb][2] + bia.z, 0.f);
        const float h3 = fmaxf(hacc[fbi][mb][3] + bia.w, 0.f);
        uint2 p;
        p.x = f2bf(h0) | (f2bf(h1) << 16);
        p.y = f2bf(h2) | (f2bf(h3) << 16);
        const int bc = (fb*2) ^ ((m & 7) << 4);
        *(uint2*)((char*)Hs + m*256 + bc) = p;
      }
    }
    {
      const long wb = (long)(e*128) * 512 + fc*128;
#pragma unroll
      for (int s = 0; s < 8; ++s) {
        const int id = tid + s*256;
        const int orr = id >> 4, c16 = id & 15;
        const uint4 v = *(const uint4*)(w2b + wb + (long)orr*512 + c16*8);
        *(uint4*)((char*)Wts + orr*256 + ((c16*16) ^ ((orr & 7) << 4))) = v;
      }
    }
    __syncthreads();
#pragma unroll
    for (int ks = 0; ks < 4; ++ks) {
      const int bcol = ks*64 + lq*16;
      const bf16x8 a0 = ld_frag(Wts, (2*w  )*16 + lr, bcol);
      const bf16x8 a1 = ld_frag(Wts, (2*w+1)*16 + lr, bcol);
      const bf16x8 b0 = ld_frag(Hs,  0*16 + lr, bcol);
      const bf16x8 b1 = ld_frag(Hs,  1*16 + lr, bcol);
      const bf16x8 b2 = ld_frag(Hs,  2*16 + lr, bcol);
      const bf16x8 b3 = ld_frag(Hs,  3*16 + lr, bcol);
      yacc[0][0] = __builtin_amdgcn_mfma_f32_16x16x32_bf16(a0, b0, yacc[0][0], 0, 0, 0);
      yacc[0][1] = __builtin_amdgcn_mfma_f32_16x16x32_bf16(a0, b1, yacc[0][1], 0, 0, 0);
      yacc[0][2] = __builtin_amdgcn_mfma_f32_16x16x32_bf16(a0, b2, yacc[0][2], 0, 0, 0);
      yacc[0][3] = __builtin_amdgcn_mfma_f32_16x16x32_bf16(a0, b3, yacc[0][3], 0, 0, 0);
      yacc[1][0] = __builtin_amdgcn_mfma_f32_16x16x32_bf16(a1, b0, yacc[1][0], 0, 0, 0);
      yacc[1][1] = __builtin_amdgcn_mfma_f32_16x16x32_bf16(a1, b1, yacc[1][1], 0, 0, 0);
      yacc[1][2] = __builtin_amdgcn_mfma_f32_16x16x32_bf16(a1, b2, yacc[1][2], 0, 0, 0);
      yacc[1][3] = __builtin_amdgcn_mfma_f32_16x16x32_bf16(a1, b3, yacc[1][3], 0, 0, 0);
    }
  }
#pragma unroll
  for (int obi = 0; obi < 2; ++obi) {
    const int ob = (2*w + obi)*16 + lq*4;
    const float4 b2 = *(const float4*)&seb2[ob];
#pragma unroll
    for (int mb = 0; mb < 4; ++mb) {
      const int tl = mb*16 + lr;
      if (tl < nt) {
        const int pk = stok[tl];
        const int tk = pk & 0x3FFFFFFF;
        const float wgt = swgt[tl];
        float* Yp = ((pk >> 30) ? Y1 : Y0) + (long)tk*128 + ob;
        float4 o;
        o.x = (yacc[obi][mb][0] + b2.x) * wgt;
        o.y = (yacc[obi][mb][1] + b2.y) * wgt;
        o.z = (yacc[obi][mb][2] + b2.z) * wgt;
        o.w = (yacc[obi][mb][3] + b2.w) * wgt;
        *(float4*)Yp = o;
      }
    }
  }
}

// ---------------- final: probs = softmax(10*tanh(sc/sqrt(128)) + mask) -----
__global__ __launch_bounds__(256)
void k_softmax(float* __restrict__ out, const float* __restrict__ mask) {
  const long row = (long)blockIdx.x*4 + (threadIdx.x >> 6);
  const int l = threadIdx.x & 63;
  float4* r = (float4*)(out + row*512);
  const float4* mr = (const float4*)(mask + row*512);
  const float4 x0 = r[l], x1 = r[64 + l];
  const float4 m0 = mr[l], m1 = mr[64 + l];
  float li[8];
  li[0] = 10.f*tanhf(x0.x*(1.f/11.313708498984761f)) + m0.x;
  li[1] = 10.f*tanhf(x0.y*(1.f/11.313708498984761f)) + m0.y;
  li[2] = 10.f*tanhf(x0.z*(1.f/11.313708498984761f)) + m0.z;
  li[3] = 10.f*tanhf(x0.w*(1.f/11.313708498984761f)) + m0.w;
  li[4] = 10.f*tanhf(x1.x*(1.f/11.313708498984761f)) + m1.x;
  li[5] = 10.f*tanhf(x1.y*(1.f/11.313708498984761f)) + m1.y;
  li[6] = 10.f*tanhf(x1.z*(1.f/11.313708498984761f)) + m1.z;
  li[7] = 10.f*tanhf(x1.w*(1.f/11.313708498984761f)) + m1.w;
  float mx = li[0];
#pragma unroll
  for (int u = 1; u < 8; ++u) mx = fmaxf(mx, li[u]);
#pragma unroll
  for (int o = 1; o < 64; o <<= 1) mx = fmaxf(mx, __shfl_xor(mx, o));
  float ev[8], s = 0.f;
#pragma unroll
  for (int u = 0; u < 8; ++u) { ev[u] = __expf(li[u] - mx); s += ev[u]; }
#pragma unroll
  for (int o = 1; o < 64; o <<= 1) s += __shfl_xor(s, o);
  const float inv = 1.f / s;
  float4 y0, y1;
  y0.x = ev[0]*inv; y0.y = ev[1]*inv; y0.z = ev[2]*inv; y0.w = ev[3]*inv;
  y1.x = ev[4]*inv; y1.y = ev[5]*inv; y1.z = ev[6]*inv; y1.w = ev[7]*inv;
  r[l] = y0; r[64 + l] = y1;
}

// ---------------------------------------------------------------------------
extern "C" void kernel_launch(void* const* d_in, const int* in_sizes, int n_in,
                              void* d_out, int out_size, void* d_ws, size_t ws_size,
                              hipStream_t stream) {
  (void)in_sizes; (void)n_in; (void)out_size; (void)ws_size;
  const float* pref  = (const float*)d_in[0];
  const float* graph = (const float*)d_in[1];
  const float* cap   = (const float*)d_in[2];
  const float* enc   = (const float*)d_in[3];
  const float* mask  = (const float*)d_in[4];
  const float* fc1w  = (const float*)d_in[5];
  const float* fc1b  = (const float*)d_in[6];
  const float* fc2w  = (const float*)d_in[7];
  const float* fc2b  = (const float*)d_in[8];
  const float* fc3w  = (const float*)d_in[9];
  const float* fc3b  = (const float*)d_in[10];
  const float* hWq   = (const float*)d_in[11];
  const float* hWk   = (const float*)d_in[12];
  const float* hWv   = (const float*)d_in[13];
  const float* hWc   = (const float*)d_in[14];
  const float* gw    = (const float*)d_in[15];
  const float* gpw   = (const float*)d_in[16];
  const float* ew1   = (const float*)d_in[17];
  const float* eb1   = (const float*)d_in[18];
  const float* ew2   = (const float*)d_in[19];
  const float* eb2   = (const float*)d_in[20];
  float* ws  = (float*)d_ws;
  float* out = (float*)d_out;
  float* Kbuf = out;
  float* Vbuf = out + 2097152;
  float* Y0   = out;
  float* Y1   = out + 2097152;
  unsigned short* ew1b = (unsigned short*)(out + 4194304);
  unsigned short* ew2b = (unsigned short*)(out + 4456448);

  hipMemsetAsync((char*)d_ws + OFF_CNT*sizeof(float), 0, 8*sizeof(int), stream);
  k_cvt<<<1024, 256, 0, stream>>>(ew1, ew2, ew1b, ew2b);
  k_hyper<<<1, 256, 0, stream>>>(pref, fc1w, fc1b, fc2w, fc2b, fc3w, fc3b, gpw, ws);
  k_hyperw<<<257, 256, 0, stream>>>(hWq, hWk, hWv, hWc, ws);
  k_qbase<<<32, 128, 0, stream>>>(graph, ws);
  k_gemm<0><<<dim3(128, 2), 256, 0, stream>>>(enc, nullptr, ws + OFF_WK, ws + OFF_WV, Kbuf, Vbuf);
  k_attn<<<256, 256, 0, stream>>>(Kbuf, Vbuf, ws, cap, mask, ws + OFF_AO);
  k_gate<<<64, 256, 0, stream>>>(ws + OFF_AO, gw, ws);
  k_moe<<<dim3(256, 8), 256, 0, stream>>>(ws + OFF_AO, ew1b, ew2b, eb1, eb2, ws, Y0, Y1);
  k_gemm<1><<<dim3(128, 1), 256, 0, stream>>>(Y0, Y1, ws + OFF_WC, nullptr, ws + OFF_MH, nullptr);
  k_gemm<2><<<dim3(4, 4, 32), 256, 0, stream>>>(ws + OFF_MH, nullptr, enc, nullptr, out, nullptr);
  k_softmax<<<4096, 256, 0, stream>>>(out, mask);
}

// Round 5
// 189.622 us; speedup vs baseline: 4.7861x; 1.0715x over previous
//
#include <hip/hip_runtime.h>

// ---------------------------------------------------------------------------
// KP_Decoder: hypernet -> (k,v,q) -> attention -> top2 MoE -> combine softmax
// B=32 G=512 N=512 EMB=128 H=8 DK=16 E=8 FH=512 K=2
// R2: k_gate block-aggregated routing.
// R3: k_moe bf16 MFMA (16x16x32), XOR-swizzled LDS.
// R4: k_attn bf16 MFMA flash attention (S^T orientation), XCD-aware mapping.
// R5: k_attn 512 threads (8 waves -> 2 waves/SIMD, latency hiding);
//     k_gemm<0> writes K/V directly in bf16 (half traffic, no f2bf in attn).
// ---------------------------------------------------------------------------

typedef __attribute__((ext_vector_type(8))) __bf16 bf16x8;
typedef __attribute__((ext_vector_type(4))) float f32x4;

// ws layout (float offsets)
static constexpr long OFF_MID   = 0;        // 8
static constexpr long OFF_PREFL = 8;        // 8
static constexpr long OFF_WQ    = 64;       // 128x129 = 16512
static constexpr long OFF_WK    = 16576;    // 128x128
static constexpr long OFF_WV    = 32960;    // 128x128
static constexpr long OFF_WC    = 49344;    // 128x128
static constexpr long OFF_QB    = 65728;    // 32x128 qbase
static constexpr long OFF_CNT   = 69824;    // 8 ints
static constexpr long OFF_TOK   = 69888;    // 8*16384 ints
static constexpr long OFF_WGT   = 200960;   // 8*16384 floats
static constexpr long OFF_AO    = 332288;   // 16384x128 attention out
static constexpr long OFF_MH    = 2429440;  // 16384x128 mh
// total = 4,526,592 floats = 18.1 MB

__device__ __forceinline__ unsigned f2bf(float x) {
  union { float f; unsigned u; } v; v.f = x;
  return ((v.u + 0x7FFFu + ((v.u >> 16) & 1u)) >> 16) & 0xFFFFu;
}

// ---------------- hypernet: mid + pref gate logits -------------------------
__global__ __launch_bounds__(256)
void k_hyper(const float* __restrict__ pref, const float* __restrict__ fc1w,
             const float* __restrict__ fc1b, const float* __restrict__ fc2w,
             const float* __restrict__ fc2b, const float* __restrict__ fc3w,
             const float* __restrict__ fc3b, const float* __restrict__ gpw,
             float* __restrict__ ws) {
  __shared__ float h1[256];
  __shared__ float h2[256];
  __shared__ float mid[8];
  const int t = threadIdx.x;
  const float p0 = pref[0], p1 = pref[1];
  h1[t] = fc1w[2*t]*p0 + fc1w[2*t+1]*p1 + fc1b[t];
  __syncthreads();
  float s = 0.f;
  for (int j = 0; j < 256; ++j) s = fmaf(fc2w[t*256+j], h1[j], s);
  h2[t] = s + fc2b[t];
  __syncthreads();
  if (t < 8) {
    float s2 = 0.f;
    for (int j = 0; j < 256; ++j) s2 = fmaf(fc3w[t*256+j], h2[j], s2);
    mid[t] = s2 + fc3b[t];
    ws[OFF_MID + t] = mid[t];
  }
  __syncthreads();
  if (t < 8) {
    float s3 = 0.f;
    for (int i = 0; i < 8; ++i) s3 = fmaf(mid[i], gpw[i*8 + t], s3);
    ws[OFF_PREFL + t] = s3;
  }
}

// ---------------- hypernet heads: Wq/Wk/Wv/Wc ------------------------------
__global__ __launch_bounds__(256)
void k_hyperw(const float* __restrict__ hWq, const float* __restrict__ hWk,
              const float* __restrict__ hWv, const float* __restrict__ hWc,
              float* __restrict__ ws) {
  const int i = blockIdx.x*256 + threadIdx.x;
  const float m0 = ws[0], m1 = ws[1], m2 = ws[2], m3 = ws[3],
              m4 = ws[4], m5 = ws[5], m6 = ws[6], m7 = ws[7];
  if (i < 16512) {
    ws[OFF_WQ + i] = hWq[2*i]*m0 + hWq[2*i+1]*m1;
  } else if (i < 32896) {
    const int j = i - 16512;
    ws[OFF_WK + j] = hWk[2*j]*m2 + hWk[2*j+1]*m3;
  } else if (i < 49280) {
    const int j = i - 32896;
    ws[OFF_WV + j] = hWv[2*j]*m4 + hWv[2*j+1]*m5;
  } else if (i < 65664) {
    const int j = i - 49280;
    ws[OFF_WC + j] = hWc[2*j]*m6 + hWc[2*j+1]*m7;
  }
}

// ---------------- weight bf16 conversion for MoE ---------------------------
__global__ __launch_bounds__(256)
void k_cvt(const float* __restrict__ ew1, const float* __restrict__ ew2,
           unsigned short* __restrict__ w1b, unsigned short* __restrict__ w2b) {
  const int i = blockIdx.x*256 + threadIdx.x;
  const int h = 131072;
  const float4 v = (i < h) ? *(const float4*)(ew1 + (long)i*4)
                           : *(const float4*)(ew2 + (long)(i-h)*4);
  uint2 p;
  p.x = f2bf(v.x) | (f2bf(v.y) << 16);
  p.y = f2bf(v.z) | (f2bf(v.w) << 16);
  unsigned short* dst = (i < h) ? (w1b + (long)i*4) : (w2b + (long)(i-h)*4);
  *(uint2*)dst = p;
}

// ---------------- qbase[b][o] = graph[b] . Wq[o,0:128] ---------------------
__global__ __launch_bounds__(128)
void k_qbase(const float* __restrict__ graph, float* __restrict__ ws) {
  __shared__ float g[128];
  const int b = blockIdx.x, t = threadIdx.x;
  g[t] = graph[b*128 + t];
  __syncthreads();
  const float* wq = ws + OFF_WQ + (long)t*129;
  float s = 0.f;
  for (int i = 0; i < 128; ++i) s = fmaf(g[i], wq[i], s);
  ws[OFF_QB + b*128 + t] = s;
}

// ---------------- generic fp32 GEMM, C = A @ B^T, K=128 --------------------
// MODE 0: kv   grid(128,2): A=enc, B={Wk,Wv}, C bf16 {K,V}, ldc=128 (shorts)
// MODE 1: mh   grid(128,1): A=Y0+Y1, B=Wc, C=MH fp32, ldc=128
// MODE 2: sc   grid(4,4,32): per-b A=mh[b], B=enc[b], C=out fp32, ldc=512
template <int MODE>
__global__ __launch_bounds__(256)
void k_gemm(const float* __restrict__ A, const float* __restrict__ A2,
            const float* __restrict__ B0, const float* __restrict__ B1,
            void* __restrict__ C0v, void* __restrict__ C1v) {
  constexpr int LDT = 132;
  __shared__ float As[32][LDT];
  __shared__ float Bs[32][LDT];
  const int tid = threadIdx.x;
  const int bx = blockIdx.x;
  const float* Ap;
  const float* Ap2 = nullptr;
  const float* Bp;
  if constexpr (MODE == 0) {
    Ap = A + (long)bx*128*128;
    Bp = blockIdx.y ? B1 : B0;
  } else if constexpr (MODE == 1) {
    Ap  = A  + (long)bx*128*128;
    Ap2 = A2 + (long)bx*128*128;
    Bp = B0;
  } else {
    const long zo = (long)blockIdx.z*512*128;
    Ap = A + zo + (long)bx*128*128;
    Bp = B0 + zo + (long)blockIdx.y*128*128;
  }
  float acc[8][8];
#pragma unroll
  for (int i = 0; i < 8; ++i)
#pragma unroll
    for (int j = 0; j < 8; ++j) acc[i][j] = 0.f;
  const int tm = (tid >> 4) * 8;
  const int tn = (tid & 15) * 8;
  for (int kt = 0; kt < 4; ++kt) {
    __syncthreads();
#pragma unroll
    for (int r = 0; r < 4; ++r) {
      const int id = tid + r*256;
      const int m = id >> 3, kq = id & 7;
      float4 av = *(const float4*)(Ap + (long)m*128 + kt*32 + kq*4);
      if constexpr (MODE == 1) {
        const float4 a2 = *(const float4*)(Ap2 + (long)m*128 + kt*32 + kq*4);
        av.x += a2.x; av.y += a2.y; av.z += a2.z; av.w += a2.w;
      }
      As[kq*4+0][m] = av.x; As[kq*4+1][m] = av.y;
      As[kq*4+2][m] = av.z; As[kq*4+3][m] = av.w;
      const float4 bv = *(const float4*)(Bp + (long)m*128 + kt*32 + kq*4);
      Bs[kq*4+0][m] = bv.x; Bs[kq*4+1][m] = bv.y;
      Bs[kq*4+2][m] = bv.z; Bs[kq*4+3][m] = bv.w;
    }
    __syncthreads();
#pragma unroll
    for (int kk = 0; kk < 32; ++kk) {
      float a[8], b[8];
      *(float4*)&a[0] = *(const float4*)&As[kk][tm];
      *(float4*)&a[4] = *(const float4*)&As[kk][tm+4];
      *(float4*)&b[0] = *(const float4*)&Bs[kk][tn];
      *(float4*)&b[4] = *(const float4*)&Bs[kk][tn+4];
#pragma unroll
      for (int i = 0; i < 8; ++i)
#pragma unroll
        for (int j = 0; j < 8; ++j) acc[i][j] = fmaf(a[i], b[j], acc[i][j]);
    }
  }
  if constexpr (MODE == 0) {
    unsigned short* Cp = (unsigned short*)(blockIdx.y ? C1v : C0v) + (long)bx*128*128;
#pragma unroll
    for (int i = 0; i < 8; ++i) {
      uint4 p;
      p.x = f2bf(acc[i][0]) | (f2bf(acc[i][1]) << 16);
      p.y = f2bf(acc[i][2]) | (f2bf(acc[i][3]) << 16);
      p.z = f2bf(acc[i][4]) | (f2bf(acc[i][5]) << 16);
      p.w = f2bf(acc[i][6]) | (f2bf(acc[i][7]) << 16);
      *(uint4*)(Cp + (long)(tm+i)*128 + tn) = p;
    }
  } else {
    float* Cp;
    int ldc;
    if constexpr (MODE == 1) {
      Cp = (float*)C0v + (long)bx*128*128;
      ldc = 128;
    } else {
      Cp = (float*)C0v + (long)blockIdx.z*512*512 + (long)bx*128*512 + (long)blockIdx.y*128;
      ldc = 512;
    }
#pragma unroll
    for (int i = 0; i < 8; ++i) {
      const float4 c0 = {acc[i][0], acc[i][1], acc[i][2], acc[i][3]};
      const float4 c1 = {acc[i][4], acc[i][5], acc[i][6], acc[i][7]};
      *(float4*)(Cp + (long)(tm+i)*ldc + tn)     = c0;
      *(float4*)(Cp + (long)(tm+i)*ldc + tn + 4) = c1;
    }
  }
}

// ---------------- MFMA flash attention per (b,h), 8 waves ------------------
// S^T = mfma(K-frag, Q-frag): D[n][q], DK padded 16->32 with zero frags.
// Online softmax in S^T layout: per lane ONE q-row (q = lane&15), 4 consec n.
// PV: out^T[d][q] = mfma(Vt-frag, P-frag); Vt = V transposed in LDS.
// K/V arrive in bf16 (produced by k_gemm<0>).
__global__ __launch_bounds__(512)
void k_attn(const unsigned short* __restrict__ Kb,
            const unsigned short* __restrict__ Vb,
            const float* __restrict__ ws, const float* __restrict__ cap,
            const float* __restrict__ mask, float* __restrict__ AO) {
  const int bid = blockIdx.x;
  const int b = bid & 31, h = bid >> 5;   // XCD-aware: L2 keeps mask[b] per XCD
  __shared__ unsigned short Kbf[512*24];  // [n][24] pitch, 24 KB
  __shared__ unsigned short Vt[16*536];   // [d][536] pitch, 16.75 KB
  __shared__ unsigned short Ps[8*16*136]; // per-wave [16 q][136], 34 KB
  const int tid = threadIdx.x;
  // stage K (copy) + V (transpose), both bf16 already
#pragma unroll
  for (int it = 0; it < 2; ++it) {
    const int i = tid + it*512;           // 0..1023
    const int n = i >> 1, hf = i & 1;     // 8-short halves of the 16-dk slice
    const long src = (long)(b*512 + n)*128 + h*16 + hf*8;
    const uint4 kv = *(const uint4*)(Kb + src);
    *(uint4*)(Kbf + n*24 + hf*8) = kv;
    const uint4 vv = *(const uint4*)(Vb + src);
    const unsigned short* sp = (const unsigned short*)&vv;
#pragma unroll
    for (int j = 0; j < 8; ++j) Vt[(hf*8 + j)*536 + n] = sp[j];
  }
  const int w = tid >> 6, l = tid & 63;
  const int lq = l >> 4, lr = l & 15;
  // per-lane Q constants for dk = lq*8+j (valid lq<2)
  float qb8[8], wl8[8];
  if (lq < 2) {
    const float* qbp = ws + OFF_QB + b*128 + h*16 + lq*8;
    const float* wqp = ws + OFF_WQ;
#pragma unroll
    for (int j = 0; j < 8; ++j) {
      qb8[j] = qbp[j];
      wl8[j] = wqp[(h*16 + lq*8 + j)*129 + 128];
    }
  }
  unsigned short* Pw = Ps + w*16*136;
  __syncthreads();
  const float SC = 0.25f;
  for (int qb = 0; qb < 4; ++qb) {
    const int grow = w*64 + qb*16 + lr;   // this lane's q-row
    // B-frag: Q[q=lr][dk]
    bf16x8 qf;
    {
      union { uint4 u; bf16x8 v; } cv;
      cv.u = make_uint4(0u, 0u, 0u, 0u);
      if (lq < 2) {
        const float cp = cap[b*512 + grow];
        float qv[8];
#pragma unroll
        for (int j = 0; j < 8; ++j) qv[j] = (qb8[j] + cp*wl8[j]) * SC;
        cv.u.x = f2bf(qv[0]) | (f2bf(qv[1]) << 16);
        cv.u.y = f2bf(qv[2]) | (f2bf(qv[3]) << 16);
        cv.u.z = f2bf(qv[4]) | (f2bf(qv[5]) << 16);
        cv.u.w = f2bf(qv[6]) | (f2bf(qv[7]) << 16);
      }
      qf = cv.v;
    }
    float m = -3.0e38f, lsum = 0.f;
    f32x4 oacc = {0.f, 0.f, 0.f, 0.f};
    const float* mrow = mask + ((long)(b*512 + grow))*512 + lq*4;
    for (int ch = 0; ch < 4; ++ch) {
      const int n0 = ch*128;
      f32x4 s[8];
#pragma unroll
      for (int nb = 0; nb < 8; ++nb) {
        bf16x8 kf;
        {
          union { uint4 u; bf16x8 v; } cv;
          cv.u = make_uint4(0u, 0u, 0u, 0u);
          if (lq < 2) cv.u = *(const uint4*)(Kbf + (n0 + nb*16 + lr)*24 + lq*8);
          kf = cv.v;
        }
        s[nb] = __builtin_amdgcn_mfma_f32_16x16x32_bf16(
            kf, qf, (f32x4){0.f, 0.f, 0.f, 0.f}, 0, 0, 0);
        const float4 mk = *(const float4*)(mrow + n0 + nb*16);
        s[nb][0] += mk.x; s[nb][1] += mk.y; s[nb][2] += mk.z; s[nb][3] += mk.w;
      }
      // chunk max (in-lane 32 values -> cross lq groups)
      f32x4 mx = s[0];
#pragma unroll
      for (int nb = 1; nb < 8; ++nb) {
        mx[0] = fmaxf(mx[0], s[nb][0]); mx[1] = fmaxf(mx[1], s[nb][1]);
        mx[2] = fmaxf(mx[2], s[nb][2]); mx[3] = fmaxf(mx[3], s[nb][3]);
      }
      float cm = fmaxf(fmaxf(mx[0], mx[1]), fmaxf(mx[2], mx[3]));
      cm = fmaxf(cm, __shfl_xor(cm, 16));
      cm = fmaxf(cm, __shfl_xor(cm, 32));
      const float nm = fmaxf(m, cm);
      const float rs = __expf(m - nm);
      lsum *= rs;
      oacc[0] *= rs; oacc[1] *= rs; oacc[2] *= rs; oacc[3] *= rs;
      m = nm;
      float ls = 0.f;
#pragma unroll
      for (int nb = 0; nb < 8; ++nb) {
        const float p0 = __expf(s[nb][0] - m);
        const float p1 = __expf(s[nb][1] - m);
        const float p2 = __expf(s[nb][2] - m);
        const float p3 = __expf(s[nb][3] - m);
        ls += (p0 + p1) + (p2 + p3);
        uint2 pp;
        asm("v_cvt_pk_bf16_f32 %0, %1, %2" : "=v"(pp.x) : "v"(p0), "v"(p1));
        asm("v_cvt_pk_bf16_f32 %0, %1, %2" : "=v"(pp.y) : "v"(p2), "v"(p3));
        *(uint2*)(Pw + lr*136 + nb*16 + lq*4) = pp;
      }
      lsum += ls;
      // PV: oacc[d][q] += Vt . P  (contract 128 n in 4 K=32 steps)
#pragma unroll
      for (int ks = 0; ks < 4; ++ks) {
        const bf16x8 va = *(const bf16x8*)(Vt + lr*536 + n0 + ks*32 + lq*8);
        const bf16x8 pb = *(const bf16x8*)(Pw + lr*136 + ks*32 + lq*8);
        oacc = __builtin_amdgcn_mfma_f32_16x16x32_bf16(va, pb, oacc, 0, 0, 0);
      }
    }
    lsum += __shfl_xor(lsum, 16);
    lsum += __shfl_xor(lsum, 32);
    const float inv = 1.f / lsum;
    float4 o;
    o.x = oacc[0]*inv; o.y = oacc[1]*inv; o.z = oacc[2]*inv; o.w = oacc[3]*inv;
    *(float4*)(AO + (long)(b*512 + grow)*128 + h*16 + lq*4) = o;
  }
}

// ---------------- gating: top-2 + expert lists (block-aggregated) ----------
__global__ __launch_bounds__(256)
void k_gate(const float* __restrict__ AO, const float* __restrict__ gw,
            float* __restrict__ ws) {
  const int tid = threadIdx.x;
  const int t = blockIdx.x*256 + tid;
  const float* x = AO + (long)t*128;
  float lg[8];
  {
    const float* pl = ws + OFF_PREFL;
#pragma unroll
    for (int e = 0; e < 8; ++e) lg[e] = pl[e];
  }
  for (int i = 0; i < 128; i += 4) {
    const float4 xv = *(const float4*)(x + i);
#pragma unroll
    for (int u = 0; u < 4; ++u) {
      const float xi = (&xv.x)[u];
      const float4 ga = *(const float4*)(gw + (i+u)*8);
      const float4 gb = *(const float4*)(gw + (i+u)*8 + 4);
      lg[0] = fmaf(xi, ga.x, lg[0]); lg[1] = fmaf(xi, ga.y, lg[1]);
      lg[2] = fmaf(xi, ga.z, lg[2]); lg[3] = fmaf(xi, ga.w, lg[3]);
      lg[4] = fmaf(xi, gb.x, lg[4]); lg[5] = fmaf(xi, gb.y, lg[5]);
      lg[6] = fmaf(xi, gb.z, lg[6]); lg[7] = fmaf(xi, gb.w, lg[7]);
    }
  }
  int i0 = 0; float v0 = lg[0];
#pragma unroll
  for (int e = 1; e < 8; ++e) if (lg[e] > v0) { v0 = lg[e]; i0 = e; }
  int i1 = -1; float v1 = -1e30f;
#pragma unroll
  for (int e = 0; e < 8; ++e) if (e != i0 && lg[e] > v1) { v1 = lg[e]; i1 = e; }
  const float e1 = __expf(v1 - v0);
  const float w0 = 1.f / (1.f + e1);
  const float w1 = 1.f - w0;
  __shared__ int bcnt[8];
  __shared__ int gbase[8];
  if (tid < 8) bcnt[tid] = 0;
  __syncthreads();
  const int p0 = atomicAdd(&bcnt[i0], 1);
  const int p1 = atomicAdd(&bcnt[i1], 1);
  __syncthreads();
  if (tid < 8) {
    int* cnt = (int*)(ws + OFF_CNT);
    gbase[tid] = (bcnt[tid] > 0) ? atomicAdd(&cnt[tid], bcnt[tid]) : 0;
  }
  __syncthreads();
  int* tokp = (int*)(ws + OFF_TOK);
  float* wgtp = ws + OFF_WGT;
  const int s0 = gbase[i0] + p0;
  tokp[i0*16384 + s0] = t;             // rank 0
  wgtp[i0*16384 + s0] = w0;
  const int s1 = gbase[i1] + p1;
  tokp[i1*16384 + s1] = t | (1 << 30); // rank 1
  wgtp[i1*16384 + s1] = w1;
}

// ---------------- MoE experts: bf16 MFMA, per (expert, 64-token chunk) -----
__device__ __forceinline__ bf16x8 ld_frag(const unsigned short* base, int row, int bytecol) {
  const int addr = row*256 + (bytecol ^ ((row & 7) << 4));
  return *(const bf16x8*)((const char*)base + addr);
}

__global__ __launch_bounds__(256)
void k_moe(const float* __restrict__ AO,
           const unsigned short* __restrict__ w1b,
           const unsigned short* __restrict__ w2b,
           const float* __restrict__ eb1, const float* __restrict__ eb2,
           float* __restrict__ ws,
           float* __restrict__ Y0, float* __restrict__ Y1) {
  const int e = blockIdx.y;
  const int ce = ((const int*)(ws + OFF_CNT))[e];
  const int base = blockIdx.x * 64;
  if (base >= ce) return;
  const int nt = min(64, ce - base);

  __shared__ unsigned short Xs[64*128];
  __shared__ unsigned short Wts[128*128];
  __shared__ unsigned short Hs[64*128];
  __shared__ float seb1[512];
  __shared__ float seb2[128];
  __shared__ int   stok[64];
  __shared__ float swgt[64];

  const int tid = threadIdx.x;
  if (tid < 64) {
    if (tid < nt) {
      stok[tid] = ((const int*)(ws + OFF_TOK))[e*16384 + base + tid];
      swgt[tid] = (ws + OFF_WGT)[e*16384 + base + tid];
    } else { stok[tid] = -1; swgt[tid] = 0.f; }
  }
  for (int i = tid; i < 512; i += 256) seb1[i] = eb1[e*512 + i];
  if (tid < 128) seb2[tid] = eb2[e*128 + tid];
  __syncthreads();

#pragma unroll
  for (int r8 = 0; r8 < 8; ++r8) {
    const int id = tid + r8*256;
    const int r = id >> 5, c = id & 31;
    const int pk = stok[r];
    float4 xv = make_float4(0.f, 0.f, 0.f, 0.f);
    if (pk >= 0) xv = *(const float4*)(AO + (long)(pk & 0x3FFFFFFF)*128 + c*4);
    uint2 pkd;
    pkd.x = f2bf(xv.x) | (f2bf(xv.y) << 16);
    pkd.y = f2bf(xv.z) | (f2bf(xv.w) << 16);
    const int bc = (c*8) ^ ((r & 7) << 4);
    *(uint2*)((char*)Xs + r*256 + bc) = pkd;
  }

  const int w  = tid >> 6;
  const int l  = tid & 63;
  const int lq = l >> 4;
  const int lr = l & 15;

  f32x4 yacc[2][4];
#pragma unroll
  for (int a = 0; a < 2; ++a)
#pragma unroll
    for (int m = 0; m < 4; ++m) yacc[a][m] = (f32x4){0.f, 0.f, 0.f, 0.f};

  for (int fc = 0; fc < 4; ++fc) {
    __syncthreads();
    {
      const long wb = (long)(e*512 + fc*128) * 128;
#pragma unroll
      for (int s = 0; s < 8; ++s) {
        const int id = tid + s*256;
        const int fr = id >> 4, c16 = id & 15;
        const uint4 v = *(const uint4*)(w1b + wb + (long)fr*128 + c16*8);
        *(uint4*)((char*)Wts + fr*256 + ((c16*16) ^ ((fr & 7) << 4))) = v;
      }
    }
    __syncthreads();
    f32x4 hacc[2][4];
#pragma unroll
    for (int a = 0; a < 2; ++a)
#pragma unroll
      for (int m = 0; m < 4; ++m) hacc[a][m] = (f32x4){0.f, 0.f, 0.f, 0.f};
#pragma unroll
    for (int ks = 0; ks < 4; ++ks) {
      const int bcol = ks*64 + lq*16;
      const bf16x8 a0 = ld_frag(Wts, (2*w  )*16 + lr, bcol);
      const bf16x8 a1 = ld_frag(Wts, (2*w+1)*16 + lr, bcol);
      const bf16x8 b0 = ld_frag(Xs,  0*16 + lr, bcol);
      const bf16x8 b1 = ld_frag(Xs,  1*16 + lr, bcol);
      const bf16x8 b2 = ld_frag(Xs,  2*16 + lr, bcol);
      const bf16x8 b3 = ld_frag(Xs,  3*16 + lr, bcol);
      hacc[0][0] = __builtin_amdgcn_mfma_f32_16x16x32_bf16(a0, b0, hacc[0][0], 0, 0, 0);
      hacc[0][1] = __builtin_amdgcn_mfma_f32_16x16x32_bf16(a0, b1, hacc[0][1], 0, 0, 0);
      hacc[0][2] = __builtin_amdgcn_mfma_f32_16x16x32_bf16(a0, b2, hacc[0][2], 0, 0, 0);
      hacc[0][3] = __builtin_amdgcn_mfma_f32_16x16x32_bf16(a0, b3, hacc[0][3], 0, 0, 0);
      hacc[1][0] = __builtin_amdgcn_mfma_f32_16x16x32_bf16(a1, b0, hacc[1][0], 0, 0, 0);
      hacc[1][1] = __builtin_amdgcn_mfma_f32_16x16x32_bf16(a1, b1, hacc[1][1], 0, 0, 0);
      hacc[1][2] = __builtin_amdgcn_mfma_f32_16x16x32_bf16(a1, b2, hacc[1][2], 0, 0, 0);
      hacc[1][3] = __builtin_amdgcn_mfma_f32_16x16x32_bf16(a1, b3, hacc[1][3], 0, 0, 0);
    }
    __syncthreads();
#pragma unroll
    for (int fbi = 0; fbi < 2; ++fbi) {
      const int fb = (2*w + fbi)*16 + lq*4;
      const float4 bia = *(const float4*)&seb1[fc*128 + fb];
#pragma unroll
      for (int mb = 0; mb < 4; ++mb) {
        const int m = mb*16 + lr;
        const float h0 = fmaxf(hacc[fbi][mb][0] + bia.x, 0.f);
        const float h1 = fmaxf(hacc[fbi][mb][1] + bia.y, 0.f);
        const float h2 = fmaxf(hacc[fbi][mb][2] + bia.z, 0.f);
        const float h3 = fmaxf(hacc[fbi][mb][3] + bia.w, 0.f);
        uint2 p;
        p.x = f2bf(h0) | (f2bf(h1) << 16);
        p.y = f2bf(h2) | (f2bf(h3) << 16);
        const int bc = (fb*2) ^ ((m & 7) << 4);
        *(uint2*)((char*)Hs + m*256 + bc) = p;
      }
    }
    {
      const long wb = (long)(e*128) * 512 + fc*128;
#pragma unroll
      for (int s = 0; s < 8; ++s) {
        const int id = tid + s*256;
        const int orr = id >> 4, c16 = id & 15;
        const uint4 v = *(const uint4*)(w2b + wb + (long)orr*512 + c16*8);
        *(uint4*)((char*)Wts + orr*256 + ((c16*16) ^ ((orr & 7) << 4))) = v;
      }
    }
    __syncthreads();
#pragma unroll
    for (int ks = 0; ks < 4; ++ks) {
      const int bcol = ks*64 + lq*16;
      const bf16x8 a0 = ld_frag(Wts, (2*w  )*16 + lr, bcol);
      const bf16x8 a1 = ld_frag(Wts, (2*w+1)*16 + lr, bcol);
      const bf16x8 b0 = ld_frag(Hs,  0*16 + lr, bcol);
      const bf16x8 b1 = ld_frag(Hs,  1*16 + lr, bcol);
      const bf16x8 b2 = ld_frag(Hs,  2*16 + lr, bcol);
      const bf16x8 b3 = ld_frag(Hs,  3*16 + lr, bcol);
      yacc[0][0] = __builtin_amdgcn_mfma_f32_16x16x32_bf16(a0, b0, yacc[0][0], 0, 0, 0);
      yacc[0][1] = __builtin_amdgcn_mfma_f32_16x16x32_bf16(a0, b1, yacc[0][1], 0, 0, 0);
      yacc[0][2] = __builtin_amdgcn_mfma_f32_16x16x32_bf16(a0, b2, yacc[0][2], 0, 0, 0);
      yacc[0][3] = __builtin_amdgcn_mfma_f32_16x16x32_bf16(a0, b3, yacc[0][3], 0, 0, 0);
      yacc[1][0] = __builtin_amdgcn_mfma_f32_16x16x32_bf16(a1, b0, yacc[1][0], 0, 0, 0);
      yacc[1][1] = __builtin_amdgcn_mfma_f32_16x16x32_bf16(a1, b1, yacc[1][1], 0, 0, 0);
      yacc[1][2] = __builtin_amdgcn_mfma_f32_16x16x32_bf16(a1, b2, yacc[1][2], 0, 0, 0);
      yacc[1][3] = __builtin_amdgcn_mfma_f32_16x16x32_bf16(a1, b3, yacc[1][3], 0, 0, 0);
    }
  }
#pragma unroll
  for (int obi = 0; obi < 2; ++obi) {
    const int ob = (2*w + obi)*16 + lq*4;
    const float4 b2 = *(const float4*)&seb2[ob];
#pragma unroll
    for (int mb = 0; mb < 4; ++mb) {
      const int tl = mb*16 + lr;
      if (tl < nt) {
        const int pk = stok[tl];
        const int tk = pk & 0x3FFFFFFF;
        const float wgt = swgt[tl];
        float* Yp = ((pk >> 30) ? Y1 : Y0) + (long)tk*128 + ob;
        float4 o;
        o.x = (yacc[obi][mb][0] + b2.x) * wgt;
        o.y = (yacc[obi][mb][1] + b2.y) * wgt;
        o.z = (yacc[obi][mb][2] + b2.z) * wgt;
        o.w = (yacc[obi][mb][3] + b2.w) * wgt;
        *(float4*)Yp = o;
      }
    }
  }
}

// ---------------- final: probs = softmax(10*tanh(sc/sqrt(128)) + mask) -----
__global__ __launch_bounds__(256)
void k_softmax(float* __restrict__ out, const float* __restrict__ mask) {
  const long row = (long)blockIdx.x*4 + (threadIdx.x >> 6);
  const int l = threadIdx.x & 63;
  float4* r = (float4*)(out + row*512);
  const float4* mr = (const float4*)(mask + row*512);
  const float4 x0 = r[l], x1 = r[64 + l];
  const float4 m0 = mr[l], m1 = mr[64 + l];
  float li[8];
  li[0] = 10.f*tanhf(x0.x*(1.f/11.313708498984761f)) + m0.x;
  li[1] = 10.f*tanhf(x0.y*(1.f/11.313708498984761f)) + m0.y;
  li[2] = 10.f*tanhf(x0.z*(1.f/11.313708498984761f)) + m0.z;
  li[3] = 10.f*tanhf(x0.w*(1.f/11.313708498984761f)) + m0.w;
  li[4] = 10.f*tanhf(x1.x*(1.f/11.313708498984761f)) + m1.x;
  li[5] = 10.f*tanhf(x1.y*(1.f/11.313708498984761f)) + m1.y;
  li[6] = 10.f*tanhf(x1.z*(1.f/11.313708498984761f)) + m1.z;
  li[7] = 10.f*tanhf(x1.w*(1.f/11.313708498984761f)) + m1.w;
  float mx = li[0];
#pragma unroll
  for (int u = 1; u < 8; ++u) mx = fmaxf(mx, li[u]);
#pragma unroll
  for (int o = 1; o < 64; o <<= 1) mx = fmaxf(mx, __shfl_xor(mx, o));
  float ev[8], s = 0.f;
#pragma unroll
  for (int u = 0; u < 8; ++u) { ev[u] = __expf(li[u] - mx); s += ev[u]; }
#pragma unroll
  for (int o = 1; o < 64; o <<= 1) s += __shfl_xor(s, o);
  const float inv = 1.f / s;
  float4 y0, y1;
  y0.x = ev[0]*inv; y0.y = ev[1]*inv; y0.z = ev[2]*inv; y0.w = ev[3]*inv;
  y1.x = ev[4]*inv; y1.y = ev[5]*inv; y1.z = ev[6]*inv; y1.w = ev[7]*inv;
  r[l] = y0; r[64 + l] = y1;
}

// ---------------------------------------------------------------------------
extern "C" void kernel_launch(void* const* d_in, const int* in_sizes, int n_in,
                              void* d_out, int out_size, void* d_ws, size_t ws_size,
                              hipStream_t stream) {
  (void)in_sizes; (void)n_in; (void)out_size; (void)ws_size;
  const float* pref  = (const float*)d_in[0];
  const float* graph = (const float*)d_in[1];
  const float* cap   = (const float*)d_in[2];
  const float* enc   = (const float*)d_in[3];
  const float* mask  = (const float*)d_in[4];
  const float* fc1w  = (const float*)d_in[5];
  const float* fc1b  = (const float*)d_in[6];
  const float* fc2w  = (const float*)d_in[7];
  const float* fc2b  = (const float*)d_in[8];
  const float* fc3w  = (const float*)d_in[9];
  const float* fc3b  = (const float*)d_in[10];
  const float* hWq   = (const float*)d_in[11];
  const float* hWk   = (const float*)d_in[12];
  const float* hWv   = (const float*)d_in[13];
  const float* hWc   = (const float*)d_in[14];
  const float* gw    = (const float*)d_in[15];
  const float* gpw   = (const float*)d_in[16];
  const float* ew1   = (const float*)d_in[17];
  const float* eb1   = (const float*)d_in[18];
  const float* ew2   = (const float*)d_in[19];
  const float* eb2   = (const float*)d_in[20];
  float* ws  = (float*)d_ws;
  float* out = (float*)d_out;
  // d_out scratch (bytes): K bf16 [0,4M), V bf16 [4M,8M) -> dead after attn;
  // Y0 [0,8M), Y1 [8M,16M); ew1b [16M,17M), ew2b [17M,18M). gemm<2> writes all.
  unsigned short* Kbuf = (unsigned short*)out;             // bf16, 4MB
  unsigned short* Vbuf = (unsigned short*)(out + 1048576); // bf16, 4MB
  float* Y0   = out;
  float* Y1   = out + 2097152;
  unsigned short* ew1b = (unsigned short*)(out + 4194304);
  unsigned short* ew2b = (unsigned short*)(out + 4456448);

  hipMemsetAsync((char*)d_ws + OFF_CNT*sizeof(float), 0, 8*sizeof(int), stream);
  k_cvt<<<1024, 256, 0, stream>>>(ew1, ew2, ew1b, ew2b);
  k_hyper<<<1, 256, 0, stream>>>(pref, fc1w, fc1b, fc2w, fc2b, fc3w, fc3b, gpw, ws);
  k_hyperw<<<257, 256, 0, stream>>>(hWq, hWk, hWv, hWc, ws);
  k_qbase<<<32, 128, 0, stream>>>(graph, ws);
  k_gemm<0><<<dim3(128, 2), 256, 0, stream>>>(enc, nullptr, ws + OFF_WK, ws + OFF_WV, Kbuf, Vbuf);
  k_attn<<<256, 512, 0, stream>>>(Kbuf, Vbuf, ws, cap, mask, ws + OFF_AO);
  k_gate<<<64, 256, 0, stream>>>(ws + OFF_AO, gw, ws);
  k_moe<<<dim3(256, 8), 256, 0, stream>>>(ws + OFF_AO, ew1b, ew2b, eb1, eb2, ws, Y0, Y1);
  k_gemm<1><<<dim3(128, 1), 256, 0, stream>>>(Y0, Y1, ws + OFF_WC, nullptr, ws + OFF_MH, nullptr);
  k_gemm<2><<<dim3(4, 4, 32), 256, 0, stream>>>(ws + OFF_MH, nullptr, enc, nullptr, out, nullptr);
  k_softmax<<<4096, 256, 0, stream>>>(out, mask);
}

// Round 6
// 160.510 us; speedup vs baseline: 5.6542x; 1.1814x over previous
//
#include <hip/hip_runtime.h>

// ---------------------------------------------------------------------------
// KP_Decoder: hypernet -> (k,v,q) -> attention -> top2 MoE -> combine softmax
// B=32 G=512 N=512 EMB=128 H=8 DK=16 E=8 FH=512 K=2
// R2: k_gate block-aggregated routing.
// R3: k_moe bf16 MFMA (16x16x32), XOR-swizzled LDS.
// R4: k_attn bf16 MFMA flash attention (S^T orientation), XCD-aware mapping.
// R5: k_attn 512 threads; k_gemm<0> emits bf16 K/V.
// R6: k_attn q-split (512 blocks -> all CUs); k_gemm2f = bf16 MFMA sc-GEMM
//     with fused fixed-max tanh-softmax (k_softmax deleted); mh/enc in bf16.
// ---------------------------------------------------------------------------

typedef __attribute__((ext_vector_type(8))) __bf16 bf16x8;
typedef __attribute__((ext_vector_type(4))) float f32x4;

// ws layout (float offsets)
static constexpr long OFF_MID   = 0;        // 8
static constexpr long OFF_PREFL = 8;        // 8
static constexpr long OFF_WQ    = 64;       // 128x129 = 16512
static constexpr long OFF_WK    = 16576;    // 128x128
static constexpr long OFF_WV    = 32960;    // 128x128
static constexpr long OFF_WC    = 49344;    // 128x128
static constexpr long OFF_QB    = 65728;    // 32x128 qbase
static constexpr long OFF_CNT   = 69824;    // 8 ints
static constexpr long OFF_TOK   = 69888;    // 8*16384 ints
static constexpr long OFF_WGT   = 200960;   // 8*16384 floats
static constexpr long OFF_AO    = 332288;   // 16384x128 fp32 attention out
static constexpr long OFF_MH    = 2429440;  // 16384x128 bf16 mh (1,048,576 floats)
static constexpr long OFF_ENCB  = 3478016;  // 16384x128 bf16 enc (1,048,576 floats)
// total = 4,526,592 floats = 18.1 MB (unchanged)

__device__ __forceinline__ unsigned f2bf(float x) {
  union { float f; unsigned u; } v; v.f = x;
  return ((v.u + 0x7FFFu + ((v.u >> 16) & 1u)) >> 16) & 0xFFFFu;
}

// ---------------- hypernet: mid + pref gate logits -------------------------
__global__ __launch_bounds__(256)
void k_hyper(const float* __restrict__ pref, const float* __restrict__ fc1w,
             const float* __restrict__ fc1b, const float* __restrict__ fc2w,
             const float* __restrict__ fc2b, const float* __restrict__ fc3w,
             const float* __restrict__ fc3b, const float* __restrict__ gpw,
             float* __restrict__ ws) {
  __shared__ float h1[256];
  __shared__ float h2[256];
  __shared__ float mid[8];
  const int t = threadIdx.x;
  const float p0 = pref[0], p1 = pref[1];
  h1[t] = fc1w[2*t]*p0 + fc1w[2*t+1]*p1 + fc1b[t];
  __syncthreads();
  float s = 0.f;
  for (int j = 0; j < 256; ++j) s = fmaf(fc2w[t*256+j], h1[j], s);
  h2[t] = s + fc2b[t];
  __syncthreads();
  if (t < 8) {
    float s2 = 0.f;
    for (int j = 0; j < 256; ++j) s2 = fmaf(fc3w[t*256+j], h2[j], s2);
    mid[t] = s2 + fc3b[t];
    ws[OFF_MID + t] = mid[t];
  }
  __syncthreads();
  if (t < 8) {
    float s3 = 0.f;
    for (int i = 0; i < 8; ++i) s3 = fmaf(mid[i], gpw[i*8 + t], s3);
    ws[OFF_PREFL + t] = s3;
  }
}

// ---------------- hypernet heads: Wq/Wk/Wv/Wc ------------------------------
__global__ __launch_bounds__(256)
void k_hyperw(const float* __restrict__ hWq, const float* __restrict__ hWk,
              const float* __restrict__ hWv, const float* __restrict__ hWc,
              float* __restrict__ ws) {
  const int i = blockIdx.x*256 + threadIdx.x;
  const float m0 = ws[0], m1 = ws[1], m2 = ws[2], m3 = ws[3],
              m4 = ws[4], m5 = ws[5], m6 = ws[6], m7 = ws[7];
  if (i < 16512) {
    ws[OFF_WQ + i] = hWq[2*i]*m0 + hWq[2*i+1]*m1;
  } else if (i < 32896) {
    const int j = i - 16512;
    ws[OFF_WK + j] = hWk[2*j]*m2 + hWk[2*j+1]*m3;
  } else if (i < 49280) {
    const int j = i - 32896;
    ws[OFF_WV + j] = hWv[2*j]*m4 + hWv[2*j+1]*m5;
  } else if (i < 65664) {
    const int j = i - 49280;
    ws[OFF_WC + j] = hWc[2*j]*m6 + hWc[2*j+1]*m7;
  }
}

// ---------------- bf16 conversions: MoE weights + enc ----------------------
__global__ __launch_bounds__(256)
void k_cvt(const float* __restrict__ ew1, const float* __restrict__ ew2,
           const float* __restrict__ enc,
           unsigned short* __restrict__ w1b, unsigned short* __restrict__ w2b,
           unsigned short* __restrict__ encb) {
  const int i = blockIdx.x*256 + threadIdx.x;   // one float4 per thread
  const float* src;
  unsigned short* dst;
  if (i < 131072)      { src = ew1 + (long)i*4;          dst = w1b + (long)i*4; }
  else if (i < 262144) { src = ew2 + (long)(i-131072)*4; dst = w2b + (long)(i-131072)*4; }
  else                 { src = enc + (long)(i-262144)*4; dst = encb + (long)(i-262144)*4; }
  const float4 v = *(const float4*)src;
  uint2 p;
  p.x = f2bf(v.x) | (f2bf(v.y) << 16);
  p.y = f2bf(v.z) | (f2bf(v.w) << 16);
  *(uint2*)dst = p;
}

// ---------------- qbase[b][o] = graph[b] . Wq[o,0:128] ---------------------
__global__ __launch_bounds__(128)
void k_qbase(const float* __restrict__ graph, float* __restrict__ ws) {
  __shared__ float g[128];
  const int b = blockIdx.x, t = threadIdx.x;
  g[t] = graph[b*128 + t];
  __syncthreads();
  const float* wq = ws + OFF_WQ + (long)t*129;
  float s = 0.f;
  for (int i = 0; i < 128; ++i) s = fmaf(g[i], wq[i], s);
  ws[OFF_QB + b*128 + t] = s;
}

// ---------------- fp32 GEMM, C(bf16) = A @ B^T, K=128 ----------------------
// MODE 0: kv grid(128,2): A=enc, B={Wk,Wv}, C bf16 {K,V}
// MODE 1: mh grid(128,1): A=Y0+Y1, B=Wc, C bf16 MH
template <int MODE>
__global__ __launch_bounds__(256)
void k_gemm(const float* __restrict__ A, const float* __restrict__ A2,
            const float* __restrict__ B0, const float* __restrict__ B1,
            unsigned short* __restrict__ C0, unsigned short* __restrict__ C1) {
  constexpr int LDT = 132;
  __shared__ float As[32][LDT];
  __shared__ float Bs[32][LDT];
  const int tid = threadIdx.x;
  const int bx = blockIdx.x;
  const float* Ap = A + (long)bx*128*128;
  const float* Ap2 = nullptr;
  const float* Bp;
  if constexpr (MODE == 0) {
    Bp = blockIdx.y ? B1 : B0;
  } else {
    Ap2 = A2 + (long)bx*128*128;
    Bp = B0;
  }
  float acc[8][8];
#pragma unroll
  for (int i = 0; i < 8; ++i)
#pragma unroll
    for (int j = 0; j < 8; ++j) acc[i][j] = 0.f;
  const int tm = (tid >> 4) * 8;
  const int tn = (tid & 15) * 8;
  for (int kt = 0; kt < 4; ++kt) {
    __syncthreads();
#pragma unroll
    for (int r = 0; r < 4; ++r) {
      const int id = tid + r*256;
      const int m = id >> 3, kq = id & 7;
      float4 av = *(const float4*)(Ap + (long)m*128 + kt*32 + kq*4);
      if constexpr (MODE == 1) {
        const float4 a2 = *(const float4*)(Ap2 + (long)m*128 + kt*32 + kq*4);
        av.x += a2.x; av.y += a2.y; av.z += a2.z; av.w += a2.w;
      }
      As[kq*4+0][m] = av.x; As[kq*4+1][m] = av.y;
      As[kq*4+2][m] = av.z; As[kq*4+3][m] = av.w;
      const float4 bv = *(const float4*)(Bp + (long)m*128 + kt*32 + kq*4);
      Bs[kq*4+0][m] = bv.x; Bs[kq*4+1][m] = bv.y;
      Bs[kq*4+2][m] = bv.z; Bs[kq*4+3][m] = bv.w;
    }
    __syncthreads();
#pragma unroll
    for (int kk = 0; kk < 32; ++kk) {
      float a[8], b[8];
      *(float4*)&a[0] = *(const float4*)&As[kk][tm];
      *(float4*)&a[4] = *(const float4*)&As[kk][tm+4];
      *(float4*)&b[0] = *(const float4*)&Bs[kk][tn];
      *(float4*)&b[4] = *(const float4*)&Bs[kk][tn+4];
#pragma unroll
      for (int i = 0; i < 8; ++i)
#pragma unroll
        for (int j = 0; j < 8; ++j) acc[i][j] = fmaf(a[i], b[j], acc[i][j]);
    }
  }
  unsigned short* Cp;
  if constexpr (MODE == 0) Cp = (blockIdx.y ? C1 : C0) + (long)bx*128*128;
  else                     Cp = C0 + (long)bx*128*128;
#pragma unroll
  for (int i = 0; i < 8; ++i) {
    uint4 p;
    p.x = f2bf(acc[i][0]) | (f2bf(acc[i][1]) << 16);
    p.y = f2bf(acc[i][2]) | (f2bf(acc[i][3]) << 16);
    p.z = f2bf(acc[i][4]) | (f2bf(acc[i][5]) << 16);
    p.w = f2bf(acc[i][6]) | (f2bf(acc[i][7]) << 16);
    *(uint4*)(Cp + (long)(tm+i)*128 + tn) = p;
  }
}

// ---------------- MFMA flash attention, q-split, 8 waves -------------------
// grid 512: b = bid&31, h = (bid>>5)&7, qh = bid>>8; block owns 256 q-rows.
__global__ __launch_bounds__(512)
void k_attn(const unsigned short* __restrict__ Kb,
            const unsigned short* __restrict__ Vb,
            const float* __restrict__ ws, const float* __restrict__ cap,
            const float* __restrict__ mask, float* __restrict__ AO) {
  const int bid = blockIdx.x;
  const int b = bid & 31, h = (bid >> 5) & 7, qh = bid >> 8;
  __shared__ unsigned short Kbf[512*24];  // 24 KB
  __shared__ unsigned short Vt[16*536];   // 16.75 KB
  __shared__ unsigned short Ps[8*16*136]; // 34 KB
  const int tid = threadIdx.x;
#pragma unroll
  for (int it = 0; it < 2; ++it) {
    const int i = tid + it*512;           // 0..1023
    const int n = i >> 1, hf = i & 1;
    const long src = (long)(b*512 + n)*128 + h*16 + hf*8;
    const uint4 kv = *(const uint4*)(Kb + src);
    *(uint4*)(Kbf + n*24 + hf*8) = kv;
    const uint4 vv = *(const uint4*)(Vb + src);
    const unsigned short* sp = (const unsigned short*)&vv;
#pragma unroll
    for (int j = 0; j < 8; ++j) Vt[(hf*8 + j)*536 + n] = sp[j];
  }
  const int w = tid >> 6, l = tid & 63;
  const int lq = l >> 4, lr = l & 15;
  float qb8[8], wl8[8];
  if (lq < 2) {
    const float* qbp = ws + OFF_QB + b*128 + h*16 + lq*8;
    const float* wqp = ws + OFF_WQ;
#pragma unroll
    for (int j = 0; j < 8; ++j) {
      qb8[j] = qbp[j];
      wl8[j] = wqp[(h*16 + lq*8 + j)*129 + 128];
    }
  }
  unsigned short* Pw = Ps + w*16*136;
  __syncthreads();
  const float SC = 0.25f;
  for (int qb = 0; qb < 2; ++qb) {
    const int grow = qh*256 + w*32 + qb*16 + lr;   // this lane's q-row
    bf16x8 qf;
    {
      union { uint4 u; bf16x8 v; } cv;
      cv.u = make_uint4(0u, 0u, 0u, 0u);
      if (lq < 2) {
        const float cp = cap[b*512 + grow];
        float qv[8];
#pragma unroll
        for (int j = 0; j < 8; ++j) qv[j] = (qb8[j] + cp*wl8[j]) * SC;
        cv.u.x = f2bf(qv[0]) | (f2bf(qv[1]) << 16);
        cv.u.y = f2bf(qv[2]) | (f2bf(qv[3]) << 16);
        cv.u.z = f2bf(qv[4]) | (f2bf(qv[5]) << 16);
        cv.u.w = f2bf(qv[6]) | (f2bf(qv[7]) << 16);
      }
      qf = cv.v;
    }
    float m = -3.0e38f, lsum = 0.f;
    f32x4 oacc = {0.f, 0.f, 0.f, 0.f};
    const float* mrow = mask + ((long)(b*512 + grow))*512 + lq*4;
    for (int ch = 0; ch < 4; ++ch) {
      const int n0 = ch*128;
      f32x4 s[8];
#pragma unroll
      for (int nb = 0; nb < 8; ++nb) {
        bf16x8 kf;
        {
          union { uint4 u; bf16x8 v; } cv;
          cv.u = make_uint4(0u, 0u, 0u, 0u);
          if (lq < 2) cv.u = *(const uint4*)(Kbf + (n0 + nb*16 + lr)*24 + lq*8);
          kf = cv.v;
        }
        s[nb] = __builtin_amdgcn_mfma_f32_16x16x32_bf16(
            kf, qf, (f32x4){0.f, 0.f, 0.f, 0.f}, 0, 0, 0);
        const float4 mk = *(const float4*)(mrow + n0 + nb*16);
        s[nb][0] += mk.x; s[nb][1] += mk.y; s[nb][2] += mk.z; s[nb][3] += mk.w;
      }
      f32x4 mx = s[0];
#pragma unroll
      for (int nb = 1; nb < 8; ++nb) {
        mx[0] = fmaxf(mx[0], s[nb][0]); mx[1] = fmaxf(mx[1], s[nb][1]);
        mx[2] = fmaxf(mx[2], s[nb][2]); mx[3] = fmaxf(mx[3], s[nb][3]);
      }
      float cm = fmaxf(fmaxf(mx[0], mx[1]), fmaxf(mx[2], mx[3]));
      cm = fmaxf(cm, __shfl_xor(cm, 16));
      cm = fmaxf(cm, __shfl_xor(cm, 32));
      const float nm = fmaxf(m, cm);
      const float rs = __expf(m - nm);
      lsum *= rs;
      oacc[0] *= rs; oacc[1] *= rs; oacc[2] *= rs; oacc[3] *= rs;
      m = nm;
      float ls = 0.f;
#pragma unroll
      for (int nb = 0; nb < 8; ++nb) {
        const float p0 = __expf(s[nb][0] - m);
        const float p1 = __expf(s[nb][1] - m);
        const float p2 = __expf(s[nb][2] - m);
        const float p3 = __expf(s[nb][3] - m);
        ls += (p0 + p1) + (p2 + p3);
        uint2 pp;
        asm("v_cvt_pk_bf16_f32 %0, %1, %2" : "=v"(pp.x) : "v"(p0), "v"(p1));
        asm("v_cvt_pk_bf16_f32 %0, %1, %2" : "=v"(pp.y) : "v"(p2), "v"(p3));
        *(uint2*)(Pw + lr*136 + nb*16 + lq*4) = pp;
      }
      lsum += ls;
#pragma unroll
      for (int ks = 0; ks < 4; ++ks) {
        const bf16x8 va = *(const bf16x8*)(Vt + lr*536 + n0 + ks*32 + lq*8);
        const bf16x8 pb = *(const bf16x8*)(Pw + lr*136 + ks*32 + lq*8);
        oacc = __builtin_amdgcn_mfma_f32_16x16x32_bf16(va, pb, oacc, 0, 0, 0);
      }
    }
    lsum += __shfl_xor(lsum, 16);
    lsum += __shfl_xor(lsum, 32);
    const float inv = 1.f / lsum;
    float4 o;
    o.x = oacc[0]*inv; o.y = oacc[1]*inv; o.z = oacc[2]*inv; o.w = oacc[3]*inv;
    *(float4*)(AO + (long)(b*512 + grow)*128 + h*16 + lq*4) = o;
  }
}

// ---------------- gating: top-2 + expert lists (block-aggregated) ----------
__global__ __launch_bounds__(256)
void k_gate(const float* __restrict__ AO, const float* __restrict__ gw,
            float* __restrict__ ws) {
  const int tid = threadIdx.x;
  const int t = blockIdx.x*256 + tid;
  const float* x = AO + (long)t*128;
  float lg[8];
  {
    const float* pl = ws + OFF_PREFL;
#pragma unroll
    for (int e = 0; e < 8; ++e) lg[e] = pl[e];
  }
  for (int i = 0; i < 128; i += 4) {
    const float4 xv = *(const float4*)(x + i);
#pragma unroll
    for (int u = 0; u < 4; ++u) {
      const float xi = (&xv.x)[u];
      const float4 ga = *(const float4*)(gw + (i+u)*8);
      const float4 gb = *(const float4*)(gw + (i+u)*8 + 4);
      lg[0] = fmaf(xi, ga.x, lg[0]); lg[1] = fmaf(xi, ga.y, lg[1]);
      lg[2] = fmaf(xi, ga.z, lg[2]); lg[3] = fmaf(xi, ga.w, lg[3]);
      lg[4] = fmaf(xi, gb.x, lg[4]); lg[5] = fmaf(xi, gb.y, lg[5]);
      lg[6] = fmaf(xi, gb.z, lg[6]); lg[7] = fmaf(xi, gb.w, lg[7]);
    }
  }
  int i0 = 0; float v0 = lg[0];
#pragma unroll
  for (int e = 1; e < 8; ++e) if (lg[e] > v0) { v0 = lg[e]; i0 = e; }
  int i1 = -1; float v1 = -1e30f;
#pragma unroll
  for (int e = 0; e < 8; ++e) if (e != i0 && lg[e] > v1) { v1 = lg[e]; i1 = e; }
  const float e1 = __expf(v1 - v0);
  const float w0 = 1.f / (1.f + e1);
  const float w1 = 1.f - w0;
  __shared__ int bcnt[8];
  __shared__ int gbase[8];
  if (tid < 8) bcnt[tid] = 0;
  __syncthreads();
  const int p0 = atomicAdd(&bcnt[i0], 1);
  const int p1 = atomicAdd(&bcnt[i1], 1);
  __syncthreads();
  if (tid < 8) {
    int* cnt = (int*)(ws + OFF_CNT);
    gbase[tid] = (bcnt[tid] > 0) ? atomicAdd(&cnt[tid], bcnt[tid]) : 0;
  }
  __syncthreads();
  int* tokp = (int*)(ws + OFF_TOK);
  float* wgtp = ws + OFF_WGT;
  const int s0 = gbase[i0] + p0;
  tokp[i0*16384 + s0] = t;             // rank 0
  wgtp[i0*16384 + s0] = w0;
  const int s1 = gbase[i1] + p1;
  tokp[i1*16384 + s1] = t | (1 << 30); // rank 1
  wgtp[i1*16384 + s1] = w1;
}

// ---------------- MoE experts: bf16 MFMA, per (expert, 64-token chunk) -----
__device__ __forceinline__ bf16x8 ld_frag(const unsigned short* base, int row, int bytecol) {
  const int addr = row*256 + (bytecol ^ ((row & 7) << 4));
  return *(const bf16x8*)((const char*)base + addr);
}

__global__ __launch_bounds__(256)
void k_moe(const float* __restrict__ AO,
           const unsigned short* __restrict__ w1b,
           const unsigned short* __restrict__ w2b,
           const float* __restrict__ eb1, const float* __restrict__ eb2,
           float* __restrict__ ws,
           float* __restrict__ Y0, float* __restrict__ Y1) {
  const int e = blockIdx.y;
  const int ce = ((const int*)(ws + OFF_CNT))[e];
  const int base = blockIdx.x * 64;
  if (base >= ce) return;
  const int nt = min(64, ce - base);

  __shared__ unsigned short Xs[64*128];
  __shared__ unsigned short Wts[128*128];
  __shared__ unsigned short Hs[64*128];
  __shared__ float seb1[512];
  __shared__ float seb2[128];
  __shared__ int   stok[64];
  __shared__ float swgt[64];

  const int tid = threadIdx.x;
  if (tid < 64) {
    if (tid < nt) {
      stok[tid] = ((const int*)(ws + OFF_TOK))[e*16384 + base + tid];
      swgt[tid] = (ws + OFF_WGT)[e*16384 + base + tid];
    } else { stok[tid] = -1; swgt[tid] = 0.f; }
  }
  for (int i = tid; i < 512; i += 256) seb1[i] = eb1[e*512 + i];
  if (tid < 128) seb2[tid] = eb2[e*128 + tid];
  __syncthreads();

#pragma unroll
  for (int r8 = 0; r8 < 8; ++r8) {
    const int id = tid + r8*256;
    const int r = id >> 5, c = id & 31;
    const int pk = stok[r];
    float4 xv = make_float4(0.f, 0.f, 0.f, 0.f);
    if (pk >= 0) xv = *(const float4*)(AO + (long)(pk & 0x3FFFFFFF)*128 + c*4);
    uint2 pkd;
    pkd.x = f2bf(xv.x) | (f2bf(xv.y) << 16);
    pkd.y = f2bf(xv.z) | (f2bf(xv.w) << 16);
    const int bc = (c*8) ^ ((r & 7) << 4);
    *(uint2*)((char*)Xs + r*256 + bc) = pkd;
  }

  const int w  = tid >> 6;
  const int l  = tid & 63;
  const int lq = l >> 4;
  const int lr = l & 15;

  f32x4 yacc[2][4];
#pragma unroll
  for (int a = 0; a < 2; ++a)
#pragma unroll
    for (int m = 0; m < 4; ++m) yacc[a][m] = (f32x4){0.f, 0.f, 0.f, 0.f};

  for (int fc = 0; fc < 4; ++fc) {
    __syncthreads();
    {
      const long wb = (long)(e*512 + fc*128) * 128;
#pragma unroll
      for (int s = 0; s < 8; ++s) {
        const int id = tid + s*256;
        const int fr = id >> 4, c16 = id & 15;
        const uint4 v = *(const uint4*)(w1b + wb + (long)fr*128 + c16*8);
        *(uint4*)((char*)Wts + fr*256 + ((c16*16) ^ ((fr & 7) << 4))) = v;
      }
    }
    __syncthreads();
    f32x4 hacc[2][4];
#pragma unroll
    for (int a = 0; a < 2; ++a)
#pragma unroll
      for (int m = 0; m < 4; ++m) hacc[a][m] = (f32x4){0.f, 0.f, 0.f, 0.f};
#pragma unroll
    for (int ks = 0; ks < 4; ++ks) {
      const int bcol = ks*64 + lq*16;
      const bf16x8 a0 = ld_frag(Wts, (2*w  )*16 + lr, bcol);
      const bf16x8 a1 = ld_frag(Wts, (2*w+1)*16 + lr, bcol);
      const bf16x8 b0 = ld_frag(Xs,  0*16 + lr, bcol);
      const bf16x8 b1 = ld_frag(Xs,  1*16 + lr, bcol);
      const bf16x8 b2 = ld_frag(Xs,  2*16 + lr, bcol);
      const bf16x8 b3 = ld_frag(Xs,  3*16 + lr, bcol);
      hacc[0][0] = __builtin_amdgcn_mfma_f32_16x16x32_bf16(a0, b0, hacc[0][0], 0, 0, 0);
      hacc[0][1] = __builtin_amdgcn_mfma_f32_16x16x32_bf16(a0, b1, hacc[0][1], 0, 0, 0);
      hacc[0][2] = __builtin_amdgcn_mfma_f32_16x16x32_bf16(a0, b2, hacc[0][2], 0, 0, 0);
      hacc[0][3] = __builtin_amdgcn_mfma_f32_16x16x32_bf16(a0, b3, hacc[0][3], 0, 0, 0);
      hacc[1][0] = __builtin_amdgcn_mfma_f32_16x16x32_bf16(a1, b0, hacc[1][0], 0, 0, 0);
      hacc[1][1] = __builtin_amdgcn_mfma_f32_16x16x32_bf16(a1, b1, hacc[1][1], 0, 0, 0);
      hacc[1][2] = __builtin_amdgcn_mfma_f32_16x16x32_bf16(a1, b2, hacc[1][2], 0, 0, 0);
      hacc[1][3] = __builtin_amdgcn_mfma_f32_16x16x32_bf16(a1, b3, hacc[1][3], 0, 0, 0);
    }
    __syncthreads();
#pragma unroll
    for (int fbi = 0; fbi < 2; ++fbi) {
      const int fb = (2*w + fbi)*16 + lq*4;
      const float4 bia = *(const float4*)&seb1[fc*128 + fb];
#pragma unroll
      for (int mb = 0; mb < 4; ++mb) {
        const int m = mb*16 + lr;
        const float h0 = fmaxf(hacc[fbi][mb][0] + bia.x, 0.f);
        const float h1 = fmaxf(hacc[fbi][mb][1] + bia.y, 0.f);
        const float h2 = fmaxf(hacc[fbi][mb][2] + bia.z, 0.f);
        const float h3 = fmaxf(hacc[fbi][mb][3] + bia.w, 0.f);
        uint2 p;
        p.x = f2bf(h0) | (f2bf(h1) << 16);
        p.y = f2bf(h2) | (f2bf(h3) << 16);
        const int bc = (fb*2) ^ ((m & 7) << 4);
        *(uint2*)((char*)Hs + m*256 + bc) = p;
      }
    }
    {
      const long wb = (long)(e*128) * 512 + fc*128;
#pragma unroll
      for (int s = 0; s < 8; ++s) {
        const int id = tid + s*256;
        const int orr = id >> 4, c16 = id & 15;
        const uint4 v = *(const uint4*)(w2b + wb + (long)orr*512 + c16*8);
        *(uint4*)((char*)Wts + orr*256 + ((c16*16) ^ ((orr & 7) << 4))) = v;
      }
    }
    __syncthreads();
#pragma unroll
    for (int ks = 0; ks < 4; ++ks) {
      const int bcol = ks*64 + lq*16;
      const bf16x8 a0 = ld_frag(Wts, (2*w  )*16 + lr, bcol);
      const bf16x8 a1 = ld_frag(Wts, (2*w+1)*16 + lr, bcol);
      const bf16x8 b0 = ld_frag(Hs,  0*16 + lr, bcol);
      const bf16x8 b1 = ld_frag(Hs,  1*16 + lr, bcol);
      const bf16x8 b2 = ld_frag(Hs,  2*16 + lr, bcol);
      const bf16x8 b3 = ld_frag(Hs,  3*16 + lr, bcol);
      yacc[0][0] = __builtin_amdgcn_mfma_f32_16x16x32_bf16(a0, b0, yacc[0][0], 0, 0, 0);
      yacc[0][1] = __builtin_amdgcn_mfma_f32_16x16x32_bf16(a0, b1, yacc[0][1], 0, 0, 0);
      yacc[0][2] = __builtin_amdgcn_mfma_f32_16x16x32_bf16(a0, b2, yacc[0][2], 0, 0, 0);
      yacc[0][3] = __builtin_amdgcn_mfma_f32_16x16x32_bf16(a0, b3, yacc[0][3], 0, 0, 0);
      yacc[1][0] = __builtin_amdgcn_mfma_f32_16x16x32_bf16(a1, b0, yacc[1][0], 0, 0, 0);
      yacc[1][1] = __builtin_amdgcn_mfma_f32_16x16x32_bf16(a1, b1, yacc[1][1], 0, 0, 0);
      yacc[1][2] = __builtin_amdgcn_mfma_f32_16x16x32_bf16(a1, b2, yacc[1][2], 0, 0, 0);
      yacc[1][3] = __builtin_amdgcn_mfma_f32_16x16x32_bf16(a1, b3, yacc[1][3], 0, 0, 0);
    }
  }
#pragma unroll
  for (int obi = 0; obi < 2; ++obi) {
    const int ob = (2*w + obi)*16 + lq*4;
    const float4 b2 = *(const float4*)&seb2[ob];
#pragma unroll
    for (int mb = 0; mb < 4; ++mb) {
      const int tl = mb*16 + lr;
      if (tl < nt) {
        const int pk = stok[tl];
        const int tk = pk & 0x3FFFFFFF;
        const float wgt = swgt[tl];
        float* Yp = ((pk >> 30) ? Y1 : Y0) + (long)tk*128 + ob;
        float4 o;
        o.x = (yacc[obi][mb][0] + b2.x) * wgt;
        o.y = (yacc[obi][mb][1] + b2.y) * wgt;
        o.z = (yacc[obi][mb][2] + b2.z) * wgt;
        o.w = (yacc[obi][mb][3] + b2.w) * wgt;
        *(float4*)Yp = o;
      }
    }
  }
}

// ---------------- fused sc GEMM + tanh + fixed-max softmax -----------------
// grid 256: b = bid&31, rt = bid>>5. Block: rows 64 (M), cols 512 (N), K=128.
// probs = exp(10*tanh(mh.enc/sqrt128) + mask - 10) / rowsum.
__global__ __launch_bounds__(512)
void k_gemm2f(const unsigned short* __restrict__ mhb,
              const unsigned short* __restrict__ encb,
              const float* __restrict__ mask,
              float* __restrict__ out) {
  const int bid = blockIdx.x;
  const int b = bid & 31, rt = bid >> 5;
  __shared__ unsigned short Amh[64*128];   // 16 KB, 256B swizzled rows
  __shared__ unsigned short Bch[512*32];   // 32 KB, 64B swizzled rows (k-chunk)
  __shared__ float red[64][9];
  const int tid = threadIdx.x;
  const int w = tid >> 6, l = tid & 63, lq = l >> 4, lr = l & 15;
  const long rowbase = (long)b*512 + rt*64;
  // stage A (mh rows)
#pragma unroll
  for (int s = 0; s < 2; ++s) {
    const int id = tid + s*512;
    const int r = id >> 4, c16 = id & 15;
    const uint4 v = *(const uint4*)(mhb + (rowbase + r)*128 + c16*8);
    *(uint4*)((char*)Amh + r*256 + ((c16*16) ^ ((r & 7) << 4))) = v;
  }
  f32x4 acc[4][4];
#pragma unroll
  for (int mi = 0; mi < 4; ++mi)
#pragma unroll
    for (int ni = 0; ni < 4; ++ni) acc[mi][ni] = (f32x4){0.f, 0.f, 0.f, 0.f};
  for (int kc = 0; kc < 4; ++kc) {
    __syncthreads();
#pragma unroll
    for (int s = 0; s < 4; ++s) {
      const int id = tid + s*512;         // 0..2047
      const int n = id >> 2, sl = id & 3;
      const uint4 v = *(const uint4*)(encb + ((long)b*512 + n)*128 + kc*32 + sl*8);
      *(uint4*)((char*)Bch + n*64 + ((sl*16) ^ ((n & 3) << 4))) = v;
    }
    __syncthreads();
    bf16x8 af[4], bfr[4];
#pragma unroll
    for (int mi = 0; mi < 4; ++mi) {
      const int r = mi*16 + lr;
      af[mi] = *(const bf16x8*)((const char*)Amh + r*256 + ((kc*64 + lq*16) ^ ((r & 7) << 4)));
    }
#pragma unroll
    for (int ni = 0; ni < 4; ++ni) {
      const int n = w*64 + ni*16 + lr;
      bfr[ni] = *(const bf16x8*)((const char*)Bch + n*64 + ((lq*16) ^ ((n & 3) << 4)));
    }
#pragma unroll
    for (int mi = 0; mi < 4; ++mi)
#pragma unroll
      for (int ni = 0; ni < 4; ++ni)
        acc[mi][ni] = __builtin_amdgcn_mfma_f32_16x16x32_bf16(af[mi], bfr[ni], acc[mi][ni], 0, 0, 0);
  }
  // epilogue: exp(10*tanh(sc)+mask-10), in place
  const float ISC = 1.f/11.313708498984761f;
  float rsum[4][4];
#pragma unroll
  for (int mi = 0; mi < 4; ++mi)
#pragma unroll
    for (int j = 0; j < 4; ++j) rsum[mi][j] = 0.f;
#pragma unroll
  for (int mi = 0; mi < 4; ++mi) {
#pragma unroll
    for (int j = 0; j < 4; ++j) {
      const long row = rowbase + mi*16 + lq*4 + j;
      const float* mrow = mask + row*512 + w*64 + lr;
#pragma unroll
      for (int ni = 0; ni < 4; ++ni) {
        const float sc = acc[mi][ni][j] * ISC;
        const float li = 10.f*tanhf(sc) + mrow[ni*16];
        const float e = __expf(li - 10.f);
        acc[mi][ni][j] = e;
        rsum[mi][j] += e;
      }
    }
  }
#pragma unroll
  for (int mi = 0; mi < 4; ++mi)
#pragma unroll
    for (int j = 0; j < 4; ++j) {
#pragma unroll
      for (int o = 1; o < 16; o <<= 1) rsum[mi][j] += __shfl_xor(rsum[mi][j], o);
    }
  if (lr == 0) {
#pragma unroll
    for (int mi = 0; mi < 4; ++mi)
#pragma unroll
      for (int j = 0; j < 4; ++j) red[mi*16 + lq*4 + j][w] = rsum[mi][j];
  }
  __syncthreads();
  if (tid < 64) {
    float s = 0.f;
#pragma unroll
    for (int wv = 0; wv < 8; ++wv) s += red[tid][wv];
    red[tid][8] = 1.f / s;
  }
  __syncthreads();
#pragma unroll
  for (int mi = 0; mi < 4; ++mi) {
#pragma unroll
    for (int j = 0; j < 4; ++j) {
      const int rl = mi*16 + lq*4 + j;
      const float inv = red[rl][8];
      float* orow = out + (rowbase + rl)*512 + w*64 + lr;
#pragma unroll
      for (int ni = 0; ni < 4; ++ni) orow[ni*16] = acc[mi][ni][j] * inv;
    }
  }
}

// ---------------------------------------------------------------------------
extern "C" void kernel_launch(void* const* d_in, const int* in_sizes, int n_in,
                              void* d_out, int out_size, void* d_ws, size_t ws_size,
                              hipStream_t stream) {
  (void)in_sizes; (void)n_in; (void)out_size; (void)ws_size;
  const float* pref  = (const float*)d_in[0];
  const float* graph = (const float*)d_in[1];
  const float* cap   = (const float*)d_in[2];
  const float* enc   = (const float*)d_in[3];
  const float* mask  = (const float*)d_in[4];
  const float* fc1w  = (const float*)d_in[5];
  const float* fc1b  = (const float*)d_in[6];
  const float* fc2w  = (const float*)d_in[7];
  const float* fc2b  = (const float*)d_in[8];
  const float* fc3w  = (const float*)d_in[9];
  const float* fc3b  = (const float*)d_in[10];
  const float* hWq   = (const float*)d_in[11];
  const float* hWk   = (const float*)d_in[12];
  const float* hWv   = (const float*)d_in[13];
  const float* hWc   = (const float*)d_in[14];
  const float* gw    = (const float*)d_in[15];
  const float* gpw   = (const float*)d_in[16];
  const float* ew1   = (const float*)d_in[17];
  const float* eb1   = (const float*)d_in[18];
  const float* ew2   = (const float*)d_in[19];
  const float* eb2   = (const float*)d_in[20];
  float* ws  = (float*)d_ws;
  float* out = (float*)d_out;
  // d_out scratch: Kb/Vb bf16 in [0,8MB) -> dead after attn; Y0 [0,8MB),
  // Y1 [8,16MB); ew1b [16,17MB), ew2b [17,18MB). k_gemm2f overwrites all.
  unsigned short* Kbuf = (unsigned short*)out;
  unsigned short* Vbuf = (unsigned short*)(out + 1048576);
  float* Y0 = out;
  float* Y1 = out + 2097152;
  unsigned short* ew1b = (unsigned short*)(out + 4194304);
  unsigned short* ew2b = (unsigned short*)(out + 4456448);
  unsigned short* mhb  = (unsigned short*)(ws + OFF_MH);
  unsigned short* encb = (unsigned short*)(ws + OFF_ENCB);

  hipMemsetAsync((char*)d_ws + OFF_CNT*sizeof(float), 0, 8*sizeof(int), stream);
  k_cvt<<<3072, 256, 0, stream>>>(ew1, ew2, enc, ew1b, ew2b, encb);
  k_hyper<<<1, 256, 0, stream>>>(pref, fc1w, fc1b, fc2w, fc2b, fc3w, fc3b, gpw, ws);
  k_hyperw<<<257, 256, 0, stream>>>(hWq, hWk, hWv, hWc, ws);
  k_qbase<<<32, 128, 0, stream>>>(graph, ws);
  k_gemm<0><<<dim3(128, 2), 256, 0, stream>>>(enc, nullptr, ws + OFF_WK, ws + OFF_WV, Kbuf, Vbuf);
  k_attn<<<512, 512, 0, stream>>>(Kbuf, Vbuf, ws, cap, mask, ws + OFF_AO);
  k_gate<<<64, 256, 0, stream>>>(ws + OFF_AO, gw, ws);
  k_moe<<<dim3(256, 8), 256, 0, stream>>>(ws + OFF_AO, ew1b, ew2b, eb1, eb2, ws, Y0, Y1);
  k_gemm<1><<<dim3(128, 1), 256, 0, stream>>>(Y0, Y1, ws + OFF_WC, nullptr, mhb, nullptr);
  k_gemm2f<<<256, 512, 0, stream>>>(mhb, encb, mask, out);
}

// Round 7
// 132.579 us; speedup vs baseline: 6.8454x; 1.2107x over previous
//
#include <hip/hip_runtime.h>

// ---------------------------------------------------------------------------
// KP_Decoder: hypernet -> (k,v,q) -> attention -> top2 MoE -> combine softmax
// B=32 G=512 N=512 EMB=128 H=8 DK=16 E=8 FH=512 K=2
// R3: k_moe bf16 MFMA. R4: MFMA flash attn. R5: 8-wave attn, bf16 K/V.
// R6: attn q-split; k_gemm2f fused fixed-max tanh-softmax.
// R7: k_kv/k_mh bf16 MFMA (fp32 VALU GEMMs gone); attn mask reg-prefetch.
// ---------------------------------------------------------------------------

typedef __attribute__((ext_vector_type(8))) __bf16 bf16x8;
typedef __attribute__((ext_vector_type(4))) float f32x4;

// ws layout (float offsets)
static constexpr long OFF_MID   = 0;        // 8
static constexpr long OFF_PREFL = 8;        // 8
static constexpr long OFF_WQ    = 64;       // 128x129 fp32 = 16512
static constexpr long OFF_WKB   = 16576;    // 128x128 bf16 (8192 floats)
static constexpr long OFF_WVB   = 24768;    // 128x128 bf16
static constexpr long OFF_WCB   = 32960;    // 128x128 bf16
static constexpr long OFF_QB    = 65728;    // 32x128 qbase fp32
static constexpr long OFF_CNT   = 69824;    // 8 ints
static constexpr long OFF_TOK   = 69888;    // 8*16384 ints
static constexpr long OFF_WGT   = 200960;   // 8*16384 floats
static constexpr long OFF_AO    = 332288;   // 16384x128 fp32 attention out
static constexpr long OFF_MH    = 2429440;  // 16384x128 bf16 mh
static constexpr long OFF_ENCB  = 3478016;  // 16384x128 bf16 enc

__device__ __forceinline__ unsigned f2bf(float x) {
  union { float f; unsigned u; } v; v.f = x;
  return ((v.u + 0x7FFFu + ((v.u >> 16) & 1u)) >> 16) & 0xFFFFu;
}

// ---------------- hypernet: mid + pref gate logits -------------------------
__global__ __launch_bounds__(256)
void k_hyper(const float* __restrict__ pref, const float* __restrict__ fc1w,
             const float* __restrict__ fc1b, const float* __restrict__ fc2w,
             const float* __restrict__ fc2b, const float* __restrict__ fc3w,
             const float* __restrict__ fc3b, const float* __restrict__ gpw,
             float* __restrict__ ws) {
  __shared__ float h1[256];
  __shared__ float h2[256];
  __shared__ float mid[8];
  const int t = threadIdx.x;
  const float p0 = pref[0], p1 = pref[1];
  h1[t] = fc1w[2*t]*p0 + fc1w[2*t+1]*p1 + fc1b[t];
  __syncthreads();
  float s = 0.f;
  for (int j = 0; j < 256; ++j) s = fmaf(fc2w[t*256+j], h1[j], s);
  h2[t] = s + fc2b[t];
  __syncthreads();
  if (t < 8) {
    float s2 = 0.f;
    for (int j = 0; j < 256; ++j) s2 = fmaf(fc3w[t*256+j], h2[j], s2);
    mid[t] = s2 + fc3b[t];
    ws[OFF_MID + t] = mid[t];
  }
  __syncthreads();
  if (t < 8) {
    float s3 = 0.f;
    for (int i = 0; i < 8; ++i) s3 = fmaf(mid[i], gpw[i*8 + t], s3);
    ws[OFF_PREFL + t] = s3;
  }
}

// ---------------- hypernet heads: Wq fp32, Wk/Wv/Wc bf16 -------------------
__global__ __launch_bounds__(256)
void k_hyperw(const float* __restrict__ hWq, const float* __restrict__ hWk,
              const float* __restrict__ hWv, const float* __restrict__ hWc,
              float* __restrict__ ws) {
  const int i = blockIdx.x*256 + threadIdx.x;
  const float m0 = ws[0], m1 = ws[1], m2 = ws[2], m3 = ws[3],
              m4 = ws[4], m5 = ws[5], m6 = ws[6], m7 = ws[7];
  if (i < 16512) {
    ws[OFF_WQ + i] = hWq[2*i]*m0 + hWq[2*i+1]*m1;
  } else if (i < 32896) {
    const int j = i - 16512;
    ((unsigned short*)(ws + OFF_WKB))[j] = (unsigned short)f2bf(hWk[2*j]*m2 + hWk[2*j+1]*m3);
  } else if (i < 49280) {
    const int j = i - 32896;
    ((unsigned short*)(ws + OFF_WVB))[j] = (unsigned short)f2bf(hWv[2*j]*m4 + hWv[2*j+1]*m5);
  } else if (i < 65664) {
    const int j = i - 49280;
    ((unsigned short*)(ws + OFF_WCB))[j] = (unsigned short)f2bf(hWc[2*j]*m6 + hWc[2*j+1]*m7);
  }
}

// ---------------- bf16 conversions: MoE weights + enc ----------------------
__global__ __launch_bounds__(256)
void k_cvt(const float* __restrict__ ew1, const float* __restrict__ ew2,
           const float* __restrict__ enc,
           unsigned short* __restrict__ w1b, unsigned short* __restrict__ w2b,
           unsigned short* __restrict__ encb) {
  const int i = blockIdx.x*256 + threadIdx.x;   // one float4 per thread
  const float* src;
  unsigned short* dst;
  if (i < 131072)      { src = ew1 + (long)i*4;          dst = w1b + (long)i*4; }
  else if (i < 262144) { src = ew2 + (long)(i-131072)*4; dst = w2b + (long)(i-131072)*4; }
  else                 { src = enc + (long)(i-262144)*4; dst = encb + (long)(i-262144)*4; }
  const float4 v = *(const float4*)src;
  uint2 p;
  p.x = f2bf(v.x) | (f2bf(v.y) << 16);
  p.y = f2bf(v.z) | (f2bf(v.w) << 16);
  *(uint2*)dst = p;
}

// ---------------- qbase[b][o] = graph[b] . Wq[o,0:128] ---------------------
__global__ __launch_bounds__(128)
void k_qbase(const float* __restrict__ graph, float* __restrict__ ws) {
  __shared__ float g[128];
  const int b = blockIdx.x, t = threadIdx.x;
  g[t] = graph[b*128 + t];
  __syncthreads();
  const float* wq = ws + OFF_WQ + (long)t*129;
  float s = 0.f;
  for (int i = 0; i < 128; ++i) s = fmaf(g[i], wq[i], s);
  ws[OFF_QB + b*128 + t] = s;
}

// ---------------- shared swizzled-LDS fragment loader ----------------------
__device__ __forceinline__ bf16x8 ld_frag(const unsigned short* base, int row, int bytecol) {
  const int addr = row*256 + (bytecol ^ ((row & 7) << 4));
  return *(const bf16x8*)((const char*)base + addr);
}

// ---------------- k_kv: bf16 MFMA GEMM, {K,V}[n][o] = enc . W^T ------------
// grid (256, 2): 64 n-rows per block, by selects Wk/Wv and K/V output.
__global__ __launch_bounds__(256)
void k_kv(const unsigned short* __restrict__ encb,
          const unsigned short* __restrict__ wkb,
          const unsigned short* __restrict__ wvb,
          unsigned short* __restrict__ Kb, unsigned short* __restrict__ Vb) {
  __shared__ unsigned short Ws[128*128];  // 32KB
  __shared__ unsigned short Xs[64*128];   // 16KB
  const int tid = threadIdx.x;
  const int nbase = blockIdx.x * 64;
  const unsigned short* Wb = blockIdx.y ? wvb : wkb;
  unsigned short* Cb = blockIdx.y ? Vb : Kb;
#pragma unroll
  for (int s = 0; s < 8; ++s) {
    const int id = tid + s*256;
    const int fr = id >> 4, c16 = id & 15;
    const uint4 v = *(const uint4*)(Wb + (long)fr*128 + c16*8);
    *(uint4*)((char*)Ws + fr*256 + ((c16*16) ^ ((fr & 7) << 4))) = v;
  }
#pragma unroll
  for (int s = 0; s < 4; ++s) {
    const int id = tid + s*256;
    const int r = id >> 4, c16 = id & 15;
    const uint4 v = *(const uint4*)(encb + (long)(nbase + r)*128 + c16*8);
    *(uint4*)((char*)Xs + r*256 + ((c16*16) ^ ((r & 7) << 4))) = v;
  }
  __syncthreads();
  const int w = tid >> 6, l = tid & 63, lq = l >> 4, lr = l & 15;
  f32x4 acc[2][4];
#pragma unroll
  for (int a = 0; a < 2; ++a)
#pragma unroll
    for (int m = 0; m < 4; ++m) acc[a][m] = (f32x4){0.f, 0.f, 0.f, 0.f};
#pragma unroll
  for (int ks = 0; ks < 4; ++ks) {
    const int bcol = ks*64 + lq*16;
    const bf16x8 a0 = ld_frag(Ws, (2*w  )*16 + lr, bcol);
    const bf16x8 a1 = ld_frag(Ws, (2*w+1)*16 + lr, bcol);
    const bf16x8 b0 = ld_frag(Xs, 0*16 + lr, bcol);
    const bf16x8 b1 = ld_frag(Xs, 1*16 + lr, bcol);
    const bf16x8 b2 = ld_frag(Xs, 2*16 + lr, bcol);
    const bf16x8 b3 = ld_frag(Xs, 3*16 + lr, bcol);
    acc[0][0] = __builtin_amdgcn_mfma_f32_16x16x32_bf16(a0, b0, acc[0][0], 0, 0, 0);
    acc[0][1] = __builtin_amdgcn_mfma_f32_16x16x32_bf16(a0, b1, acc[0][1], 0, 0, 0);
    acc[0][2] = __builtin_amdgcn_mfma_f32_16x16x32_bf16(a0, b2, acc[0][2], 0, 0, 0);
    acc[0][3] = __builtin_amdgcn_mfma_f32_16x16x32_bf16(a0, b3, acc[0][3], 0, 0, 0);
    acc[1][0] = __builtin_amdgcn_mfma_f32_16x16x32_bf16(a1, b0, acc[1][0], 0, 0, 0);
    acc[1][1] = __builtin_amdgcn_mfma_f32_16x16x32_bf16(a1, b1, acc[1][1], 0, 0, 0);
    acc[1][2] = __builtin_amdgcn_mfma_f32_16x16x32_bf16(a1, b2, acc[1][2], 0, 0, 0);
    acc[1][3] = __builtin_amdgcn_mfma_f32_16x16x32_bf16(a1, b3, acc[1][3], 0, 0, 0);
  }
#pragma unroll
  for (int obi = 0; obi < 2; ++obi) {
    const int o0 = (2*w + obi)*16 + lq*4;
#pragma unroll
    for (int mb = 0; mb < 4; ++mb) {
      const long n = nbase + mb*16 + lr;
      uint2 pp;
      pp.x = f2bf(acc[obi][mb][0]) | (f2bf(acc[obi][mb][1]) << 16);
      pp.y = f2bf(acc[obi][mb][2]) | (f2bf(acc[obi][mb][3]) << 16);
      *(uint2*)(Cb + n*128 + o0) = pp;
    }
  }
}

// ---------------- k_mh: bf16 MFMA GEMM, mh[n][o] = (Y0+Y1) . Wc^T ----------
__global__ __launch_bounds__(256)
void k_mh(const float* __restrict__ Y0, const float* __restrict__ Y1,
          const unsigned short* __restrict__ wcb,
          unsigned short* __restrict__ mhb) {
  __shared__ unsigned short Ws[128*128];  // 32KB
  __shared__ unsigned short Xs[64*128];   // 16KB
  const int tid = threadIdx.x;
  const int nbase = blockIdx.x * 64;
#pragma unroll
  for (int s = 0; s < 8; ++s) {
    const int id = tid + s*256;
    const int fr = id >> 4, c16 = id & 15;
    const uint4 v = *(const uint4*)(wcb + (long)fr*128 + c16*8);
    *(uint4*)((char*)Ws + fr*256 + ((c16*16) ^ ((fr & 7) << 4))) = v;
  }
#pragma unroll
  for (int s = 0; s < 4; ++s) {
    const int id = tid + s*256;
    const int r = id >> 4, c16 = id & 15;
    const long base = (long)(nbase + r)*128 + c16*8;
    const float4 a0 = *(const float4*)(Y0 + base);
    const float4 a1 = *(const float4*)(Y0 + base + 4);
    const float4 b0 = *(const float4*)(Y1 + base);
    const float4 b1 = *(const float4*)(Y1 + base + 4);
    uint4 p;
    p.x = f2bf(a0.x + b0.x) | (f2bf(a0.y + b0.y) << 16);
    p.y = f2bf(a0.z + b0.z) | (f2bf(a0.w + b0.w) << 16);
    p.z = f2bf(a1.x + b1.x) | (f2bf(a1.y + b1.y) << 16);
    p.w = f2bf(a1.z + b1.z) | (f2bf(a1.w + b1.w) << 16);
    *(uint4*)((char*)Xs + r*256 + ((c16*16) ^ ((r & 7) << 4))) = p;
  }
  __syncthreads();
  const int w = tid >> 6, l = tid & 63, lq = l >> 4, lr = l & 15;
  f32x4 acc[2][4];
#pragma unroll
  for (int a = 0; a < 2; ++a)
#pragma unroll
    for (int m = 0; m < 4; ++m) acc[a][m] = (f32x4){0.f, 0.f, 0.f, 0.f};
#pragma unroll
  for (int ks = 0; ks < 4; ++ks) {
    const int bcol = ks*64 + lq*16;
    const bf16x8 a0 = ld_frag(Ws, (2*w  )*16 + lr, bcol);
    const bf16x8 a1 = ld_frag(Ws, (2*w+1)*16 + lr, bcol);
    const bf16x8 b0 = ld_frag(Xs, 0*16 + lr, bcol);
    const bf16x8 b1 = ld_frag(Xs, 1*16 + lr, bcol);
    const bf16x8 b2 = ld_frag(Xs, 2*16 + lr, bcol);
    const bf16x8 b3 = ld_frag(Xs, 3*16 + lr, bcol);
    acc[0][0] = __builtin_amdgcn_mfma_f32_16x16x32_bf16(a0, b0, acc[0][0], 0, 0, 0);
    acc[0][1] = __builtin_amdgcn_mfma_f32_16x16x32_bf16(a0, b1, acc[0][1], 0, 0, 0);
    acc[0][2] = __builtin_amdgcn_mfma_f32_16x16x32_bf16(a0, b2, acc[0][2], 0, 0, 0);
    acc[0][3] = __builtin_amdgcn_mfma_f32_16x16x32_bf16(a0, b3, acc[0][3], 0, 0, 0);
    acc[1][0] = __builtin_amdgcn_mfma_f32_16x16x32_bf16(a1, b0, acc[1][0], 0, 0, 0);
    acc[1][1] = __builtin_amdgcn_mfma_f32_16x16x32_bf16(a1, b1, acc[1][1], 0, 0, 0);
    acc[1][2] = __builtin_amdgcn_mfma_f32_16x16x32_bf16(a1, b2, acc[1][2], 0, 0, 0);
    acc[1][3] = __builtin_amdgcn_mfma_f32_16x16x32_bf16(a1, b3, acc[1][3], 0, 0, 0);
  }
#pragma unroll
  for (int obi = 0; obi < 2; ++obi) {
    const int o0 = (2*w + obi)*16 + lq*4;
#pragma unroll
    for (int mb = 0; mb < 4; ++mb) {
      const long n = nbase + mb*16 + lr;
      uint2 pp;
      pp.x = f2bf(acc[obi][mb][0]) | (f2bf(acc[obi][mb][1]) << 16);
      pp.y = f2bf(acc[obi][mb][2]) | (f2bf(acc[obi][mb][3]) << 16);
      *(uint2*)(mhb + n*128 + o0) = pp;
    }
  }
}

// ---------------- MFMA flash attention, q-split, 8 waves -------------------
// grid 512: b = bid&31, h = (bid>>5)&7, qh = bid>>8; block owns 256 q-rows.
// R7: mask chunk ch+1 prefetched into registers during softmax/PV of ch.
__global__ __launch_bounds__(512)
void k_attn(const unsigned short* __restrict__ Kb,
            const unsigned short* __restrict__ Vb,
            const float* __restrict__ ws, const float* __restrict__ cap,
            const float* __restrict__ mask, float* __restrict__ AO) {
  const int bid = blockIdx.x;
  const int b = bid & 31, h = (bid >> 5) & 7, qh = bid >> 8;
  __shared__ unsigned short Kbf[512*24];  // 24 KB
  __shared__ unsigned short Vt[16*536];   // 16.75 KB
  __shared__ unsigned short Ps[8*16*136]; // 34 KB
  const int tid = threadIdx.x;
#pragma unroll
  for (int it = 0; it < 2; ++it) {
    const int i = tid + it*512;           // 0..1023
    const int n = i >> 1, hf = i & 1;
    const long src = (long)(b*512 + n)*128 + h*16 + hf*8;
    const uint4 kv = *(const uint4*)(Kb + src);
    *(uint4*)(Kbf + n*24 + hf*8) = kv;
    const uint4 vv = *(const uint4*)(Vb + src);
    const unsigned short* sp = (const unsigned short*)&vv;
#pragma unroll
    for (int j = 0; j < 8; ++j) Vt[(hf*8 + j)*536 + n] = sp[j];
  }
  const int w = tid >> 6, l = tid & 63;
  const int lq = l >> 4, lr = l & 15;
  float qb8[8], wl8[8];
  if (lq < 2) {
    const float* qbp = ws + OFF_QB + b*128 + h*16 + lq*8;
    const float* wqp = ws + OFF_WQ;
#pragma unroll
    for (int j = 0; j < 8; ++j) {
      qb8[j] = qbp[j];
      wl8[j] = wqp[(h*16 + lq*8 + j)*129 + 128];
    }
  }
  unsigned short* Pw = Ps + w*16*136;
  __syncthreads();
  const float SC = 0.25f;
  for (int qb = 0; qb < 2; ++qb) {
    const int grow = qh*256 + w*32 + qb*16 + lr;   // this lane's q-row
    bf16x8 qf;
    {
      union { uint4 u; bf16x8 v; } cv;
      cv.u = make_uint4(0u, 0u, 0u, 0u);
      if (lq < 2) {
        const float cp = cap[b*512 + grow];
        float qv[8];
#pragma unroll
        for (int j = 0; j < 8; ++j) qv[j] = (qb8[j] + cp*wl8[j]) * SC;
        cv.u.x = f2bf(qv[0]) | (f2bf(qv[1]) << 16);
        cv.u.y = f2bf(qv[2]) | (f2bf(qv[3]) << 16);
        cv.u.z = f2bf(qv[4]) | (f2bf(qv[5]) << 16);
        cv.u.w = f2bf(qv[6]) | (f2bf(qv[7]) << 16);
      }
      qf = cv.v;
    }
    float m = -3.0e38f, lsum = 0.f;
    f32x4 oacc = {0.f, 0.f, 0.f, 0.f};
    const float* mrow = mask + ((long)(b*512 + grow))*512 + lq*4;
    float4 mk[8];
#pragma unroll
    for (int nb = 0; nb < 8; ++nb) mk[nb] = *(const float4*)(mrow + nb*16);
    for (int ch = 0; ch < 4; ++ch) {
      const int n0 = ch*128;
      f32x4 s[8];
#pragma unroll
      for (int nb = 0; nb < 8; ++nb) {
        bf16x8 kf;
        {
          union { uint4 u; bf16x8 v; } cv;
          cv.u = make_uint4(0u, 0u, 0u, 0u);
          if (lq < 2) cv.u = *(const uint4*)(Kbf + (n0 + nb*16 + lr)*24 + lq*8);
          kf = cv.v;
        }
        s[nb] = __builtin_amdgcn_mfma_f32_16x16x32_bf16(
            kf, qf, (f32x4){0.f, 0.f, 0.f, 0.f}, 0, 0, 0);
        s[nb][0] += mk[nb].x; s[nb][1] += mk[nb].y;
        s[nb][2] += mk[nb].z; s[nb][3] += mk[nb].w;
      }
      // prefetch next chunk's mask into regs (hidden under softmax+PV)
      if (ch < 3) {
#pragma unroll
        for (int nb = 0; nb < 8; ++nb)
          mk[nb] = *(const float4*)(mrow + (ch+1)*128 + nb*16);
      }
      f32x4 mx = s[0];
#pragma unroll
      for (int nb = 1; nb < 8; ++nb) {
        mx[0] = fmaxf(mx[0], s[nb][0]); mx[1] = fmaxf(mx[1], s[nb][1]);
        mx[2] = fmaxf(mx[2], s[nb][2]); mx[3] = fmaxf(mx[3], s[nb][3]);
      }
      float cm = fmaxf(fmaxf(mx[0], mx[1]), fmaxf(mx[2], mx[3]));
      cm = fmaxf(cm, __shfl_xor(cm, 16));
      cm = fmaxf(cm, __shfl_xor(cm, 32));
      const float nm = fmaxf(m, cm);
      const float rs = __expf(m - nm);
      lsum *= rs;
      oacc[0] *= rs; oacc[1] *= rs; oacc[2] *= rs; oacc[3] *= rs;
      m = nm;
      float ls = 0.f;
#pragma unroll
      for (int nb = 0; nb < 8; ++nb) {
        const float p0 = __expf(s[nb][0] - m);
        const float p1 = __expf(s[nb][1] - m);
        const float p2 = __expf(s[nb][2] - m);
        const float p3 = __expf(s[nb][3] - m);
        ls += (p0 + p1) + (p2 + p3);
        uint2 pp;
        asm("v_cvt_pk_bf16_f32 %0, %1, %2" : "=v"(pp.x) : "v"(p0), "v"(p1));
        asm("v_cvt_pk_bf16_f32 %0, %1, %2" : "=v"(pp.y) : "v"(p2), "v"(p3));
        *(uint2*)(Pw + lr*136 + nb*16 + lq*4) = pp;
      }
      lsum += ls;
#pragma unroll
      for (int ks = 0; ks < 4; ++ks) {
        const bf16x8 va = *(const bf16x8*)(Vt + lr*536 + n0 + ks*32 + lq*8);
        const bf16x8 pb = *(const bf16x8*)(Pw + lr*136 + ks*32 + lq*8);
        oacc = __builtin_amdgcn_mfma_f32_16x16x32_bf16(va, pb, oacc, 0, 0, 0);
      }
    }
    lsum += __shfl_xor(lsum, 16);
    lsum += __shfl_xor(lsum, 32);
    const float inv = 1.f / lsum;
    float4 o;
    o.x = oacc[0]*inv; o.y = oacc[1]*inv; o.z = oacc[2]*inv; o.w = oacc[3]*inv;
    *(float4*)(AO + (long)(b*512 + grow)*128 + h*16 + lq*4) = o;
  }
}

// ---------------- gating: top-2 + expert lists (block-aggregated) ----------
__global__ __launch_bounds__(256)
void k_gate(const float* __restrict__ AO, const float* __restrict__ gw,
            float* __restrict__ ws) {
  const int tid = threadIdx.x;
  const int t = blockIdx.x*256 + tid;
  const float* x = AO + (long)t*128;
  float lg[8];
  {
    const float* pl = ws + OFF_PREFL;
#pragma unroll
    for (int e = 0; e < 8; ++e) lg[e] = pl[e];
  }
  for (int i = 0; i < 128; i += 4) {
    const float4 xv = *(const float4*)(x + i);
#pragma unroll
    for (int u = 0; u < 4; ++u) {
      const float xi = (&xv.x)[u];
      const float4 ga = *(const float4*)(gw + (i+u)*8);
      const float4 gb = *(const float4*)(gw + (i+u)*8 + 4);
      lg[0] = fmaf(xi, ga.x, lg[0]); lg[1] = fmaf(xi, ga.y, lg[1]);
      lg[2] = fmaf(xi, ga.z, lg[2]); lg[3] = fmaf(xi, ga.w, lg[3]);
      lg[4] = fmaf(xi, gb.x, lg[4]); lg[5] = fmaf(xi, gb.y, lg[5]);
      lg[6] = fmaf(xi, gb.z, lg[6]); lg[7] = fmaf(xi, gb.w, lg[7]);
    }
  }
  int i0 = 0; float v0 = lg[0];
#pragma unroll
  for (int e = 1; e < 8; ++e) if (lg[e] > v0) { v0 = lg[e]; i0 = e; }
  int i1 = -1; float v1 = -1e30f;
#pragma unroll
  for (int e = 0; e < 8; ++e) if (e != i0 && lg[e] > v1) { v1 = lg[e]; i1 = e; }
  const float e1 = __expf(v1 - v0);
  const float w0 = 1.f / (1.f + e1);
  const float w1 = 1.f - w0;
  __shared__ int bcnt[8];
  __shared__ int gbase[8];
  if (tid < 8) bcnt[tid] = 0;
  __syncthreads();
  const int p0 = atomicAdd(&bcnt[i0], 1);
  const int p1 = atomicAdd(&bcnt[i1], 1);
  __syncthreads();
  if (tid < 8) {
    int* cnt = (int*)(ws + OFF_CNT);
    gbase[tid] = (bcnt[tid] > 0) ? atomicAdd(&cnt[tid], bcnt[tid]) : 0;
  }
  __syncthreads();
  int* tokp = (int*)(ws + OFF_TOK);
  float* wgtp = ws + OFF_WGT;
  const int s0 = gbase[i0] + p0;
  tokp[i0*16384 + s0] = t;             // rank 0
  wgtp[i0*16384 + s0] = w0;
  const int s1 = gbase[i1] + p1;
  tokp[i1*16384 + s1] = t | (1 << 30); // rank 1
  wgtp[i1*16384 + s1] = w1;
}

// ---------------- MoE experts: bf16 MFMA, per (expert, 64-token chunk) -----
__global__ __launch_bounds__(256)
void k_moe(const float* __restrict__ AO,
           const unsigned short* __restrict__ w1b,
           const unsigned short* __restrict__ w2b,
           const float* __restrict__ eb1, const float* __restrict__ eb2,
           float* __restrict__ ws,
           float* __restrict__ Y0, float* __restrict__ Y1) {
  const int e = blockIdx.y;
  const int ce = ((const int*)(ws + OFF_CNT))[e];
  const int base = blockIdx.x * 64;
  if (base >= ce) return;
  const int nt = min(64, ce - base);

  __shared__ unsigned short Xs[64*128];
  __shared__ unsigned short Wts[128*128];
  __shared__ unsigned short Hs[64*128];
  __shared__ float seb1[512];
  __shared__ float seb2[128];
  __shared__ int   stok[64];
  __shared__ float swgt[64];

  const int tid = threadIdx.x;
  if (tid < 64) {
    if (tid < nt) {
      stok[tid] = ((const int*)(ws + OFF_TOK))[e*16384 + base + tid];
      swgt[tid] = (ws + OFF_WGT)[e*16384 + base + tid];
    } else { stok[tid] = -1; swgt[tid] = 0.f; }
  }
  for (int i = tid; i < 512; i += 256) seb1[i] = eb1[e*512 + i];
  if (tid < 128) seb2[tid] = eb2[e*128 + tid];
  __syncthreads();

#pragma unroll
  for (int r8 = 0; r8 < 8; ++r8) {
    const int id = tid + r8*256;
    const int r = id >> 5, c = id & 31;
    const int pk = stok[r];
    float4 xv = make_float4(0.f, 0.f, 0.f, 0.f);
    if (pk >= 0) xv = *(const float4*)(AO + (long)(pk & 0x3FFFFFFF)*128 + c*4);
    uint2 pkd;
    pkd.x = f2bf(xv.x) | (f2bf(xv.y) << 16);
    pkd.y = f2bf(xv.z) | (f2bf(xv.w) << 16);
    const int bc = (c*8) ^ ((r & 7) << 4);
    *(uint2*)((char*)Xs + r*256 + bc) = pkd;
  }

  const int w  = tid >> 6;
  const int l  = tid & 63;
  const int lq = l >> 4;
  const int lr = l & 15;

  f32x4 yacc[2][4];
#pragma unroll
  for (int a = 0; a < 2; ++a)
#pragma unroll
    for (int m = 0; m < 4; ++m) yacc[a][m] = (f32x4){0.f, 0.f, 0.f, 0.f};

  for (int fc = 0; fc < 4; ++fc) {
    __syncthreads();
    {
      const long wb = (long)(e*512 + fc*128) * 128;
#pragma unroll
      for (int s = 0; s < 8; ++s) {
        const int id = tid + s*256;
        const int fr = id >> 4, c16 = id & 15;
        const uint4 v = *(const uint4*)(w1b + wb + (long)fr*128 + c16*8);
        *(uint4*)((char*)Wts + fr*256 + ((c16*16) ^ ((fr & 7) << 4))) = v;
      }
    }
    __syncthreads();
    f32x4 hacc[2][4];
#pragma unroll
    for (int a = 0; a < 2; ++a)
#pragma unroll
      for (int m = 0; m < 4; ++m) hacc[a][m] = (f32x4){0.f, 0.f, 0.f, 0.f};
#pragma unroll
    for (int ks = 0; ks < 4; ++ks) {
      const int bcol = ks*64 + lq*16;
      const bf16x8 a0 = ld_frag(Wts, (2*w  )*16 + lr, bcol);
      const bf16x8 a1 = ld_frag(Wts, (2*w+1)*16 + lr, bcol);
      const bf16x8 b0 = ld_frag(Xs,  0*16 + lr, bcol);
      const bf16x8 b1 = ld_frag(Xs,  1*16 + lr, bcol);
      const bf16x8 b2 = ld_frag(Xs,  2*16 + lr, bcol);
      const bf16x8 b3 = ld_frag(Xs,  3*16 + lr, bcol);
      hacc[0][0] = __builtin_amdgcn_mfma_f32_16x16x32_bf16(a0, b0, hacc[0][0], 0, 0, 0);
      hacc[0][1] = __builtin_amdgcn_mfma_f32_16x16x32_bf16(a0, b1, hacc[0][1], 0, 0, 0);
      hacc[0][2] = __builtin_amdgcn_mfma_f32_16x16x32_bf16(a0, b2, hacc[0][2], 0, 0, 0);
      hacc[0][3] = __builtin_amdgcn_mfma_f32_16x16x32_bf16(a0, b3, hacc[0][3], 0, 0, 0);
      hacc[1][0] = __builtin_amdgcn_mfma_f32_16x16x32_bf16(a1, b0, hacc[1][0], 0, 0, 0);
      hacc[1][1] = __builtin_amdgcn_mfma_f32_16x16x32_bf16(a1, b1, hacc[1][1], 0, 0, 0);
      hacc[1][2] = __builtin_amdgcn_mfma_f32_16x16x32_bf16(a1, b2, hacc[1][2], 0, 0, 0);
      hacc[1][3] = __builtin_amdgcn_mfma_f32_16x16x32_bf16(a1, b3, hacc[1][3], 0, 0, 0);
    }
    __syncthreads();
#pragma unroll
    for (int fbi = 0; fbi < 2; ++fbi) {
      const int fb = (2*w + fbi)*16 + lq*4;
      const float4 bia = *(const float4*)&seb1[fc*128 + fb];
#pragma unroll
      for (int mb = 0; mb < 4; ++mb) {
        const int m = mb*16 + lr;
        const float h0 = fmaxf(hacc[fbi][mb][0] + bia.x, 0.f);
        const float h1 = fmaxf(hacc[fbi][mb][1] + bia.y, 0.f);
        const float h2 = fmaxf(hacc[fbi][mb][2] + bia.z, 0.f);
        const float h3 = fmaxf(hacc[fbi][mb][3] + bia.w, 0.f);
        uint2 p;
        p.x = f2bf(h0) | (f2bf(h1) << 16);
        p.y = f2bf(h2) | (f2bf(h3) << 16);
        const int bc = (fb*2) ^ ((m & 7) << 4);
        *(uint2*)((char*)Hs + m*256 + bc) = p;
      }
    }
    {
      const long wb = (long)(e*128) * 512 + fc*128;
#pragma unroll
      for (int s = 0; s < 8; ++s) {
        const int id = tid + s*256;
        const int orr = id >> 4, c16 = id & 15;
        const uint4 v = *(const uint4*)(w2b + wb + (long)orr*512 + c16*8);
        *(uint4*)((char*)Wts + orr*256 + ((c16*16) ^ ((orr & 7) << 4))) = v;
      }
    }
    __syncthreads();
#pragma unroll
    for (int ks = 0; ks < 4; ++ks) {
      const int bcol = ks*64 + lq*16;
      const bf16x8 a0 = ld_frag(Wts, (2*w  )*16 + lr, bcol);
      const bf16x8 a1 = ld_frag(Wts, (2*w+1)*16 + lr, bcol);
      const bf16x8 b0 = ld_frag(Hs,  0*16 + lr, bcol);
      const bf16x8 b1 = ld_frag(Hs,  1*16 + lr, bcol);
      const bf16x8 b2 = ld_frag(Hs,  2*16 + lr, bcol);
      const bf16x8 b3 = ld_frag(Hs,  3*16 + lr, bcol);
      yacc[0][0] = __builtin_amdgcn_mfma_f32_16x16x32_bf16(a0, b0, yacc[0][0], 0, 0, 0);
      yacc[0][1] = __builtin_amdgcn_mfma_f32_16x16x32_bf16(a0, b1, yacc[0][1], 0, 0, 0);
      yacc[0][2] = __builtin_amdgcn_mfma_f32_16x16x32_bf16(a0, b2, yacc[0][2], 0, 0, 0);
      yacc[0][3] = __builtin_amdgcn_mfma_f32_16x16x32_bf16(a0, b3, yacc[0][3], 0, 0, 0);
      yacc[1][0] = __builtin_amdgcn_mfma_f32_16x16x32_bf16(a1, b0, yacc[1][0], 0, 0, 0);
      yacc[1][1] = __builtin_amdgcn_mfma_f32_16x16x32_bf16(a1, b1, yacc[1][1], 0, 0, 0);
      yacc[1][2] = __builtin_amdgcn_mfma_f32_16x16x32_bf16(a1, b2, yacc[1][2], 0, 0, 0);
      yacc[1][3] = __builtin_amdgcn_mfma_f32_16x16x32_bf16(a1, b3, yacc[1][3], 0, 0, 0);
    }
  }
#pragma unroll
  for (int obi = 0; obi < 2; ++obi) {
    const int ob = (2*w + obi)*16 + lq*4;
    const float4 b2 = *(const float4*)&seb2[ob];
#pragma unroll
    for (int mb = 0; mb < 4; ++mb) {
      const int tl = mb*16 + lr;
      if (tl < nt) {
        const int pk = stok[tl];
        const int tk = pk & 0x3FFFFFFF;
        const float wgt = swgt[tl];
        float* Yp = ((pk >> 30) ? Y1 : Y0) + (long)tk*128 + ob;
        float4 o;
        o.x = (yacc[obi][mb][0] + b2.x) * wgt;
        o.y = (yacc[obi][mb][1] + b2.y) * wgt;
        o.z = (yacc[obi][mb][2] + b2.z) * wgt;
        o.w = (yacc[obi][mb][3] + b2.w) * wgt;
        *(float4*)Yp = o;
      }
    }
  }
}

// ---------------- fused sc GEMM + tanh + fixed-max softmax -----------------
__global__ __launch_bounds__(512)
void k_gemm2f(const unsigned short* __restrict__ mhb,
              const unsigned short* __restrict__ encb,
              const float* __restrict__ mask,
              float* __restrict__ out) {
  const int bid = blockIdx.x;
  const int b = bid & 31, rt = bid >> 5;
  __shared__ unsigned short Amh[64*128];   // 16 KB
  __shared__ unsigned short Bch[512*32];   // 32 KB
  __shared__ float red[64][9];
  const int tid = threadIdx.x;
  const int w = tid >> 6, l = tid & 63, lq = l >> 4, lr = l & 15;
  const long rowbase = (long)b*512 + rt*64;
#pragma unroll
  for (int s = 0; s < 2; ++s) {
    const int id = tid + s*512;
    const int r = id >> 4, c16 = id & 15;
    const uint4 v = *(const uint4*)(mhb + (rowbase + r)*128 + c16*8);
    *(uint4*)((char*)Amh + r*256 + ((c16*16) ^ ((r & 7) << 4))) = v;
  }
  f32x4 acc[4][4];
#pragma unroll
  for (int mi = 0; mi < 4; ++mi)
#pragma unroll
    for (int ni = 0; ni < 4; ++ni) acc[mi][ni] = (f32x4){0.f, 0.f, 0.f, 0.f};
  for (int kc = 0; kc < 4; ++kc) {
    __syncthreads();
#pragma unroll
    for (int s = 0; s < 4; ++s) {
      const int id = tid + s*512;
      const int n = id >> 2, sl = id & 3;
      const uint4 v = *(const uint4*)(encb + ((long)b*512 + n)*128 + kc*32 + sl*8);
      *(uint4*)((char*)Bch + n*64 + ((sl*16) ^ ((n & 3) << 4))) = v;
    }
    __syncthreads();
    bf16x8 af[4], bfr[4];
#pragma unroll
    for (int mi = 0; mi < 4; ++mi) {
      const int r = mi*16 + lr;
      af[mi] = *(const bf16x8*)((const char*)Amh + r*256 + ((kc*64 + lq*16) ^ ((r & 7) << 4)));
    }
#pragma unroll
    for (int ni = 0; ni < 4; ++ni) {
      const int n = w*64 + ni*16 + lr;
      bfr[ni] = *(const bf16x8*)((const char*)Bch + n*64 + ((lq*16) ^ ((n & 3) << 4)));
    }
#pragma unroll
    for (int mi = 0; mi < 4; ++mi)
#pragma unroll
      for (int ni = 0; ni < 4; ++ni)
        acc[mi][ni] = __builtin_amdgcn_mfma_f32_16x16x32_bf16(af[mi], bfr[ni], acc[mi][ni], 0, 0, 0);
  }
  const float ISC = 1.f/11.313708498984761f;
  float rsum[4][4];
#pragma unroll
  for (int mi = 0; mi < 4; ++mi)
#pragma unroll
    for (int j = 0; j < 4; ++j) rsum[mi][j] = 0.f;
#pragma unroll
  for (int mi = 0; mi < 4; ++mi) {
#pragma unroll
    for (int j = 0; j < 4; ++j) {
      const long row = rowbase + mi*16 + lq*4 + j;
      const float* mrow = mask + row*512 + w*64 + lr;
#pragma unroll
      for (int ni = 0; ni < 4; ++ni) {
        const float sc = acc[mi][ni][j] * ISC;
        const float li = 10.f*tanhf(sc) + mrow[ni*16];
        const float e = __expf(li - 10.f);
        acc[mi][ni][j] = e;
        rsum[mi][j] += e;
      }
    }
  }
#pragma unroll
  for (int mi = 0; mi < 4; ++mi)
#pragma unroll
    for (int j = 0; j < 4; ++j) {
#pragma unroll
      for (int o = 1; o < 16; o <<= 1) rsum[mi][j] += __shfl_xor(rsum[mi][j], o);
    }
  if (lr == 0) {
#pragma unroll
    for (int mi = 0; mi < 4; ++mi)
#pragma unroll
      for (int j = 0; j < 4; ++j) red[mi*16 + lq*4 + j][w] = rsum[mi][j];
  }
  __syncthreads();
  if (tid < 64) {
    float s = 0.f;
#pragma unroll
    for (int wv = 0; wv < 8; ++wv) s += red[tid][wv];
    red[tid][8] = 1.f / s;
  }
  __syncthreads();
#pragma unroll
  for (int mi = 0; mi < 4; ++mi) {
#pragma unroll
    for (int j = 0; j < 4; ++j) {
      const int rl = mi*16 + lq*4 + j;
      const float inv = red[rl][8];
      float* orow = out + (rowbase + rl)*512 + w*64 + lr;
#pragma unroll
      for (int ni = 0; ni < 4; ++ni) orow[ni*16] = acc[mi][ni][j] * inv;
    }
  }
}

// ---------------------------------------------------------------------------
extern "C" void kernel_launch(void* const* d_in, const int* in_sizes, int n_in,
                              void* d_out, int out_size, void* d_ws, size_t ws_size,
                              hipStream_t stream) {
  (void)in_sizes; (void)n_in; (void)out_size; (void)ws_size;
  const float* pref  = (const float*)d_in[0];
  const float* graph = (const float*)d_in[1];
  const float* cap   = (const float*)d_in[2];
  const float* enc   = (const float*)d_in[3];
  const float* mask  = (const float*)d_in[4];
  const float* fc1w  = (const float*)d_in[5];
  const float* fc1b  = (const float*)d_in[6];
  const float* fc2w  = (const float*)d_in[7];
  const float* fc2b  = (const float*)d_in[8];
  const float* fc3w  = (const float*)d_in[9];
  const float* fc3b  = (const float*)d_in[10];
  const float* hWq   = (const float*)d_in[11];
  const float* hWk   = (const float*)d_in[12];
  const float* hWv   = (const float*)d_in[13];
  const float* hWc   = (const float*)d_in[14];
  const float* gw    = (const float*)d_in[15];
  const float* gpw   = (const float*)d_in[16];
  const float* ew1   = (const float*)d_in[17];
  const float* eb1   = (const float*)d_in[18];
  const float* ew2   = (const float*)d_in[19];
  const float* eb2   = (const float*)d_in[20];
  float* ws  = (float*)d_ws;
  float* out = (float*)d_out;
  unsigned short* Kbuf = (unsigned short*)out;
  unsigned short* Vbuf = (unsigned short*)(out + 1048576);
  float* Y0 = out;
  float* Y1 = out + 2097152;
  unsigned short* ew1b = (unsigned short*)(out + 4194304);
  unsigned short* ew2b = (unsigned short*)(out + 4456448);
  unsigned short* mhb  = (unsigned short*)(ws + OFF_MH);
  unsigned short* encb = (unsigned short*)(ws + OFF_ENCB);
  unsigned short* wkb  = (unsigned short*)(ws + OFF_WKB);
  unsigned short* wvb  = (unsigned short*)(ws + OFF_WVB);
  unsigned short* wcb  = (unsigned short*)(ws + OFF_WCB);

  hipMemsetAsync((char*)d_ws + OFF_CNT*sizeof(float), 0, 8*sizeof(int), stream);
  k_cvt<<<3072, 256, 0, stream>>>(ew1, ew2, enc, ew1b, ew2b, encb);
  k_hyper<<<1, 256, 0, stream>>>(pref, fc1w, fc1b, fc2w, fc2b, fc3w, fc3b, gpw, ws);
  k_hyperw<<<257, 256, 0, stream>>>(hWq, hWk, hWv, hWc, ws);
  k_qbase<<<32, 128, 0, stream>>>(graph, ws);
  k_kv<<<dim3(256, 2), 256, 0, stream>>>(encb, wkb, wvb, Kbuf, Vbuf);
  k_attn<<<512, 512, 0, stream>>>(Kbuf, Vbuf, ws, cap, mask, ws + OFF_AO);
  k_gate<<<64, 256, 0, stream>>>(ws + OFF_AO, gw, ws);
  k_moe<<<dim3(256, 8), 256, 0, stream>>>(ws + OFF_AO, ew1b, ew2b, eb1, eb2, ws, Y0, Y1);
  k_mh<<<256, 256, 0, stream>>>(Y0, Y1, wcb, mhb);
  k_gemm2f<<<256, 512, 0, stream>>>(mhb, encb, mask, out);
}

// Round 8
// 127.693 us; speedup vs baseline: 7.1073x; 1.0383x over previous
//
#include <hip/hip_runtime.h>

// ---------------------------------------------------------------------------
// KP_Decoder: hypernet -> (k,v,q) -> attention -> top2 MoE -> combine softmax
// B=32 G=512 N=512 EMB=128 H=8 DK=16 E=8 FH=512 K=2
// R3: k_moe bf16 MFMA. R4-7: MFMA flash attn ladder; k_kv/k_mh bf16 MFMA;
//     k_gemm2f fused fixed-max tanh-softmax.
// R8: k_prep fuses cvt+hyper+hyperw+qbase+memset (11 -> 7 dispatches);
//     k_attn v3: 40KB LDS + VGPR<=64 targeting 4 blocks/CU (8 waves/SIMD),
//     grid 1024 (qh x4), quarter-chunk (32n) online softmax.
// ---------------------------------------------------------------------------

typedef __attribute__((ext_vector_type(8))) __bf16 bf16x8;
typedef __attribute__((ext_vector_type(4))) float f32x4;

// ws layout (float offsets)
static constexpr long OFF_MID   = 0;        // 8
static constexpr long OFF_PREFL = 8;        // 8
static constexpr long OFF_WL    = 16;       // 128 (Wq[:,128] capacity col)
static constexpr long OFF_WKB   = 256;      // 128x128 bf16
static constexpr long OFF_WVB   = 8448;     // 128x128 bf16
static constexpr long OFF_WCB   = 16640;    // 128x128 bf16
static constexpr long OFF_QB    = 24832;    // 32x128 qbase fp32
static constexpr long OFF_CNT   = 28928;    // 8 ints
static constexpr long OFF_TOK   = 28936;    // 8*16384 ints
static constexpr long OFF_WGT   = 160008;   // 8*16384 floats
static constexpr long OFF_AO    = 291080;   // 16384x128 fp32 attention out
static constexpr long OFF_MH    = 2388232;  // 16384x128 bf16 mh
static constexpr long OFF_ENCB  = 3436808;  // 16384x128 bf16 enc
// total 4,485,384 floats = 17.9 MB

__device__ __forceinline__ unsigned f2bf(float x) {
  union { float f; unsigned u; } v; v.f = x;
  return ((v.u + 0x7FFFu + ((v.u >> 16) & 1u)) >> 16) & 0xFFFFu;
}

// ---------------- k_prep: cvt + hypernet + heads + qbase + init ------------
// blocks [0,3072): bf16 cvt of ew1/ew2/enc
// blocks [3072,3264): Wk/Wv/Wc bf16 heads (recompute mid per block)
// blocks [3264,3280): qbase (2 b per block) + block0: mid/prefl/cnt/wl
__global__ __launch_bounds__(256)
void k_prep(const float* __restrict__ pref, const float* __restrict__ fc1w,
            const float* __restrict__ fc1b, const float* __restrict__ fc2w,
            const float* __restrict__ fc2b, const float* __restrict__ fc3w,
            const float* __restrict__ fc3b, const float* __restrict__ gpw,
            const float* __restrict__ graph,
            const float* __restrict__ hWq, const float* __restrict__ hWk,
            const float* __restrict__ hWv, const float* __restrict__ hWc,
            const float* __restrict__ ew1, const float* __restrict__ ew2,
            const float* __restrict__ enc,
            unsigned short* __restrict__ w1b, unsigned short* __restrict__ w2b,
            unsigned short* __restrict__ encb, float* __restrict__ ws) {
  const int bid = blockIdx.x;
  const int tid = threadIdx.x;
  if (bid < 3072) {
    const int i = bid*256 + tid;
    const float* src;
    unsigned short* dst;
    if (i < 131072)      { src = ew1 + (long)i*4;          dst = w1b + (long)i*4; }
    else if (i < 262144) { src = ew2 + (long)(i-131072)*4; dst = w2b + (long)(i-131072)*4; }
    else                 { src = enc + (long)(i-262144)*4; dst = encb + (long)(i-262144)*4; }
    const float4 v = *(const float4*)src;
    uint2 p;
    p.x = f2bf(v.x) | (f2bf(v.y) << 16);
    p.y = f2bf(v.z) | (f2bf(v.w) << 16);
    *(uint2*)dst = p;
    return;
  }
  // recompute mid (tiny hypernet MLP) in every remaining block
  __shared__ float h1[256];
  __shared__ float h2[256];
  __shared__ float mid[8];
  __shared__ float g[2][128];
  const float p0 = pref[0], p1 = pref[1];
  h1[tid] = fc1w[2*tid]*p0 + fc1w[2*tid+1]*p1 + fc1b[tid];
  __syncthreads();
  float s = 0.f;
  for (int j = 0; j < 256; ++j) s = fmaf(fc2w[tid*256+j], h1[j], s);
  h2[tid] = s + fc2b[tid];
  __syncthreads();
  if (tid < 8) {
    float s2 = 0.f;
    for (int j = 0; j < 256; ++j) s2 = fmaf(fc3w[tid*256+j], h2[j], s2);
    mid[tid] = s2 + fc3b[tid];
  }
  __syncthreads();
  if (bid < 3264) {
    const int i = (bid - 3072)*256 + tid;   // 0..49151
    if (i < 16384) {
      ((unsigned short*)(ws + OFF_WKB))[i] =
          (unsigned short)f2bf(hWk[2*i]*mid[2] + hWk[2*i+1]*mid[3]);
    } else if (i < 32768) {
      const int j = i - 16384;
      ((unsigned short*)(ws + OFF_WVB))[j] =
          (unsigned short)f2bf(hWv[2*j]*mid[4] + hWv[2*j+1]*mid[5]);
    } else {
      const int j = i - 32768;
      ((unsigned short*)(ws + OFF_WCB))[j] =
          (unsigned short)f2bf(hWc[2*j]*mid[6] + hWc[2*j+1]*mid[7]);
    }
    return;
  }
  // qbase section: 16 blocks, 2 b each
  const int qb = bid - 3264;
  const int b0 = qb*2;
  {
    const int bb = tid >> 7, ii = tid & 127;
    g[bb][ii] = graph[(b0+bb)*128 + ii];
  }
  __syncthreads();
  const float m0 = mid[0], m1 = mid[1];
  {
    const int bb = tid >> 7, o = tid & 127;
    const float* hq = hWq + (long)o*129*2;
    float acc = 0.f;
    for (int i2 = 0; i2 < 128; ++i2) {
      const float w = hq[2*i2]*m0 + hq[2*i2+1]*m1;
      acc = fmaf(g[bb][i2], w, acc);
    }
    ws[OFF_QB + (b0+bb)*128 + o] = acc;
  }
  if (qb == 0) {
    if (tid < 8) {
      ws[OFF_MID + tid] = mid[tid];
      float s3 = 0.f;
      for (int i2 = 0; i2 < 8; ++i2) s3 = fmaf(mid[i2], gpw[i2*8 + tid], s3);
      ws[OFF_PREFL + tid] = s3;
      ((int*)(ws + OFF_CNT))[tid] = 0;
    }
    if (tid >= 16 && tid < 144) {
      const int o = tid - 16;
      ws[OFF_WL + o] = hWq[((long)o*129 + 128)*2]*m0 + hWq[((long)o*129 + 128)*2 + 1]*m1;
    }
  }
}

// ---------------- shared swizzled-LDS fragment loader (256B rows) ----------
__device__ __forceinline__ bf16x8 ld_frag(const unsigned short* base, int row, int bytecol) {
  const int addr = row*256 + (bytecol ^ ((row & 7) << 4));
  return *(const bf16x8*)((const char*)base + addr);
}

// ---------------- k_kv: bf16 MFMA GEMM, {K,V}[n][o] = enc . W^T ------------
__global__ __launch_bounds__(256)
void k_kv(const unsigned short* __restrict__ encb,
          const unsigned short* __restrict__ wkb,
          const unsigned short* __restrict__ wvb,
          unsigned short* __restrict__ Kb, unsigned short* __restrict__ Vb) {
  __shared__ unsigned short Ws[128*128];
  __shared__ unsigned short Xs[64*128];
  const int tid = threadIdx.x;
  const int nbase = blockIdx.x * 64;
  const unsigned short* Wb = blockIdx.y ? wvb : wkb;
  unsigned short* Cb = blockIdx.y ? Vb : Kb;
#pragma unroll
  for (int s = 0; s < 8; ++s) {
    const int id = tid + s*256;
    const int fr = id >> 4, c16 = id & 15;
    const uint4 v = *(const uint4*)(Wb + (long)fr*128 + c16*8);
    *(uint4*)((char*)Ws + fr*256 + ((c16*16) ^ ((fr & 7) << 4))) = v;
  }
#pragma unroll
  for (int s = 0; s < 4; ++s) {
    const int id = tid + s*256;
    const int r = id >> 4, c16 = id & 15;
    const uint4 v = *(const uint4*)(encb + (long)(nbase + r)*128 + c16*8);
    *(uint4*)((char*)Xs + r*256 + ((c16*16) ^ ((r & 7) << 4))) = v;
  }
  __syncthreads();
  const int w = tid >> 6, l = tid & 63, lq = l >> 4, lr = l & 15;
  f32x4 acc[2][4];
#pragma unroll
  for (int a = 0; a < 2; ++a)
#pragma unroll
    for (int m = 0; m < 4; ++m) acc[a][m] = (f32x4){0.f, 0.f, 0.f, 0.f};
#pragma unroll
  for (int ks = 0; ks < 4; ++ks) {
    const int bcol = ks*64 + lq*16;
    const bf16x8 a0 = ld_frag(Ws, (2*w  )*16 + lr, bcol);
    const bf16x8 a1 = ld_frag(Ws, (2*w+1)*16 + lr, bcol);
    const bf16x8 b0 = ld_frag(Xs, 0*16 + lr, bcol);
    const bf16x8 b1 = ld_frag(Xs, 1*16 + lr, bcol);
    const bf16x8 b2 = ld_frag(Xs, 2*16 + lr, bcol);
    const bf16x8 b3 = ld_frag(Xs, 3*16 + lr, bcol);
    acc[0][0] = __builtin_amdgcn_mfma_f32_16x16x32_bf16(a0, b0, acc[0][0], 0, 0, 0);
    acc[0][1] = __builtin_amdgcn_mfma_f32_16x16x32_bf16(a0, b1, acc[0][1], 0, 0, 0);
    acc[0][2] = __builtin_amdgcn_mfma_f32_16x16x32_bf16(a0, b2, acc[0][2], 0, 0, 0);
    acc[0][3] = __builtin_amdgcn_mfma_f32_16x16x32_bf16(a0, b3, acc[0][3], 0, 0, 0);
    acc[1][0] = __builtin_amdgcn_mfma_f32_16x16x32_bf16(a1, b0, acc[1][0], 0, 0, 0);
    acc[1][1] = __builtin_amdgcn_mfma_f32_16x16x32_bf16(a1, b1, acc[1][1], 0, 0, 0);
    acc[1][2] = __builtin_amdgcn_mfma_f32_16x16x32_bf16(a1, b2, acc[1][2], 0, 0, 0);
    acc[1][3] = __builtin_amdgcn_mfma_f32_16x16x32_bf16(a1, b3, acc[1][3], 0, 0, 0);
  }
#pragma unroll
  for (int obi = 0; obi < 2; ++obi) {
    const int o0 = (2*w + obi)*16 + lq*4;
#pragma unroll
    for (int mb = 0; mb < 4; ++mb) {
      const long n = nbase + mb*16 + lr;
      uint2 pp;
      pp.x = f2bf(acc[obi][mb][0]) | (f2bf(acc[obi][mb][1]) << 16);
      pp.y = f2bf(acc[obi][mb][2]) | (f2bf(acc[obi][mb][3]) << 16);
      *(uint2*)(Cb + n*128 + o0) = pp;
    }
  }
}

// ---------------- k_mh: bf16 MFMA GEMM, mh[n][o] = (Y0+Y1) . Wc^T ----------
__global__ __launch_bounds__(256)
void k_mh(const float* __restrict__ Y0, const float* __restrict__ Y1,
          const unsigned short* __restrict__ wcb,
          unsigned short* __restrict__ mhb) {
  __shared__ unsigned short Ws[128*128];
  __shared__ unsigned short Xs[64*128];
  const int tid = threadIdx.x;
  const int nbase = blockIdx.x * 64;
#pragma unroll
  for (int s = 0; s < 8; ++s) {
    const int id = tid + s*256;
    const int fr = id >> 4, c16 = id & 15;
    const uint4 v = *(const uint4*)(wcb + (long)fr*128 + c16*8);
    *(uint4*)((char*)Ws + fr*256 + ((c16*16) ^ ((fr & 7) << 4))) = v;
  }
#pragma unroll
  for (int s = 0; s < 4; ++s) {
    const int id = tid + s*256;
    const int r = id >> 4, c16 = id & 15;
    const long base = (long)(nbase + r)*128 + c16*8;
    const float4 a0 = *(const float4*)(Y0 + base);
    const float4 a1 = *(const float4*)(Y0 + base + 4);
    const float4 b0 = *(const float4*)(Y1 + base);
    const float4 b1 = *(const float4*)(Y1 + base + 4);
    uint4 p;
    p.x = f2bf(a0.x + b0.x) | (f2bf(a0.y + b0.y) << 16);
    p.y = f2bf(a0.z + b0.z) | (f2bf(a0.w + b0.w) << 16);
    p.z = f2bf(a1.x + b1.x) | (f2bf(a1.y + b1.y) << 16);
    p.w = f2bf(a1.z + b1.z) | (f2bf(a1.w + b1.w) << 16);
    *(uint4*)((char*)Xs + r*256 + ((c16*16) ^ ((r & 7) << 4))) = p;
  }
  __syncthreads();
  const int w = tid >> 6, l = tid & 63, lq = l >> 4, lr = l & 15;
  f32x4 acc[2][4];
#pragma unroll
  for (int a = 0; a < 2; ++a)
#pragma unroll
    for (int m = 0; m < 4; ++m) acc[a][m] = (f32x4){0.f, 0.f, 0.f, 0.f};
#pragma unroll
  for (int ks = 0; ks < 4; ++ks) {
    const int bcol = ks*64 + lq*16;
    const bf16x8 a0 = ld_frag(Ws, (2*w  )*16 + lr, bcol);
    const bf16x8 a1 = ld_frag(Ws, (2*w+1)*16 + lr, bcol);
    const bf16x8 b0 = ld_frag(Xs, 0*16 + lr, bcol);
    const bf16x8 b1 = ld_frag(Xs, 1*16 + lr, bcol);
    const bf16x8 b2 = ld_frag(Xs, 2*16 + lr, bcol);
    const bf16x8 b3 = ld_frag(Xs, 3*16 + lr, bcol);
    acc[0][0] = __builtin_amdgcn_mfma_f32_16x16x32_bf16(a0, b0, acc[0][0], 0, 0, 0);
    acc[0][1] = __builtin_amdgcn_mfma_f32_16x16x32_bf16(a0, b1, acc[0][1], 0, 0, 0);
    acc[0][2] = __builtin_amdgcn_mfma_f32_16x16x32_bf16(a0, b2, acc[0][2], 0, 0, 0);
    acc[0][3] = __builtin_amdgcn_mfma_f32_16x16x32_bf16(a0, b3, acc[0][3], 0, 0, 0);
    acc[1][0] = __builtin_amdgcn_mfma_f32_16x16x32_bf16(a1, b0, acc[1][0], 0, 0, 0);
    acc[1][1] = __builtin_amdgcn_mfma_f32_16x16x32_bf16(a1, b1, acc[1][1], 0, 0, 0);
    acc[1][2] = __builtin_amdgcn_mfma_f32_16x16x32_bf16(a1, b2, acc[1][2], 0, 0, 0);
    acc[1][3] = __builtin_amdgcn_mfma_f32_16x16x32_bf16(a1, b3, acc[1][3], 0, 0, 0);
  }
#pragma unroll
  for (int obi = 0; obi < 2; ++obi) {
    const int o0 = (2*w + obi)*16 + lq*4;
#pragma unroll
    for (int mb = 0; mb < 4; ++mb) {
      const long n = nbase + mb*16 + lr;
      uint2 pp;
      pp.x = f2bf(acc[obi][mb][0]) | (f2bf(acc[obi][mb][1]) << 16);
      pp.y = f2bf(acc[obi][mb][2]) | (f2bf(acc[obi][mb][3]) << 16);
      *(uint2*)(mhb + n*128 + o0) = pp;
    }
  }
}

// ---------------- MFMA flash attention v3 ----------------------------------
// grid 1024: b = bid&31, h = (bid>>5)&7, qh = bid>>8 (0..3); 512 thr, 8 waves;
// each wave owns ONE 16-row q-tile. LDS 40KB -> 4 blocks/CU; VGPR target <=64
// for 8 waves/SIMD. Quarter-chunk (32 n) online softmax.
__global__ __launch_bounds__(512, 8)
void k_attn(const unsigned short* __restrict__ Kb,
            const unsigned short* __restrict__ Vb,
            const float* __restrict__ ws, const float* __restrict__ cap,
            const float* __restrict__ mask, float* __restrict__ AO) {
  const int bid = blockIdx.x;
  const int b = bid & 31, h = (bid >> 5) & 7, qh = bid >> 8;
  __shared__ unsigned short Kbf[512*16];  // 16KB, pitch 16 shorts (32B rows)
  __shared__ unsigned short Vt[16*512];   // 16KB, row d, short-idx ^((d&7)<<3)
  __shared__ unsigned short Ps[8*16*32];  // 8KB, per-wave [16 q][32 n]
  const int tid = threadIdx.x;
#pragma unroll
  for (int it = 0; it < 2; ++it) {
    const int i = tid + it*512;           // 0..1023
    const int n = i >> 1, hf = i & 1;
    const long src = (long)(b*512 + n)*128 + h*16 + hf*8;
    const uint4 kv = *(const uint4*)(Kb + src);
    *(uint4*)(Kbf + n*16 + hf*8) = kv;
    const uint4 vv = *(const uint4*)(Vb + src);
    const unsigned short* sp = (const unsigned short*)&vv;
#pragma unroll
    for (int j = 0; j < 8; ++j) {
      const int d = hf*8 + j;
      Vt[d*512 + (n ^ ((d & 7) << 3))] = sp[j];
    }
  }
  const int w = tid >> 6, l = tid & 63;
  const int lq = l >> 4, lr = l & 15;
  const int grow = qh*128 + w*16 + lr;    // this lane's q-row
  // B-frag Q[q=lr][dk], dk padded 16->32 (lq<2 live)
  bf16x8 qf;
  {
    union { uint4 u; bf16x8 v; } cv;
    cv.u = make_uint4(0u, 0u, 0u, 0u);
    if (lq < 2) {
      const float* qbp = ws + OFF_QB + b*128 + h*16 + lq*8;
      const float* wlp = ws + OFF_WL + h*16 + lq*8;
      const float cp = cap[b*512 + grow];
      float qv[8];
#pragma unroll
      for (int j = 0; j < 8; ++j) qv[j] = (qbp[j] + cp*wlp[j]) * 0.25f;
      cv.u.x = f2bf(qv[0]) | (f2bf(qv[1]) << 16);
      cv.u.y = f2bf(qv[2]) | (f2bf(qv[3]) << 16);
      cv.u.z = f2bf(qv[4]) | (f2bf(qv[5]) << 16);
      cv.u.w = f2bf(qv[6]) | (f2bf(qv[7]) << 16);
    }
    qf = cv.v;
  }
  unsigned short* Pw = Ps + w*16*32;
  const int psw = (lr & 3) << 3;          // 16B-granular XOR (short units)
  __syncthreads();
  float m = -3.0e38f, lsum = 0.f;
  f32x4 oacc = {0.f, 0.f, 0.f, 0.f};
  const float* mrow = mask + ((long)(b*512 + grow))*512 + lq*4;
  for (int qc = 0; qc < 16; ++qc) {       // 16 quarter-chunks of 32 n
    const int n0 = qc*32;
    f32x4 s[2];
#pragma unroll
    for (int nb = 0; nb < 2; ++nb) {
      bf16x8 kf;
      {
        union { uint4 u; bf16x8 v; } cv;
        cv.u = make_uint4(0u, 0u, 0u, 0u);
        if (lq < 2) cv.u = *(const uint4*)(Kbf + (n0 + nb*16 + lr)*16 + lq*8);
        kf = cv.v;
      }
      s[nb] = __builtin_amdgcn_mfma_f32_16x16x32_bf16(
          kf, qf, (f32x4){0.f, 0.f, 0.f, 0.f}, 0, 0, 0);
      const float4 mk = *(const float4*)(mrow + n0 + nb*16);
      s[nb][0] += mk.x; s[nb][1] += mk.y; s[nb][2] += mk.z; s[nb][3] += mk.w;
    }
    f32x4 mx;
    mx[0] = fmaxf(s[0][0], s[1][0]); mx[1] = fmaxf(s[0][1], s[1][1]);
    mx[2] = fmaxf(s[0][2], s[1][2]); mx[3] = fmaxf(s[0][3], s[1][3]);
    float cm = fmaxf(fmaxf(mx[0], mx[1]), fmaxf(mx[2], mx[3]));
    cm = fmaxf(cm, __shfl_xor(cm, 16));
    cm = fmaxf(cm, __shfl_xor(cm, 32));
    const float nm = fmaxf(m, cm);
    const float rs = __expf(m - nm);
    lsum *= rs;
    oacc[0] *= rs; oacc[1] *= rs; oacc[2] *= rs; oacc[3] *= rs;
    m = nm;
    float ls = 0.f;
#pragma unroll
    for (int nb = 0; nb < 2; ++nb) {
      const float e0 = __expf(s[nb][0] - m);
      const float e1 = __expf(s[nb][1] - m);
      const float e2 = __expf(s[nb][2] - m);
      const float e3 = __expf(s[nb][3] - m);
      ls += (e0 + e1) + (e2 + e3);
      uint2 pp;
      asm("v_cvt_pk_bf16_f32 %0, %1, %2" : "=v"(pp.x) : "v"(e0), "v"(e1));
      asm("v_cvt_pk_bf16_f32 %0, %1, %2" : "=v"(pp.y) : "v"(e2), "v"(e3));
      *(uint2*)(Pw + lr*32 + ((nb*16 + lq*4) ^ psw)) = pp;
    }
    lsum += ls;
    const bf16x8 va = *(const bf16x8*)(Vt + lr*512 + ((n0 + lq*8) ^ ((lr & 7) << 3)));
    const bf16x8 pb = *(const bf16x8*)(Pw + lr*32 + ((lq*8) ^ psw));
    oacc = __builtin_amdgcn_mfma_f32_16x16x32_bf16(va, pb, oacc, 0, 0, 0);
  }
  lsum += __shfl_xor(lsum, 16);
  lsum += __shfl_xor(lsum, 32);
  const float inv = 1.f / lsum;
  float4 o;
  o.x = oacc[0]*inv; o.y = oacc[1]*inv; o.z = oacc[2]*inv; o.w = oacc[3]*inv;
  *(float4*)(AO + (long)(b*512 + grow)*128 + h*16 + lq*4) = o;
}

// ---------------- gating: top-2 + expert lists (block-aggregated) ----------
__global__ __launch_bounds__(256)
void k_gate(const float* __restrict__ AO, const float* __restrict__ gw,
            float* __restrict__ ws) {
  const int tid = threadIdx.x;
  const int t = blockIdx.x*256 + tid;
  const float* x = AO + (long)t*128;
  float lg[8];
  {
    const float* pl = ws + OFF_PREFL;
#pragma unroll
    for (int e = 0; e < 8; ++e) lg[e] = pl[e];
  }
  for (int i = 0; i < 128; i += 4) {
    const float4 xv = *(const float4*)(x + i);
#pragma unroll
    for (int u = 0; u < 4; ++u) {
      const float xi = (&xv.x)[u];
      const float4 ga = *(const float4*)(gw + (i+u)*8);
      const float4 gb = *(const float4*)(gw + (i+u)*8 + 4);
      lg[0] = fmaf(xi, ga.x, lg[0]); lg[1] = fmaf(xi, ga.y, lg[1]);
      lg[2] = fmaf(xi, ga.z, lg[2]); lg[3] = fmaf(xi, ga.w, lg[3]);
      lg[4] = fmaf(xi, gb.x, lg[4]); lg[5] = fmaf(xi, gb.y, lg[5]);
      lg[6] = fmaf(xi, gb.z, lg[6]); lg[7] = fmaf(xi, gb.w, lg[7]);
    }
  }
  int i0 = 0; float v0 = lg[0];
#pragma unroll
  for (int e = 1; e < 8; ++e) if (lg[e] > v0) { v0 = lg[e]; i0 = e; }
  int i1 = -1; float v1 = -1e30f;
#pragma unroll
  for (int e = 0; e < 8; ++e) if (e != i0 && lg[e] > v1) { v1 = lg[e]; i1 = e; }
  const float e1 = __expf(v1 - v0);
  const float w0 = 1.f / (1.f + e1);
  const float w1 = 1.f - w0;
  __shared__ int bcnt[8];
  __shared__ int gbase[8];
  if (tid < 8) bcnt[tid] = 0;
  __syncthreads();
  const int p0 = atomicAdd(&bcnt[i0], 1);
  const int p1 = atomicAdd(&bcnt[i1], 1);
  __syncthreads();
  if (tid < 8) {
    int* cnt = (int*)(ws + OFF_CNT);
    gbase[tid] = (bcnt[tid] > 0) ? atomicAdd(&cnt[tid], bcnt[tid]) : 0;
  }
  __syncthreads();
  int* tokp = (int*)(ws + OFF_TOK);
  float* wgtp = ws + OFF_WGT;
  const int s0 = gbase[i0] + p0;
  tokp[i0*16384 + s0] = t;             // rank 0
  wgtp[i0*16384 + s0] = w0;
  const int s1 = gbase[i1] + p1;
  tokp[i1*16384 + s1] = t | (1 << 30); // rank 1
  wgtp[i1*16384 + s1] = w1;
}

// ---------------- MoE experts: bf16 MFMA, per (expert, 64-token chunk) -----
__global__ __launch_bounds__(256)
void k_moe(const float* __restrict__ AO,
           const unsigned short* __restrict__ w1b,
           const unsigned short* __restrict__ w2b,
           const float* __restrict__ eb1, const float* __restrict__ eb2,
           float* __restrict__ ws,
           float* __restrict__ Y0, float* __restrict__ Y1) {
  const int e = blockIdx.y;
  const int ce = ((const int*)(ws + OFF_CNT))[e];
  const int base = blockIdx.x * 64;
  if (base >= ce) return;
  const int nt = min(64, ce - base);

  __shared__ unsigned short Xs[64*128];
  __shared__ unsigned short Wts[128*128];
  __shared__ unsigned short Hs[64*128];
  __shared__ float seb1[512];
  __shared__ float seb2[128];
  __shared__ int   stok[64];
  __shared__ float swgt[64];

  const int tid = threadIdx.x;
  if (tid < 64) {
    if (tid < nt) {
      stok[tid] = ((const int*)(ws + OFF_TOK))[e*16384 + base + tid];
      swgt[tid] = (ws + OFF_WGT)[e*16384 + base + tid];
    } else { stok[tid] = -1; swgt[tid] = 0.f; }
  }
  for (int i = tid; i < 512; i += 256) seb1[i] = eb1[e*512 + i];
  if (tid < 128) seb2[tid] = eb2[e*128 + tid];
  __syncthreads();

#pragma unroll
  for (int r8 = 0; r8 < 8; ++r8) {
    const int id = tid + r8*256;
    const int r = id >> 5, c = id & 31;
    const int pk = stok[r];
    float4 xv = make_float4(0.f, 0.f, 0.f, 0.f);
    if (pk >= 0) xv = *(const float4*)(AO + (long)(pk & 0x3FFFFFFF)*128 + c*4);
    uint2 pkd;
    pkd.x = f2bf(xv.x) | (f2bf(xv.y) << 16);
    pkd.y = f2bf(xv.z) | (f2bf(xv.w) << 16);
    const int bc = (c*8) ^ ((r & 7) << 4);
    *(uint2*)((char*)Xs + r*256 + bc) = pkd;
  }

  const int w  = tid >> 6;
  const int l  = tid & 63;
  const int lq = l >> 4;
  const int lr = l & 15;

  f32x4 yacc[2][4];
#pragma unroll
  for (int a = 0; a < 2; ++a)
#pragma unroll
    for (int m = 0; m < 4; ++m) yacc[a][m] = (f32x4){0.f, 0.f, 0.f, 0.f};

  for (int fc = 0; fc < 4; ++fc) {
    __syncthreads();
    {
      const long wb = (long)(e*512 + fc*128) * 128;
#pragma unroll
      for (int s = 0; s < 8; ++s) {
        const int id = tid + s*256;
        const int fr = id >> 4, c16 = id & 15;
        const uint4 v = *(const uint4*)(w1b + wb + (long)fr*128 + c16*8);
        *(uint4*)((char*)Wts + fr*256 + ((c16*16) ^ ((fr & 7) << 4))) = v;
      }
    }
    __syncthreads();
    f32x4 hacc[2][4];
#pragma unroll
    for (int a = 0; a < 2; ++a)
#pragma unroll
      for (int m = 0; m < 4; ++m) hacc[a][m] = (f32x4){0.f, 0.f, 0.f, 0.f};
#pragma unroll
    for (int ks = 0; ks < 4; ++ks) {
      const int bcol = ks*64 + lq*16;
      const bf16x8 a0 = ld_frag(Wts, (2*w  )*16 + lr, bcol);
      const bf16x8 a1 = ld_frag(Wts, (2*w+1)*16 + lr, bcol);
      const bf16x8 b0 = ld_frag(Xs,  0*16 + lr, bcol);
      const bf16x8 b1 = ld_frag(Xs,  1*16 + lr, bcol);
      const bf16x8 b2 = ld_frag(Xs,  2*16 + lr, bcol);
      const bf16x8 b3 = ld_frag(Xs,  3*16 + lr, bcol);
      hacc[0][0] = __builtin_amdgcn_mfma_f32_16x16x32_bf16(a0, b0, hacc[0][0], 0, 0, 0);
      hacc[0][1] = __builtin_amdgcn_mfma_f32_16x16x32_bf16(a0, b1, hacc[0][1], 0, 0, 0);
      hacc[0][2] = __builtin_amdgcn_mfma_f32_16x16x32_bf16(a0, b2, hacc[0][2], 0, 0, 0);
      hacc[0][3] = __builtin_amdgcn_mfma_f32_16x16x32_bf16(a0, b3, hacc[0][3], 0, 0, 0);
      hacc[1][0] = __builtin_amdgcn_mfma_f32_16x16x32_bf16(a1, b0, hacc[1][0], 0, 0, 0);
      hacc[1][1] = __builtin_amdgcn_mfma_f32_16x16x32_bf16(a1, b1, hacc[1][1], 0, 0, 0);
      hacc[1][2] = __builtin_amdgcn_mfma_f32_16x16x32_bf16(a1, b2, hacc[1][2], 0, 0, 0);
      hacc[1][3] = __builtin_amdgcn_mfma_f32_16x16x32_bf16(a1, b3, hacc[1][3], 0, 0, 0);
    }
    __syncthreads();
#pragma unroll
    for (int fbi = 0; fbi < 2; ++fbi) {
      const int fb = (2*w + fbi)*16 + lq*4;
      const float4 bia = *(const float4*)&seb1[fc*128 + fb];
#pragma unroll
      for (int mb = 0; mb < 4; ++mb) {
        const int m = mb*16 + lr;
        const float h0 = fmaxf(hacc[fbi][mb][0] + bia.x, 0.f);
        const float h1 = fmaxf(hacc[fbi][mb][1] + bia.y, 0.f);
        const float h2 = fmaxf(hacc[fbi][mb][2] + bia.z, 0.f);
        const float h3 = fmaxf(hacc[fbi][mb][3] + bia.w, 0.f);
        uint2 p;
        p.x = f2bf(h0) | (f2bf(h1) << 16);
        p.y = f2bf(h2) | (f2bf(h3) << 16);
        const int bc = (fb*2) ^ ((m & 7) << 4);
        *(uint2*)((char*)Hs + m*256 + bc) = p;
      }
    }
    {
      const long wb = (long)(e*128) * 512 + fc*128;
#pragma unroll
      for (int s = 0; s < 8; ++s) {
        const int id = tid + s*256;
        const int orr = id >> 4, c16 = id & 15;
        const uint4 v = *(const uint4*)(w2b + wb + (long)orr*512 + c16*8);
        *(uint4*)((char*)Wts + orr*256 + ((c16*16) ^ ((orr & 7) << 4))) = v;
      }
    }
    __syncthreads();
#pragma unroll
    for (int ks = 0; ks < 4; ++ks) {
      const int bcol = ks*64 + lq*16;
      const bf16x8 a0 = ld_frag(Wts, (2*w  )*16 + lr, bcol);
      const bf16x8 a1 = ld_frag(Wts, (2*w+1)*16 + lr, bcol);
      const bf16x8 b0 = ld_frag(Hs,  0*16 + lr, bcol);
      const bf16x8 b1 = ld_frag(Hs,  1*16 + lr, bcol);
      const bf16x8 b2 = ld_frag(Hs,  2*16 + lr, bcol);
      const bf16x8 b3 = ld_frag(Hs,  3*16 + lr, bcol);
      yacc[0][0] = __builtin_amdgcn_mfma_f32_16x16x32_bf16(a0, b0, yacc[0][0], 0, 0, 0);
      yacc[0][1] = __builtin_amdgcn_mfma_f32_16x16x32_bf16(a0, b1, yacc[0][1], 0, 0, 0);
      yacc[0][2] = __builtin_amdgcn_mfma_f32_16x16x32_bf16(a0, b2, yacc[0][2], 0, 0, 0);
      yacc[0][3] = __builtin_amdgcn_mfma_f32_16x16x32_bf16(a0, b3, yacc[0][3], 0, 0, 0);
      yacc[1][0] = __builtin_amdgcn_mfma_f32_16x16x32_bf16(a1, b0, yacc[1][0], 0, 0, 0);
      yacc[1][1] = __builtin_amdgcn_mfma_f32_16x16x32_bf16(a1, b1, yacc[1][1], 0, 0, 0);
      yacc[1][2] = __builtin_amdgcn_mfma_f32_16x16x32_bf16(a1, b2, yacc[1][2], 0, 0, 0);
      yacc[1][3] = __builtin_amdgcn_mfma_f32_16x16x32_bf16(a1, b3, yacc[1][3], 0, 0, 0);
    }
  }
#pragma unroll
  for (int obi = 0; obi < 2; ++obi) {
    const int ob = (2*w + obi)*16 + lq*4;
    const float4 b2 = *(const float4*)&seb2[ob];
#pragma unroll
    for (int mb = 0; mb < 4; ++mb) {
      const int tl = mb*16 + lr;
      if (tl < nt) {
        const int pk = stok[tl];
        const int tk = pk & 0x3FFFFFFF;
        const float wgt = swgt[tl];
        float* Yp = ((pk >> 30) ? Y1 : Y0) + (long)tk*128 + ob;
        float4 o;
        o.x = (yacc[obi][mb][0] + b2.x) * wgt;
        o.y = (yacc[obi][mb][1] + b2.y) * wgt;
        o.z = (yacc[obi][mb][2] + b2.z) * wgt;
        o.w = (yacc[obi][mb][3] + b2.w) * wgt;
        *(float4*)Yp = o;
      }
    }
  }
}

// ---------------- fused sc GEMM + tanh + fixed-max softmax -----------------
__global__ __launch_bounds__(512)
void k_gemm2f(const unsigned short* __restrict__ mhb,
              const unsigned short* __restrict__ encb,
              const float* __restrict__ mask,
              float* __restrict__ out) {
  const int bid = blockIdx.x;
  const int b = bid & 31, rt = bid >> 5;
  __shared__ unsigned short Amh[64*128];
  __shared__ unsigned short Bch[512*32];
  __shared__ float red[64][9];
  const int tid = threadIdx.x;
  const int w = tid >> 6, l = tid & 63, lq = l >> 4, lr = l & 15;
  const long rowbase = (long)b*512 + rt*64;
#pragma unroll
  for (int s = 0; s < 2; ++s) {
    const int id = tid + s*512;
    const int r = id >> 4, c16 = id & 15;
    const uint4 v = *(const uint4*)(mhb + (rowbase + r)*128 + c16*8);
    *(uint4*)((char*)Amh + r*256 + ((c16*16) ^ ((r & 7) << 4))) = v;
  }
  f32x4 acc[4][4];
#pragma unroll
  for (int mi = 0; mi < 4; ++mi)
#pragma unroll
    for (int ni = 0; ni < 4; ++ni) acc[mi][ni] = (f32x4){0.f, 0.f, 0.f, 0.f};
  for (int kc = 0; kc < 4; ++kc) {
    __syncthreads();
#pragma unroll
    for (int s = 0; s < 4; ++s) {
      const int id = tid + s*512;
      const int n = id >> 2, sl = id & 3;
      const uint4 v = *(const uint4*)(encb + ((long)b*512 + n)*128 + kc*32 + sl*8);
      *(uint4*)((char*)Bch + n*64 + ((sl*16) ^ ((n & 3) << 4))) = v;
    }
    __syncthreads();
    bf16x8 af[4], bfr[4];
#pragma unroll
    for (int mi = 0; mi < 4; ++mi) {
      const int r = mi*16 + lr;
      af[mi] = *(const bf16x8*)((const char*)Amh + r*256 + ((kc*64 + lq*16) ^ ((r & 7) << 4)));
    }
#pragma unroll
    for (int ni = 0; ni < 4; ++ni) {
      const int n = w*64 + ni*16 + lr;
      bfr[ni] = *(const bf16x8*)((const char*)Bch + n*64 + ((lq*16) ^ ((n & 3) << 4)));
    }
#pragma unroll
    for (int mi = 0; mi < 4; ++mi)
#pragma unroll
      for (int ni = 0; ni < 4; ++ni)
        acc[mi][ni] = __builtin_amdgcn_mfma_f32_16x16x32_bf16(af[mi], bfr[ni], acc[mi][ni], 0, 0, 0);
  }
  const float ISC = 1.f/11.313708498984761f;
  float rsum[4][4];
#pragma unroll
  for (int mi = 0; mi < 4; ++mi)
#pragma unroll
    for (int j = 0; j < 4; ++j) rsum[mi][j] = 0.f;
#pragma unroll
  for (int mi = 0; mi < 4; ++mi) {
#pragma unroll
    for (int j = 0; j < 4; ++j) {
      const long row = rowbase + mi*16 + lq*4 + j;
      const float* mrow = mask + row*512 + w*64 + lr;
#pragma unroll
      for (int ni = 0; ni < 4; ++ni) {
        const float sc = acc[mi][ni][j] * ISC;
        const float li = 10.f*tanhf(sc) + mrow[ni*16];
        const float e = __expf(li - 10.f);
        acc[mi][ni][j] = e;
        rsum[mi][j] += e;
      }
    }
  }
#pragma unroll
  for (int mi = 0; mi < 4; ++mi)
#pragma unroll
    for (int j = 0; j < 4; ++j) {
#pragma unroll
      for (int o = 1; o < 16; o <<= 1) rsum[mi][j] += __shfl_xor(rsum[mi][j], o);
    }
  if (lr == 0) {
#pragma unroll
    for (int mi = 0; mi < 4; ++mi)
#pragma unroll
      for (int j = 0; j < 4; ++j) red[mi*16 + lq*4 + j][w] = rsum[mi][j];
  }
  __syncthreads();
  if (tid < 64) {
    float s = 0.f;
#pragma unroll
    for (int wv = 0; wv < 8; ++wv) s += red[tid][wv];
    red[tid][8] = 1.f / s;
  }
  __syncthreads();
#pragma unroll
  for (int mi = 0; mi < 4; ++mi) {
#pragma unroll
    for (int j = 0; j < 4; ++j) {
      const int rl = mi*16 + lq*4 + j;
      const float inv = red[rl][8];
      float* orow = out + (rowbase + rl)*512 + w*64 + lr;
#pragma unroll
      for (int ni = 0; ni < 4; ++ni) orow[ni*16] = acc[mi][ni][j] * inv;
    }
  }
}

// ---------------------------------------------------------------------------
extern "C" void kernel_launch(void* const* d_in, const int* in_sizes, int n_in,
                              void* d_out, int out_size, void* d_ws, size_t ws_size,
                              hipStream_t stream) {
  (void)in_sizes; (void)n_in; (void)out_size; (void)ws_size;
  const float* pref  = (const float*)d_in[0];
  const float* graph = (const float*)d_in[1];
  const float* cap   = (const float*)d_in[2];
  const float* enc   = (const float*)d_in[3];
  const float* mask  = (const float*)d_in[4];
  const float* fc1w  = (const float*)d_in[5];
  const float* fc1b  = (const float*)d_in[6];
  const float* fc2w  = (const float*)d_in[7];
  const float* fc2b  = (const float*)d_in[8];
  const float* fc3w  = (const float*)d_in[9];
  const float* fc3b  = (const float*)d_in[10];
  const float* hWq   = (const float*)d_in[11];
  const float* hWk   = (const float*)d_in[12];
  const float* hWv   = (const float*)d_in[13];
  const float* hWc   = (const float*)d_in[14];
  const float* gw    = (const float*)d_in[15];
  const float* gpw   = (const float*)d_in[16];
  const float* ew1   = (const float*)d_in[17];
  const float* eb1   = (const float*)d_in[18];
  const float* ew2   = (const float*)d_in[19];
  const float* eb2   = (const float*)d_in[20];
  float* ws  = (float*)d_ws;
  float* out = (float*)d_out;
  // d_out scratch: Kb/Vb bf16 [0,8MB) dead after attn; Y0 [0,8MB), Y1 [8,16MB);
  // ew1b [16,17MB), ew2b [17,18MB). k_gemm2f overwrites all of d_out.
  unsigned short* Kbuf = (unsigned short*)out;
  unsigned short* Vbuf = (unsigned short*)(out + 1048576);
  float* Y0 = out;
  float* Y1 = out + 2097152;
  unsigned short* ew1b = (unsigned short*)(out + 4194304);
  unsigned short* ew2b = (unsigned short*)(out + 4456448);
  unsigned short* mhb  = (unsigned short*)(ws + OFF_MH);
  unsigned short* encb = (unsigned short*)(ws + OFF_ENCB);
  unsigned short* wkb  = (unsigned short*)(ws + OFF_WKB);
  unsigned short* wvb  = (unsigned short*)(ws + OFF_WVB);
  unsigned short* wcb  = (unsigned short*)(ws + OFF_WCB);

  k_prep<<<3280, 256, 0, stream>>>(pref, fc1w, fc1b, fc2w, fc2b, fc3w, fc3b,
                                   gpw, graph, hWq, hWk, hWv, hWc,
                                   ew1, ew2, enc, ew1b, ew2b, encb, ws);
  k_kv<<<dim3(256, 2), 256, 0, stream>>>(encb, wkb, wvb, Kbuf, Vbuf);
  k_attn<<<1024, 512, 0, stream>>>(Kbuf, Vbuf, ws, cap, mask, ws + OFF_AO);
  k_gate<<<64, 256, 0, stream>>>(ws + OFF_AO, gw, ws);
  k_moe<<<dim3(256, 8), 256, 0, stream>>>(ws + OFF_AO, ew1b, ew2b, eb1, eb2, ws, Y0, Y1);
  k_mh<<<256, 256, 0, stream>>>(Y0, Y1, wcb, mhb);
  k_gemm2f<<<256, 512, 0, stream>>>(mhb, encb, mask, out);
}

// Round 9
// 121.908 us; speedup vs baseline: 7.4445x; 1.0475x over previous
//
#include <hip/hip_runtime.h>

// ---------------------------------------------------------------------------
// KP_Decoder: hypernet -> (k,v,q) -> attention -> top2 MoE -> combine softmax
// B=32 G=512 N=512 EMB=128 H=8 DK=16 E=8 FH=512 K=2
// R3-R8: bf16 MFMA everywhere; fused tanh-softmax; q-split attn.
// R9: mask-flag skip (attn was L3-BW-bound on 268MB of redundant mask reads:
//     per-row nonzero flag, wave-uniform skip); k_prep split (hypernet once,
//     hidden under cvt blocks); attn LDS pitches restored (Kbf24/Vt536/Ps40).
// ---------------------------------------------------------------------------

typedef __attribute__((ext_vector_type(8))) __bf16 bf16x8;
typedef __attribute__((ext_vector_type(4))) float f32x4;

// ws layout (float offsets)
static constexpr long OFF_MID   = 0;        // 8
static constexpr long OFF_PREFL = 8;        // 8
static constexpr long OFF_WL    = 16;       // 128 (Wq[:,128] capacity col)
static constexpr long OFF_WKB   = 256;      // 128x128 bf16
static constexpr long OFF_WVB   = 8448;     // 128x128 bf16
static constexpr long OFF_WCB   = 16640;    // 128x128 bf16
static constexpr long OFF_QB    = 24832;    // 32x128 qbase fp32
static constexpr long OFF_MFLAG = 28928;    // 16384 bytes (4096 floats)
static constexpr long OFF_CNT   = 33024;    // 8 ints
static constexpr long OFF_TOK   = 33032;    // 8*16384 ints
static constexpr long OFF_WGT   = 164104;   // 8*16384 floats
static constexpr long OFF_AO    = 295176;   // 16384x128 fp32 attention out
static constexpr long OFF_MH    = 2392328;  // 16384x128 bf16 mh
static constexpr long OFF_ENCB  = 3440904;  // 16384x128 bf16 enc
// total 4,489,480 floats = 17.96 MB

__device__ __forceinline__ unsigned f2bf(float x) {
  union { float f; unsigned u; } v; v.f = x;
  return ((v.u + 0x7FFFu + ((v.u >> 16) & 1u)) >> 16) & 0xFFFFu;
}

// ---------------- k_prep1: hypernet (1 block) + cvt + mask flags -----------
// bid 0: hypernet -> mid/prefl/wl/cnt.  bid 1..3072: bf16 cvt.
// bid 3073..5120: per-row mask nonzero flags (8 rows/block).
__global__ __launch_bounds__(256)
void k_prep1(const float* __restrict__ pref, const float* __restrict__ fc1w,
             const float* __restrict__ fc1b, const float* __restrict__ fc2w,
             const float* __restrict__ fc2b, const float* __restrict__ fc3w,
             const float* __restrict__ fc3b, const float* __restrict__ gpw,
             const float* __restrict__ hWq, const float* __restrict__ mask,
             const float* __restrict__ ew1, const float* __restrict__ ew2,
             const float* __restrict__ enc,
             unsigned short* __restrict__ w1b, unsigned short* __restrict__ w2b,
             unsigned short* __restrict__ encb, float* __restrict__ ws) {
  const int bid = blockIdx.x;
  const int tid = threadIdx.x;
  if (bid == 0) {
    __shared__ float h1[256];
    __shared__ float h2[256];
    __shared__ float mid[8];
    const float p0 = pref[0], p1 = pref[1];
    h1[tid] = fc1w[2*tid]*p0 + fc1w[2*tid+1]*p1 + fc1b[tid];
    __syncthreads();
    float s = 0.f;
    for (int j = 0; j < 256; ++j) s = fmaf(fc2w[tid*256+j], h1[j], s);
    h2[tid] = s + fc2b[tid];
    __syncthreads();
    if (tid < 8) {
      float s2 = 0.f;
      for (int j = 0; j < 256; ++j) s2 = fmaf(fc3w[tid*256+j], h2[j], s2);
      mid[tid] = s2 + fc3b[tid];
    }
    __syncthreads();
    if (tid < 8) {
      ws[OFF_MID + tid] = mid[tid];
      float s3 = 0.f;
      for (int i = 0; i < 8; ++i) s3 = fmaf(mid[i], gpw[i*8 + tid], s3);
      ws[OFF_PREFL + tid] = s3;
      ((int*)(ws + OFF_CNT))[tid] = 0;
    }
    if (tid >= 16 && tid < 144) {
      const int o = tid - 16;
      ws[OFF_WL + o] = hWq[((long)o*129 + 128)*2]*mid[0]
                     + hWq[((long)o*129 + 128)*2 + 1]*mid[1];
    }
    return;
  }
  if (bid <= 3072) {
    const int i = (bid-1)*256 + tid;
    const float* src;
    unsigned short* dst;
    if (i < 131072)      { src = ew1 + (long)i*4;          dst = w1b + (long)i*4; }
    else if (i < 262144) { src = ew2 + (long)(i-131072)*4; dst = w2b + (long)(i-131072)*4; }
    else                 { src = enc + (long)(i-262144)*4; dst = encb + (long)(i-262144)*4; }
    const float4 v = *(const float4*)src;
    uint2 p;
    p.x = f2bf(v.x) | (f2bf(v.y) << 16);
    p.y = f2bf(v.z) | (f2bf(v.w) << 16);
    *(uint2*)dst = p;
    return;
  }
  // mask flags: 8 rows per block
  __shared__ int fl[8];
  const int rowbase = (bid - 3073) * 8;
  const int r = tid >> 5, seg = tid & 31;
  if (tid < 8) fl[tid] = 0;
  __syncthreads();
  const float* mrow = mask + (long)(rowbase + r)*512 + seg*16;
  int nz = 0;
#pragma unroll
  for (int c = 0; c < 4; ++c) {
    const float4 v = *(const float4*)(mrow + c*4);
    nz |= (v.x != 0.f) | (v.y != 0.f) | (v.z != 0.f) | (v.w != 0.f);
  }
  if (nz) atomicOr(&fl[r], 1);
  __syncthreads();
  if (tid < 8) ((char*)(ws + OFF_MFLAG))[rowbase + tid] = (char)fl[tid];
}

// ---------------- k_prep2: Wk/Wv/Wc heads + qbase (reads mid from ws) ------
__global__ __launch_bounds__(256)
void k_prep2(const float* __restrict__ graph,
             const float* __restrict__ hWq, const float* __restrict__ hWk,
             const float* __restrict__ hWv, const float* __restrict__ hWc,
             float* __restrict__ ws) {
  const int bid = blockIdx.x;
  const int tid = threadIdx.x;
  __shared__ float mid[8];
  __shared__ float g[2][128];
  if (tid < 8) mid[tid] = ws[OFF_MID + tid];
  __syncthreads();
  if (bid < 192) {
    const int i = bid*256 + tid;   // 0..49151
    if (i < 16384) {
      ((unsigned short*)(ws + OFF_WKB))[i] =
          (unsigned short)f2bf(hWk[2*i]*mid[2] + hWk[2*i+1]*mid[3]);
    } else if (i < 32768) {
      const int j = i - 16384;
      ((unsigned short*)(ws + OFF_WVB))[j] =
          (unsigned short)f2bf(hWv[2*j]*mid[4] + hWv[2*j+1]*mid[5]);
    } else {
      const int j = i - 32768;
      ((unsigned short*)(ws + OFF_WCB))[j] =
          (unsigned short)f2bf(hWc[2*j]*mid[6] + hWc[2*j+1]*mid[7]);
    }
    return;
  }
  const int qb = bid - 192;
  const int b0 = qb*2;
  {
    const int bb = tid >> 7, ii = tid & 127;
    g[bb][ii] = graph[(b0+bb)*128 + ii];
  }
  __syncthreads();
  const float m0 = mid[0], m1 = mid[1];
  const int bb = tid >> 7, o = tid & 127;
  const float* hq = hWq + (long)o*129*2;
  float acc = 0.f;
  for (int i2 = 0; i2 < 128; ++i2) {
    const float w = hq[2*i2]*m0 + hq[2*i2+1]*m1;
    acc = fmaf(g[bb][i2], w, acc);
  }
  ws[OFF_QB + (b0+bb)*128 + o] = acc;
}

// ---------------- shared swizzled-LDS fragment loader (256B rows) ----------
__device__ __forceinline__ bf16x8 ld_frag(const unsigned short* base, int row, int bytecol) {
  const int addr = row*256 + (bytecol ^ ((row & 7) << 4));
  return *(const bf16x8*)((const char*)base + addr);
}

// ---------------- k_kv: bf16 MFMA GEMM, {K,V}[n][o] = enc . W^T ------------
__global__ __launch_bounds__(256)
void k_kv(const unsigned short* __restrict__ encb,
          const unsigned short* __restrict__ wkb,
          const unsigned short* __restrict__ wvb,
          unsigned short* __restrict__ Kb, unsigned short* __restrict__ Vb) {
  __shared__ unsigned short Ws[128*128];
  __shared__ unsigned short Xs[64*128];
  const int tid = threadIdx.x;
  const int nbase = blockIdx.x * 64;
  const unsigned short* Wb = blockIdx.y ? wvb : wkb;
  unsigned short* Cb = blockIdx.y ? Vb : Kb;
#pragma unroll
  for (int s = 0; s < 8; ++s) {
    const int id = tid + s*256;
    const int fr = id >> 4, c16 = id & 15;
    const uint4 v = *(const uint4*)(Wb + (long)fr*128 + c16*8);
    *(uint4*)((char*)Ws + fr*256 + ((c16*16) ^ ((fr & 7) << 4))) = v;
  }
#pragma unroll
  for (int s = 0; s < 4; ++s) {
    const int id = tid + s*256;
    const int r = id >> 4, c16 = id & 15;
    const uint4 v = *(const uint4*)(encb + (long)(nbase + r)*128 + c16*8);
    *(uint4*)((char*)Xs + r*256 + ((c16*16) ^ ((r & 7) << 4))) = v;
  }
  __syncthreads();
  const int w = tid >> 6, l = tid & 63, lq = l >> 4, lr = l & 15;
  f32x4 acc[2][4];
#pragma unroll
  for (int a = 0; a < 2; ++a)
#pragma unroll
    for (int m = 0; m < 4; ++m) acc[a][m] = (f32x4){0.f, 0.f, 0.f, 0.f};
#pragma unroll
  for (int ks = 0; ks < 4; ++ks) {
    const int bcol = ks*64 + lq*16;
    const bf16x8 a0 = ld_frag(Ws, (2*w  )*16 + lr, bcol);
    const bf16x8 a1 = ld_frag(Ws, (2*w+1)*16 + lr, bcol);
    const bf16x8 b0 = ld_frag(Xs, 0*16 + lr, bcol);
    const bf16x8 b1 = ld_frag(Xs, 1*16 + lr, bcol);
    const bf16x8 b2 = ld_frag(Xs, 2*16 + lr, bcol);
    const bf16x8 b3 = ld_frag(Xs, 3*16 + lr, bcol);
    acc[0][0] = __builtin_amdgcn_mfma_f32_16x16x32_bf16(a0, b0, acc[0][0], 0, 0, 0);
    acc[0][1] = __builtin_amdgcn_mfma_f32_16x16x32_bf16(a0, b1, acc[0][1], 0, 0, 0);
    acc[0][2] = __builtin_amdgcn_mfma_f32_16x16x32_bf16(a0, b2, acc[0][2], 0, 0, 0);
    acc[0][3] = __builtin_amdgcn_mfma_f32_16x16x32_bf16(a0, b3, acc[0][3], 0, 0, 0);
    acc[1][0] = __builtin_amdgcn_mfma_f32_16x16x32_bf16(a1, b0, acc[1][0], 0, 0, 0);
    acc[1][1] = __builtin_amdgcn_mfma_f32_16x16x32_bf16(a1, b1, acc[1][1], 0, 0, 0);
    acc[1][2] = __builtin_amdgcn_mfma_f32_16x16x32_bf16(a1, b2, acc[1][2], 0, 0, 0);
    acc[1][3] = __builtin_amdgcn_mfma_f32_16x16x32_bf16(a1, b3, acc[1][3], 0, 0, 0);
  }
#pragma unroll
  for (int obi = 0; obi < 2; ++obi) {
    const int o0 = (2*w + obi)*16 + lq*4;
#pragma unroll
    for (int mb = 0; mb < 4; ++mb) {
      const long n = nbase + mb*16 + lr;
      uint2 pp;
      pp.x = f2bf(acc[obi][mb][0]) | (f2bf(acc[obi][mb][1]) << 16);
      pp.y = f2bf(acc[obi][mb][2]) | (f2bf(acc[obi][mb][3]) << 16);
      *(uint2*)(Cb + n*128 + o0) = pp;
    }
  }
}

// ---------------- k_mh: bf16 MFMA GEMM, mh[n][o] = (Y0+Y1) . Wc^T ----------
__global__ __launch_bounds__(256)
void k_mh(const float* __restrict__ Y0, const float* __restrict__ Y1,
          const unsigned short* __restrict__ wcb,
          unsigned short* __restrict__ mhb) {
  __shared__ unsigned short Ws[128*128];
  __shared__ unsigned short Xs[64*128];
  const int tid = threadIdx.x;
  const int nbase = blockIdx.x * 64;
#pragma unroll
  for (int s = 0; s < 8; ++s) {
    const int id = tid + s*256;
    const int fr = id >> 4, c16 = id & 15;
    const uint4 v = *(const uint4*)(wcb + (long)fr*128 + c16*8);
    *(uint4*)((char*)Ws + fr*256 + ((c16*16) ^ ((fr & 7) << 4))) = v;
  }
#pragma unroll
  for (int s = 0; s < 4; ++s) {
    const int id = tid + s*256;
    const int r = id >> 4, c16 = id & 15;
    const long base = (long)(nbase + r)*128 + c16*8;
    const float4 a0 = *(const float4*)(Y0 + base);
    const float4 a1 = *(const float4*)(Y0 + base + 4);
    const float4 b0 = *(const float4*)(Y1 + base);
    const float4 b1 = *(const float4*)(Y1 + base + 4);
    uint4 p;
    p.x = f2bf(a0.x + b0.x) | (f2bf(a0.y + b0.y) << 16);
    p.y = f2bf(a0.z + b0.z) | (f2bf(a0.w + b0.w) << 16);
    p.z = f2bf(a1.x + b1.x) | (f2bf(a1.y + b1.y) << 16);
    p.w = f2bf(a1.z + b1.z) | (f2bf(a1.w + b1.w) << 16);
    *(uint4*)((char*)Xs + r*256 + ((c16*16) ^ ((r & 7) << 4))) = p;
  }
  __syncthreads();
  const int w = tid >> 6, l = tid & 63, lq = l >> 4, lr = l & 15;
  f32x4 acc[2][4];
#pragma unroll
  for (int a = 0; a < 2; ++a)
#pragma unroll
    for (int m = 0; m < 4; ++m) acc[a][m] = (f32x4){0.f, 0.f, 0.f, 0.f};
#pragma unroll
  for (int ks = 0; ks < 4; ++ks) {
    const int bcol = ks*64 + lq*16;
    const bf16x8 a0 = ld_frag(Ws, (2*w  )*16 + lr, bcol);
    const bf16x8 a1 = ld_frag(Ws, (2*w+1)*16 + lr, bcol);
    const bf16x8 b0 = ld_frag(Xs, 0*16 + lr, bcol);
    const bf16x8 b1 = ld_frag(Xs, 1*16 + lr, bcol);
    const bf16x8 b2 = ld_frag(Xs, 2*16 + lr, bcol);
    const bf16x8 b3 = ld_frag(Xs, 3*16 + lr, bcol);
    acc[0][0] = __builtin_amdgcn_mfma_f32_16x16x32_bf16(a0, b0, acc[0][0], 0, 0, 0);
    acc[0][1] = __builtin_amdgcn_mfma_f32_16x16x32_bf16(a0, b1, acc[0][1], 0, 0, 0);
    acc[0][2] = __builtin_amdgcn_mfma_f32_16x16x32_bf16(a0, b2, acc[0][2], 0, 0, 0);
    acc[0][3] = __builtin_amdgcn_mfma_f32_16x16x32_bf16(a0, b3, acc[0][3], 0, 0, 0);
    acc[1][0] = __builtin_amdgcn_mfma_f32_16x16x32_bf16(a1, b0, acc[1][0], 0, 0, 0);
    acc[1][1] = __builtin_amdgcn_mfma_f32_16x16x32_bf16(a1, b1, acc[1][1], 0, 0, 0);
    acc[1][2] = __builtin_amdgcn_mfma_f32_16x16x32_bf16(a1, b2, acc[1][2], 0, 0, 0);
    acc[1][3] = __builtin_amdgcn_mfma_f32_16x16x32_bf16(a1, b3, acc[1][3], 0, 0, 0);
  }
#pragma unroll
  for (int obi = 0; obi < 2; ++obi) {
    const int o0 = (2*w + obi)*16 + lq*4;
#pragma unroll
    for (int mb = 0; mb < 4; ++mb) {
      const long n = nbase + mb*16 + lr;
      uint2 pp;
      pp.x = f2bf(acc[obi][mb][0]) | (f2bf(acc[obi][mb][1]) << 16);
      pp.y = f2bf(acc[obi][mb][2]) | (f2bf(acc[obi][mb][3]) << 16);
      *(uint2*)(mhb + n*128 + o0) = pp;
    }
  }
}

// ---------------- MFMA flash attention v4 ----------------------------------
// grid 1024: b = bid&31, h = (bid>>5)&7, qh = bid>>8; 512 thr, 8 waves;
// wave owns one 16-row q-tile. LDS ~52KB -> 3 blocks/CU. Mask loads skipped
// wave-uniformly when per-row flags say all-zero (exact).
__global__ __launch_bounds__(512, 8)
void k_attn(const unsigned short* __restrict__ Kb,
            const unsigned short* __restrict__ Vb,
            const float* __restrict__ ws, const float* __restrict__ cap,
            const float* __restrict__ mask, float* __restrict__ AO) {
  const int bid = blockIdx.x;
  const int b = bid & 31, h = (bid >> 5) & 7, qh = bid >> 8;
  __shared__ unsigned short Kbf[512*24];  // 24 KB, 48B rows (bank-spread)
  __shared__ unsigned short Vt[16*536];   // 16.75 KB, 1072B rows
  __shared__ unsigned short Ps[8*16*40];  // 10 KB, 80B rows
  const int tid = threadIdx.x;
#pragma unroll
  for (int it = 0; it < 2; ++it) {
    const int i = tid + it*512;           // 0..1023
    const int n = i >> 1, hf = i & 1;
    const long src = (long)(b*512 + n)*128 + h*16 + hf*8;
    const uint4 kv = *(const uint4*)(Kb + src);
    *(uint4*)(Kbf + n*24 + hf*8) = kv;
    const uint4 vv = *(const uint4*)(Vb + src);
    const unsigned short* sp = (const unsigned short*)&vv;
#pragma unroll
    for (int j = 0; j < 8; ++j) Vt[(hf*8 + j)*536 + n] = sp[j];
  }
  const int w = tid >> 6, l = tid & 63;
  const int lq = l >> 4, lr = l & 15;
  const int grow = qh*128 + w*16 + lr;    // this lane's q-row
  bf16x8 qf;
  {
    union { uint4 u; bf16x8 v; } cv;
    cv.u = make_uint4(0u, 0u, 0u, 0u);
    if (lq < 2) {
      const float* qbp = ws + OFF_QB + b*128 + h*16 + lq*8;
      const float* wlp = ws + OFF_WL + h*16 + lq*8;
      const float cp = cap[b*512 + grow];
      float qv[8];
#pragma unroll
      for (int j = 0; j < 8; ++j) qv[j] = (qbp[j] + cp*wlp[j]) * 0.25f;
      cv.u.x = f2bf(qv[0]) | (f2bf(qv[1]) << 16);
      cv.u.y = f2bf(qv[2]) | (f2bf(qv[3]) << 16);
      cv.u.z = f2bf(qv[4]) | (f2bf(qv[5]) << 16);
      cv.u.w = f2bf(qv[6]) | (f2bf(qv[7]) << 16);
    }
    qf = cv.v;
  }
  const int mf = ((const char*)(ws + OFF_MFLAG))[b*512 + grow];
  const bool usemask = __any(mf != 0);
  unsigned short* Pw = Ps + w*16*40;
  const int psw = (lr & 3) << 3;
  __syncthreads();
  float m = -3.0e38f, lsum = 0.f;
  f32x4 oacc = {0.f, 0.f, 0.f, 0.f};
  const float* mrow = mask + ((long)(b*512 + grow))*512 + lq*4;
  for (int qc = 0; qc < 16; ++qc) {       // 16 quarter-chunks of 32 n
    const int n0 = qc*32;
    f32x4 s[2];
#pragma unroll
    for (int nb = 0; nb < 2; ++nb) {
      bf16x8 kf;
      {
        union { uint4 u; bf16x8 v; } cv;
        cv.u = make_uint4(0u, 0u, 0u, 0u);
        if (lq < 2) cv.u = *(const uint4*)(Kbf + (n0 + nb*16 + lr)*24 + lq*8);
        kf = cv.v;
      }
      s[nb] = __builtin_amdgcn_mfma_f32_16x16x32_bf16(
          kf, qf, (f32x4){0.f, 0.f, 0.f, 0.f}, 0, 0, 0);
      if (usemask) {
        const float4 mk = *(const float4*)(mrow + n0 + nb*16);
        s[nb][0] += mk.x; s[nb][1] += mk.y; s[nb][2] += mk.z; s[nb][3] += mk.w;
      }
    }
    f32x4 mx;
    mx[0] = fmaxf(s[0][0], s[1][0]); mx[1] = fmaxf(s[0][1], s[1][1]);
    mx[2] = fmaxf(s[0][2], s[1][2]); mx[3] = fmaxf(s[0][3], s[1][3]);
    float cm = fmaxf(fmaxf(mx[0], mx[1]), fmaxf(mx[2], mx[3]));
    cm = fmaxf(cm, __shfl_xor(cm, 16));
    cm = fmaxf(cm, __shfl_xor(cm, 32));
    const float nm = fmaxf(m, cm);
    const float rs = __expf(m - nm);
    lsum *= rs;
    oacc[0] *= rs; oacc[1] *= rs; oacc[2] *= rs; oacc[3] *= rs;
    m = nm;
    float ls = 0.f;
#pragma unroll
    for (int nb = 0; nb < 2; ++nb) {
      const float e0 = __expf(s[nb][0] - m);
      const float e1 = __expf(s[nb][1] - m);
      const float e2 = __expf(s[nb][2] - m);
      const float e3 = __expf(s[nb][3] - m);
      ls += (e0 + e1) + (e2 + e3);
      uint2 pp;
      asm("v_cvt_pk_bf16_f32 %0, %1, %2" : "=v"(pp.x) : "v"(e0), "v"(e1));
      asm("v_cvt_pk_bf16_f32 %0, %1, %2" : "=v"(pp.y) : "v"(e2), "v"(e3));
      *(uint2*)(Pw + lr*40 + ((nb*16 + lq*4) ^ psw)) = pp;
    }
    lsum += ls;
    const bf16x8 va = *(const bf16x8*)(Vt + lr*536 + n0 + lq*8);
    const bf16x8 pb = *(const bf16x8*)(Pw + lr*40 + (lq*8 ^ psw));
    oacc = __builtin_amdgcn_mfma_f32_16x16x32_bf16(va, pb, oacc, 0, 0, 0);
  }
  lsum += __shfl_xor(lsum, 16);
  lsum += __shfl_xor(lsum, 32);
  const float inv = 1.f / lsum;
  float4 o;
  o.x = oacc[0]*inv; o.y = oacc[1]*inv; o.z = oacc[2]*inv; o.w = oacc[3]*inv;
  *(float4*)(AO + (long)(b*512 + grow)*128 + h*16 + lq*4) = o;
}

// ---------------- gating: top-2 + expert lists (block-aggregated) ----------
__global__ __launch_bounds__(256)
void k_gate(const float* __restrict__ AO, const float* __restrict__ gw,
            float* __restrict__ ws) {
  const int tid = threadIdx.x;
  const int t = blockIdx.x*256 + tid;
  const float* x = AO + (long)t*128;
  float lg[8];
  {
    const float* pl = ws + OFF_PREFL;
#pragma unroll
    for (int e = 0; e < 8; ++e) lg[e] = pl[e];
  }
  for (int i = 0; i < 128; i += 4) {
    const float4 xv = *(const float4*)(x + i);
#pragma unroll
    for (int u = 0; u < 4; ++u) {
      const float xi = (&xv.x)[u];
      const float4 ga = *(const float4*)(gw + (i+u)*8);
      const float4 gb = *(const float4*)(gw + (i+u)*8 + 4);
      lg[0] = fmaf(xi, ga.x, lg[0]); lg[1] = fmaf(xi, ga.y, lg[1]);
      lg[2] = fmaf(xi, ga.z, lg[2]); lg[3] = fmaf(xi, ga.w, lg[3]);
      lg[4] = fmaf(xi, gb.x, lg[4]); lg[5] = fmaf(xi, gb.y, lg[5]);
      lg[6] = fmaf(xi, gb.z, lg[6]); lg[7] = fmaf(xi, gb.w, lg[7]);
    }
  }
  int i0 = 0; float v0 = lg[0];
#pragma unroll
  for (int e = 1; e < 8; ++e) if (lg[e] > v0) { v0 = lg[e]; i0 = e; }
  int i1 = -1; float v1 = -1e30f;
#pragma unroll
  for (int e = 0; e < 8; ++e) if (e != i0 && lg[e] > v1) { v1 = lg[e]; i1 = e; }
  const float e1 = __expf(v1 - v0);
  const float w0 = 1.f / (1.f + e1);
  const float w1 = 1.f - w0;
  __shared__ int bcnt[8];
  __shared__ int gbase[8];
  if (tid < 8) bcnt[tid] = 0;
  __syncthreads();
  const int p0 = atomicAdd(&bcnt[i0], 1);
  const int p1 = atomicAdd(&bcnt[i1], 1);
  __syncthreads();
  if (tid < 8) {
    int* cnt = (int*)(ws + OFF_CNT);
    gbase[tid] = (bcnt[tid] > 0) ? atomicAdd(&cnt[tid], bcnt[tid]) : 0;
  }
  __syncthreads();
  int* tokp = (int*)(ws + OFF_TOK);
  float* wgtp = ws + OFF_WGT;
  const int s0 = gbase[i0] + p0;
  tokp[i0*16384 + s0] = t;             // rank 0
  wgtp[i0*16384 + s0] = w0;
  const int s1 = gbase[i1] + p1;
  tokp[i1*16384 + s1] = t | (1 << 30); // rank 1
  wgtp[i1*16384 + s1] = w1;
}

// ---------------- MoE experts: bf16 MFMA, per (expert, 64-token chunk) -----
__global__ __launch_bounds__(256)
void k_moe(const float* __restrict__ AO,
           const unsigned short* __restrict__ w1b,
           const unsigned short* __restrict__ w2b,
           const float* __restrict__ eb1, const float* __restrict__ eb2,
           float* __restrict__ ws,
           float* __restrict__ Y0, float* __restrict__ Y1) {
  const int e = blockIdx.y;
  const int ce = ((const int*)(ws + OFF_CNT))[e];
  const int base = blockIdx.x * 64;
  if (base >= ce) return;
  const int nt = min(64, ce - base);

  __shared__ unsigned short Xs[64*128];
  __shared__ unsigned short Wts[128*128];
  __shared__ unsigned short Hs[64*128];
  __shared__ float seb1[512];
  __shared__ float seb2[128];
  __shared__ int   stok[64];
  __shared__ float swgt[64];

  const int tid = threadIdx.x;
  if (tid < 64) {
    if (tid < nt) {
      stok[tid] = ((const int*)(ws + OFF_TOK))[e*16384 + base + tid];
      swgt[tid] = (ws + OFF_WGT)[e*16384 + base + tid];
    } else { stok[tid] = -1; swgt[tid] = 0.f; }
  }
  for (int i = tid; i < 512; i += 256) seb1[i] = eb1[e*512 + i];
  if (tid < 128) seb2[tid] = eb2[e*128 + tid];
  __syncthreads();

#pragma unroll
  for (int r8 = 0; r8 < 8; ++r8) {
    const int id = tid + r8*256;
    const int r = id >> 5, c = id & 31;
    const int pk = stok[r];
    float4 xv = make_float4(0.f, 0.f, 0.f, 0.f);
    if (pk >= 0) xv = *(const float4*)(AO + (long)(pk & 0x3FFFFFFF)*128 + c*4);
    uint2 pkd;
    pkd.x = f2bf(xv.x) | (f2bf(xv.y) << 16);
    pkd.y = f2bf(xv.z) | (f2bf(xv.w) << 16);
    const int bc = (c*8) ^ ((r & 7) << 4);
    *(uint2*)((char*)Xs + r*256 + bc) = pkd;
  }

  const int w  = tid >> 6;
  const int l  = tid & 63;
  const int lq = l >> 4;
  const int lr = l & 15;

  f32x4 yacc[2][4];
#pragma unroll
  for (int a = 0; a < 2; ++a)
#pragma unroll
    for (int m = 0; m < 4; ++m) yacc[a][m] = (f32x4){0.f, 0.f, 0.f, 0.f};

  for (int fc = 0; fc < 4; ++fc) {
    __syncthreads();
    {
      const long wb = (long)(e*512 + fc*128) * 128;
#pragma unroll
      for (int s = 0; s < 8; ++s) {
        const int id = tid + s*256;
        const int fr = id >> 4, c16 = id & 15;
        const uint4 v = *(const uint4*)(w1b + wb + (long)fr*128 + c16*8);
        *(uint4*)((char*)Wts + fr*256 + ((c16*16) ^ ((fr & 7) << 4))) = v;
      }
    }
    __syncthreads();
    f32x4 hacc[2][4];
#pragma unroll
    for (int a = 0; a < 2; ++a)
#pragma unroll
      for (int m = 0; m < 4; ++m) hacc[a][m] = (f32x4){0.f, 0.f, 0.f, 0.f};
#pragma unroll
    for (int ks = 0; ks < 4; ++ks) {
      const int bcol = ks*64 + lq*16;
      const bf16x8 a0 = ld_frag(Wts, (2*w  )*16 + lr, bcol);
      const bf16x8 a1 = ld_frag(Wts, (2*w+1)*16 + lr, bcol);
      const bf16x8 b0 = ld_frag(Xs,  0*16 + lr, bcol);
      const bf16x8 b1 = ld_frag(Xs,  1*16 + lr, bcol);
      const bf16x8 b2 = ld_frag(Xs,  2*16 + lr, bcol);
      const bf16x8 b3 = ld_frag(Xs,  3*16 + lr, bcol);
      hacc[0][0] = __builtin_amdgcn_mfma_f32_16x16x32_bf16(a0, b0, hacc[0][0], 0, 0, 0);
      hacc[0][1] = __builtin_amdgcn_mfma_f32_16x16x32_bf16(a0, b1, hacc[0][1], 0, 0, 0);
      hacc[0][2] = __builtin_amdgcn_mfma_f32_16x16x32_bf16(a0, b2, hacc[0][2], 0, 0, 0);
      hacc[0][3] = __builtin_amdgcn_mfma_f32_16x16x32_bf16(a0, b3, hacc[0][3], 0, 0, 0);
      hacc[1][0] = __builtin_amdgcn_mfma_f32_16x16x32_bf16(a1, b0, hacc[1][0], 0, 0, 0);
      hacc[1][1] = __builtin_amdgcn_mfma_f32_16x16x32_bf16(a1, b1, hacc[1][1], 0, 0, 0);
      hacc[1][2] = __builtin_amdgcn_mfma_f32_16x16x32_bf16(a1, b2, hacc[1][2], 0, 0, 0);
      hacc[1][3] = __builtin_amdgcn_mfma_f32_16x16x32_bf16(a1, b3, hacc[1][3], 0, 0, 0);
    }
    __syncthreads();
#pragma unroll
    for (int fbi = 0; fbi < 2; ++fbi) {
      const int fb = (2*w + fbi)*16 + lq*4;
      const float4 bia = *(const float4*)&seb1[fc*128 + fb];
#pragma unroll
      for (int mb = 0; mb < 4; ++mb) {
        const int m = mb*16 + lr;
        const float h0 = fmaxf(hacc[fbi][mb][0] + bia.x, 0.f);
        const float h1 = fmaxf(hacc[fbi][mb][1] + bia.y, 0.f);
        const float h2 = fmaxf(hacc[fbi][mb][2] + bia.z, 0.f);
        const float h3 = fmaxf(hacc[fbi][mb][3] + bia.w, 0.f);
        uint2 p;
        p.x = f2bf(h0) | (f2bf(h1) << 16);
        p.y = f2bf(h2) | (f2bf(h3) << 16);
        const int bc = (fb*2) ^ ((m & 7) << 4);
        *(uint2*)((char*)Hs + m*256 + bc) = p;
      }
    }
    {
      const long wb = (long)(e*128) * 512 + fc*128;
#pragma unroll
      for (int s = 0; s < 8; ++s) {
        const int id = tid + s*256;
        const int orr = id >> 4, c16 = id & 15;
        const uint4 v = *(const uint4*)(w2b + wb + (long)orr*512 + c16*8);
        *(uint4*)((char*)Wts + orr*256 + ((c16*16) ^ ((orr & 7) << 4))) = v;
      }
    }
    __syncthreads();
#pragma unroll
    for (int ks = 0; ks < 4; ++ks) {
      const int bcol = ks*64 + lq*16;
      const bf16x8 a0 = ld_frag(Wts, (2*w  )*16 + lr, bcol);
      const bf16x8 a1 = ld_frag(Wts, (2*w+1)*16 + lr, bcol);
      const bf16x8 b0 = ld_frag(Hs,  0*16 + lr, bcol);
      const bf16x8 b1 = ld_frag(Hs,  1*16 + lr, bcol);
      const bf16x8 b2 = ld_frag(Hs,  2*16 + lr, bcol);
      const bf16x8 b3 = ld_frag(Hs,  3*16 + lr, bcol);
      yacc[0][0] = __builtin_amdgcn_mfma_f32_16x16x32_bf16(a0, b0, yacc[0][0], 0, 0, 0);
      yacc[0][1] = __builtin_amdgcn_mfma_f32_16x16x32_bf16(a0, b1, yacc[0][1], 0, 0, 0);
      yacc[0][2] = __builtin_amdgcn_mfma_f32_16x16x32_bf16(a0, b2, yacc[0][2], 0, 0, 0);
      yacc[0][3] = __builtin_amdgcn_mfma_f32_16x16x32_bf16(a0, b3, yacc[0][3], 0, 0, 0);
      yacc[1][0] = __builtin_amdgcn_mfma_f32_16x16x32_bf16(a1, b0, yacc[1][0], 0, 0, 0);
      yacc[1][1] = __builtin_amdgcn_mfma_f32_16x16x32_bf16(a1, b1, yacc[1][1], 0, 0, 0);
      yacc[1][2] = __builtin_amdgcn_mfma_f32_16x16x32_bf16(a1, b2, yacc[1][2], 0, 0, 0);
      yacc[1][3] = __builtin_amdgcn_mfma_f32_16x16x32_bf16(a1, b3, yacc[1][3], 0, 0, 0);
    }
  }
#pragma unroll
  for (int obi = 0; obi < 2; ++obi) {
    const int ob = (2*w + obi)*16 + lq*4;
    const float4 b2 = *(const float4*)&seb2[ob];
#pragma unroll
    for (int mb = 0; mb < 4; ++mb) {
      const int tl = mb*16 + lr;
      if (tl < nt) {
        const int pk = stok[tl];
        const int tk = pk & 0x3FFFFFFF;
        const float wgt = swgt[tl];
        float* Yp = ((pk >> 30) ? Y1 : Y0) + (long)tk*128 + ob;
        float4 o;
        o.x = (yacc[obi][mb][0] + b2.x) * wgt;
        o.y = (yacc[obi][mb][1] + b2.y) * wgt;
        o.z = (yacc[obi][mb][2] + b2.z) * wgt;
        o.w = (yacc[obi][mb][3] + b2.w) * wgt;
        *(float4*)Yp = o;
      }
    }
  }
}

// ---------------- fused sc GEMM + tanh + fixed-max softmax -----------------
__global__ __launch_bounds__(512)
void k_gemm2f(const unsigned short* __restrict__ mhb,
              const unsigned short* __restrict__ encb,
              const float* __restrict__ mask,
              float* __restrict__ out) {
  const int bid = blockIdx.x;
  const int b = bid & 31, rt = bid >> 5;
  __shared__ unsigned short Amh[64*128];
  __shared__ unsigned short Bch[512*32];
  __shared__ float red[64][9];
  const int tid = threadIdx.x;
  const int w = tid >> 6, l = tid & 63, lq = l >> 4, lr = l & 15;
  const long rowbase = (long)b*512 + rt*64;
#pragma unroll
  for (int s = 0; s < 2; ++s) {
    const int id = tid + s*512;
    const int r = id >> 4, c16 = id & 15;
    const uint4 v = *(const uint4*)(mhb + (rowbase + r)*128 + c16*8);
    *(uint4*)((char*)Amh + r*256 + ((c16*16) ^ ((r & 7) << 4))) = v;
  }
  f32x4 acc[4][4];
#pragma unroll
  for (int mi = 0; mi < 4; ++mi)
#pragma unroll
    for (int ni = 0; ni < 4; ++ni) acc[mi][ni] = (f32x4){0.f, 0.f, 0.f, 0.f};
  for (int kc = 0; kc < 4; ++kc) {
    __syncthreads();
#pragma unroll
    for (int s = 0; s < 4; ++s) {
      const int id = tid + s*512;
      const int n = id >> 2, sl = id & 3;
      const uint4 v = *(const uint4*)(encb + ((long)b*512 + n)*128 + kc*32 + sl*8);
      *(uint4*)((char*)Bch + n*64 + ((sl*16) ^ ((n & 3) << 4))) = v;
    }
    __syncthreads();
    bf16x8 af[4], bfr[4];
#pragma unroll
    for (int mi = 0; mi < 4; ++mi) {
      const int r = mi*16 + lr;
      af[mi] = *(const bf16x8*)((const char*)Amh + r*256 + ((kc*64 + lq*16) ^ ((r & 7) << 4)));
    }
#pragma unroll
    for (int ni = 0; ni < 4; ++ni) {
      const int n = w*64 + ni*16 + lr;
      bfr[ni] = *(const bf16x8*)((const char*)Bch + n*64 + ((lq*16) ^ ((n & 3) << 4)));
    }
#pragma unroll
    for (int mi = 0; mi < 4; ++mi)
#pragma unroll
      for (int ni = 0; ni < 4; ++ni)
        acc[mi][ni] = __builtin_amdgcn_mfma_f32_16x16x32_bf16(af[mi], bfr[ni], acc[mi][ni], 0, 0, 0);
  }
  const float ISC = 1.f/11.313708498984761f;
  float rsum[4][4];
#pragma unroll
  for (int mi = 0; mi < 4; ++mi)
#pragma unroll
    for (int j = 0; j < 4; ++j) rsum[mi][j] = 0.f;
#pragma unroll
  for (int mi = 0; mi < 4; ++mi) {
#pragma unroll
    for (int j = 0; j < 4; ++j) {
      const long row = rowbase + mi*16 + lq*4 + j;
      const float* mrow = mask + row*512 + w*64 + lr;
#pragma unroll
      for (int ni = 0; ni < 4; ++ni) {
        const float sc = acc[mi][ni][j] * ISC;
        const float li = 10.f*tanhf(sc) + mrow[ni*16];
        const float e = __expf(li - 10.f);
        acc[mi][ni][j] = e;
        rsum[mi][j] += e;
      }
    }
  }
#pragma unroll
  for (int mi = 0; mi < 4; ++mi)
#pragma unroll
    for (int j = 0; j < 4; ++j) {
#pragma unroll
      for (int o = 1; o < 16; o <<= 1) rsum[mi][j] += __shfl_xor(rsum[mi][j], o);
    }
  if (lr == 0) {
#pragma unroll
    for (int mi = 0; mi < 4; ++mi)
#pragma unroll
      for (int j = 0; j < 4; ++j) red[mi*16 + lq*4 + j][w] = rsum[mi][j];
  }
  __syncthreads();
  if (tid < 64) {
    float s = 0.f;
#pragma unroll
    for (int wv = 0; wv < 8; ++wv) s += red[tid][wv];
    red[tid][8] = 1.f / s;
  }
  __syncthreads();
#pragma unroll
  for (int mi = 0; mi < 4; ++mi) {
#pragma unroll
    for (int j = 0; j < 4; ++j) {
      const int rl = mi*16 + lq*4 + j;
      const float inv = red[rl][8];
      float* orow = out + (rowbase + rl)*512 + w*64 + lr;
#pragma unroll
      for (int ni = 0; ni < 4; ++ni) orow[ni*16] = acc[mi][ni][j] * inv;
    }
  }
}

// ---------------------------------------------------------------------------
extern "C" void kernel_launch(void* const* d_in, const int* in_sizes, int n_in,
                              void* d_out, int out_size, void* d_ws, size_t ws_size,
                              hipStream_t stream) {
  (void)in_sizes; (void)n_in; (void)out_size; (void)ws_size;
  const float* pref  = (const float*)d_in[0];
  const float* graph = (const float*)d_in[1];
  const float* cap   = (const float*)d_in[2];
  const float* enc   = (const float*)d_in[3];
  const float* mask  = (const float*)d_in[4];
  const float* fc1w  = (const float*)d_in[5];
  const float* fc1b  = (const float*)d_in[6];
  const float* fc2w  = (const float*)d_in[7];
  const float* fc2b  = (const float*)d_in[8];
  const float* fc3w  = (const float*)d_in[9];
  const float* fc3b  = (const float*)d_in[10];
  const float* hWq   = (const float*)d_in[11];
  const float* hWk   = (const float*)d_in[12];
  const float* hWv   = (const float*)d_in[13];
  const float* hWc   = (const float*)d_in[14];
  const float* gw    = (const float*)d_in[15];
  const float* gpw   = (const float*)d_in[16];
  const float* ew1   = (const float*)d_in[17];
  const float* eb1   = (const float*)d_in[18];
  const float* ew2   = (const float*)d_in[19];
  const float* eb2   = (const float*)d_in[20];
  float* ws  = (float*)d_ws;
  float* out = (float*)d_out;
  // d_out scratch: Kb/Vb bf16 [0,8MB) dead after attn; Y0 [0,8MB), Y1 [8,16MB);
  // ew1b [16,17MB), ew2b [17,18MB). k_gemm2f overwrites all of d_out.
  unsigned short* Kbuf = (unsigned short*)out;
  unsigned short* Vbuf = (unsigned short*)(out + 1048576);
  float* Y0 = out;
  float* Y1 = out + 2097152;
  unsigned short* ew1b = (unsigned short*)(out + 4194304);
  unsigned short* ew2b = (unsigned short*)(out + 4456448);
  unsigned short* mhb  = (unsigned short*)(ws + OFF_MH);
  unsigned short* encb = (unsigned short*)(ws + OFF_ENCB);
  unsigned short* wkb  = (unsigned short*)(ws + OFF_WKB);
  unsigned short* wvb  = (unsigned short*)(ws + OFF_WVB);
  unsigned short* wcb  = (unsigned short*)(ws + OFF_WCB);

  k_prep1<<<5121, 256, 0, stream>>>(pref, fc1w, fc1b, fc2w, fc2b, fc3w, fc3b,
                                    gpw, hWq, mask, ew1, ew2, enc,
                                    ew1b, ew2b, encb, ws);
  k_prep2<<<208, 256, 0, stream>>>(graph, hWq, hWk, hWv, hWc, ws);
  k_kv<<<dim3(256, 2), 256, 0, stream>>>(encb, wkb, wvb, Kbuf, Vbuf);
  k_attn<<<1024, 512, 0, stream>>>(Kbuf, Vbuf, ws, cap, mask, ws + OFF_AO);
  k_gate<<<64, 256, 0, stream>>>(ws + OFF_AO, gw, ws);
  k_moe<<<dim3(256, 8), 256, 0, stream>>>(ws + OFF_AO, ew1b, ew2b, eb1, eb2, ws, Y0, Y1);
  k_mh<<<256, 256, 0, stream>>>(Y0, Y1, wcb, mhb);
  k_gemm2f<<<256, 512, 0, stream>>>(mhb, encb, mask, out);
}

// Round 10
// 118.517 us; speedup vs baseline: 7.6576x; 1.0286x over previous
//
#include <hip/hip_runtime.h>

// ---------------------------------------------------------------------------
// KP_Decoder: hypernet -> (k,v,q) -> attention -> top2 MoE -> combine softmax
// B=32 G=512 N=512 EMB=128 H=8 DK=16 E=8 FH=512 K=2
// R3-R9: bf16 MFMA everywhere; fused tanh-softmax; q-split attn; mask-flag
//        skip; split prep.
// R10: k_attn FIXED-MAX softmax (scores bounded ~0.01, mask <= 0): removes
//      max-tree + shfls + rescale + the loop-carried dependency entirely.
// ---------------------------------------------------------------------------

typedef __attribute__((ext_vector_type(8))) __bf16 bf16x8;
typedef __attribute__((ext_vector_type(4))) float f32x4;

// ws layout (float offsets)
static constexpr long OFF_MID   = 0;        // 8
static constexpr long OFF_PREFL = 8;        // 8
static constexpr long OFF_WL    = 16;       // 128 (Wq[:,128] capacity col)
static constexpr long OFF_WKB   = 256;      // 128x128 bf16
static constexpr long OFF_WVB   = 8448;     // 128x128 bf16
static constexpr long OFF_WCB   = 16640;    // 128x128 bf16
static constexpr long OFF_QB    = 24832;    // 32x128 qbase fp32
static constexpr long OFF_MFLAG = 28928;    // 16384 bytes (4096 floats)
static constexpr long OFF_CNT   = 33024;    // 8 ints
static constexpr long OFF_TOK   = 33032;    // 8*16384 ints
static constexpr long OFF_WGT   = 164104;   // 8*16384 floats
static constexpr long OFF_AO    = 295176;   // 16384x128 fp32 attention out
static constexpr long OFF_MH    = 2392328;  // 16384x128 bf16 mh
static constexpr long OFF_ENCB  = 3440904;  // 16384x128 bf16 enc
// total 4,489,480 floats = 17.96 MB

__device__ __forceinline__ unsigned f2bf(float x) {
  union { float f; unsigned u; } v; v.f = x;
  return ((v.u + 0x7FFFu + ((v.u >> 16) & 1u)) >> 16) & 0xFFFFu;
}

// ---------------- k_prep1: hypernet (1 block) + cvt + mask flags -----------
__global__ __launch_bounds__(256)
void k_prep1(const float* __restrict__ pref, const float* __restrict__ fc1w,
             const float* __restrict__ fc1b, const float* __restrict__ fc2w,
             const float* __restrict__ fc2b, const float* __restrict__ fc3w,
             const float* __restrict__ fc3b, const float* __restrict__ gpw,
             const float* __restrict__ hWq, const float* __restrict__ mask,
             const float* __restrict__ ew1, const float* __restrict__ ew2,
             const float* __restrict__ enc,
             unsigned short* __restrict__ w1b, unsigned short* __restrict__ w2b,
             unsigned short* __restrict__ encb, float* __restrict__ ws) {
  const int bid = blockIdx.x;
  const int tid = threadIdx.x;
  if (bid == 0) {
    __shared__ float h1[256];
    __shared__ float h2[256];
    __shared__ float mid[8];
    const float p0 = pref[0], p1 = pref[1];
    h1[tid] = fc1w[2*tid]*p0 + fc1w[2*tid+1]*p1 + fc1b[tid];
    __syncthreads();
    float s = 0.f;
    for (int j = 0; j < 256; ++j) s = fmaf(fc2w[tid*256+j], h1[j], s);
    h2[tid] = s + fc2b[tid];
    __syncthreads();
    if (tid < 8) {
      float s2 = 0.f;
      for (int j = 0; j < 256; ++j) s2 = fmaf(fc3w[tid*256+j], h2[j], s2);
      mid[tid] = s2 + fc3b[tid];
    }
    __syncthreads();
    if (tid < 8) {
      ws[OFF_MID + tid] = mid[tid];
      float s3 = 0.f;
      for (int i = 0; i < 8; ++i) s3 = fmaf(mid[i], gpw[i*8 + tid], s3);
      ws[OFF_PREFL + tid] = s3;
      ((int*)(ws + OFF_CNT))[tid] = 0;
    }
    if (tid >= 16 && tid < 144) {
      const int o = tid - 16;
      ws[OFF_WL + o] = hWq[((long)o*129 + 128)*2]*mid[0]
                     + hWq[((long)o*129 + 128)*2 + 1]*mid[1];
    }
    return;
  }
  if (bid <= 3072) {
    const int i = (bid-1)*256 + tid;
    const float* src;
    unsigned short* dst;
    if (i < 131072)      { src = ew1 + (long)i*4;          dst = w1b + (long)i*4; }
    else if (i < 262144) { src = ew2 + (long)(i-131072)*4; dst = w2b + (long)(i-131072)*4; }
    else                 { src = enc + (long)(i-262144)*4; dst = encb + (long)(i-262144)*4; }
    const float4 v = *(const float4*)src;
    uint2 p;
    p.x = f2bf(v.x) | (f2bf(v.y) << 16);
    p.y = f2bf(v.z) | (f2bf(v.w) << 16);
    *(uint2*)dst = p;
    return;
  }
  // mask flags: 8 rows per block
  __shared__ int fl[8];
  const int rowbase = (bid - 3073) * 8;
  const int r = tid >> 5, seg = tid & 31;
  if (tid < 8) fl[tid] = 0;
  __syncthreads();
  const float* mrow = mask + (long)(rowbase + r)*512 + seg*16;
  int nz = 0;
#pragma unroll
  for (int c = 0; c < 4; ++c) {
    const float4 v = *(const float4*)(mrow + c*4);
    nz |= (v.x != 0.f) | (v.y != 0.f) | (v.z != 0.f) | (v.w != 0.f);
  }
  if (nz) atomicOr(&fl[r], 1);
  __syncthreads();
  if (tid < 8) ((char*)(ws + OFF_MFLAG))[rowbase + tid] = (char)fl[tid];
}

// ---------------- k_prep2: Wk/Wv/Wc heads + qbase (reads mid from ws) ------
__global__ __launch_bounds__(256)
void k_prep2(const float* __restrict__ graph,
             const float* __restrict__ hWq, const float* __restrict__ hWk,
             const float* __restrict__ hWv, const float* __restrict__ hWc,
             float* __restrict__ ws) {
  const int bid = blockIdx.x;
  const int tid = threadIdx.x;
  __shared__ float mid[8];
  __shared__ float g[2][128];
  if (tid < 8) mid[tid] = ws[OFF_MID + tid];
  __syncthreads();
  if (bid < 192) {
    const int i = bid*256 + tid;   // 0..49151
    if (i < 16384) {
      ((unsigned short*)(ws + OFF_WKB))[i] =
          (unsigned short)f2bf(hWk[2*i]*mid[2] + hWk[2*i+1]*mid[3]);
    } else if (i < 32768) {
      const int j = i - 16384;
      ((unsigned short*)(ws + OFF_WVB))[j] =
          (unsigned short)f2bf(hWv[2*j]*mid[4] + hWv[2*j+1]*mid[5]);
    } else {
      const int j = i - 32768;
      ((unsigned short*)(ws + OFF_WCB))[j] =
          (unsigned short)f2bf(hWc[2*j]*mid[6] + hWc[2*j+1]*mid[7]);
    }
    return;
  }
  const int qb = bid - 192;
  const int b0 = qb*2;
  {
    const int bb = tid >> 7, ii = tid & 127;
    g[bb][ii] = graph[(b0+bb)*128 + ii];
  }
  __syncthreads();
  const float m0 = mid[0], m1 = mid[1];
  const int bb = tid >> 7, o = tid & 127;
  const float* hq = hWq + (long)o*129*2;
  float acc = 0.f;
  for (int i2 = 0; i2 < 128; ++i2) {
    const float w = hq[2*i2]*m0 + hq[2*i2+1]*m1;
    acc = fmaf(g[bb][i2], w, acc);
  }
  ws[OFF_QB + (b0+bb)*128 + o] = acc;
}

// ---------------- shared swizzled-LDS fragment loader (256B rows) ----------
__device__ __forceinline__ bf16x8 ld_frag(const unsigned short* base, int row, int bytecol) {
  const int addr = row*256 + (bytecol ^ ((row & 7) << 4));
  return *(const bf16x8*)((const char*)base + addr);
}

// ---------------- k_kv: bf16 MFMA GEMM, {K,V}[n][o] = enc . W^T ------------
__global__ __launch_bounds__(256)
void k_kv(const unsigned short* __restrict__ encb,
          const unsigned short* __restrict__ wkb,
          const unsigned short* __restrict__ wvb,
          unsigned short* __restrict__ Kb, unsigned short* __restrict__ Vb) {
  __shared__ unsigned short Ws[128*128];
  __shared__ unsigned short Xs[64*128];
  const int tid = threadIdx.x;
  const int nbase = blockIdx.x * 64;
  const unsigned short* Wb = blockIdx.y ? wvb : wkb;
  unsigned short* Cb = blockIdx.y ? Vb : Kb;
#pragma unroll
  for (int s = 0; s < 8; ++s) {
    const int id = tid + s*256;
    const int fr = id >> 4, c16 = id & 15;
    const uint4 v = *(const uint4*)(Wb + (long)fr*128 + c16*8);
    *(uint4*)((char*)Ws + fr*256 + ((c16*16) ^ ((fr & 7) << 4))) = v;
  }
#pragma unroll
  for (int s = 0; s < 4; ++s) {
    const int id = tid + s*256;
    const int r = id >> 4, c16 = id & 15;
    const uint4 v = *(const uint4*)(encb + (long)(nbase + r)*128 + c16*8);
    *(uint4*)((char*)Xs + r*256 + ((c16*16) ^ ((r & 7) << 4))) = v;
  }
  __syncthreads();
  const int w = tid >> 6, l = tid & 63, lq = l >> 4, lr = l & 15;
  f32x4 acc[2][4];
#pragma unroll
  for (int a = 0; a < 2; ++a)
#pragma unroll
    for (int m = 0; m < 4; ++m) acc[a][m] = (f32x4){0.f, 0.f, 0.f, 0.f};
#pragma unroll
  for (int ks = 0; ks < 4; ++ks) {
    const int bcol = ks*64 + lq*16;
    const bf16x8 a0 = ld_frag(Ws, (2*w  )*16 + lr, bcol);
    const bf16x8 a1 = ld_frag(Ws, (2*w+1)*16 + lr, bcol);
    const bf16x8 b0 = ld_frag(Xs, 0*16 + lr, bcol);
    const bf16x8 b1 = ld_frag(Xs, 1*16 + lr, bcol);
    const bf16x8 b2 = ld_frag(Xs, 2*16 + lr, bcol);
    const bf16x8 b3 = ld_frag(Xs, 3*16 + lr, bcol);
    acc[0][0] = __builtin_amdgcn_mfma_f32_16x16x32_bf16(a0, b0, acc[0][0], 0, 0, 0);
    acc[0][1] = __builtin_amdgcn_mfma_f32_16x16x32_bf16(a0, b1, acc[0][1], 0, 0, 0);
    acc[0][2] = __builtin_amdgcn_mfma_f32_16x16x32_bf16(a0, b2, acc[0][2], 0, 0, 0);
    acc[0][3] = __builtin_amdgcn_mfma_f32_16x16x32_bf16(a0, b3, acc[0][3], 0, 0, 0);
    acc[1][0] = __builtin_amdgcn_mfma_f32_16x16x32_bf16(a1, b0, acc[1][0], 0, 0, 0);
    acc[1][1] = __builtin_amdgcn_mfma_f32_16x16x32_bf16(a1, b1, acc[1][1], 0, 0, 0);
    acc[1][2] = __builtin_amdgcn_mfma_f32_16x16x32_bf16(a1, b2, acc[1][2], 0, 0, 0);
    acc[1][3] = __builtin_amdgcn_mfma_f32_16x16x32_bf16(a1, b3, acc[1][3], 0, 0, 0);
  }
#pragma unroll
  for (int obi = 0; obi < 2; ++obi) {
    const int o0 = (2*w + obi)*16 + lq*4;
#pragma unroll
    for (int mb = 0; mb < 4; ++mb) {
      const long n = nbase + mb*16 + lr;
      uint2 pp;
      pp.x = f2bf(acc[obi][mb][0]) | (f2bf(acc[obi][mb][1]) << 16);
      pp.y = f2bf(acc[obi][mb][2]) | (f2bf(acc[obi][mb][3]) << 16);
      *(uint2*)(Cb + n*128 + o0) = pp;
    }
  }
}

// ---------------- k_mh: bf16 MFMA GEMM, mh[n][o] = (Y0+Y1) . Wc^T ----------
__global__ __launch_bounds__(256)
void k_mh(const float* __restrict__ Y0, const float* __restrict__ Y1,
          const unsigned short* __restrict__ wcb,
          unsigned short* __restrict__ mhb) {
  __shared__ unsigned short Ws[128*128];
  __shared__ unsigned short Xs[64*128];
  const int tid = threadIdx.x;
  const int nbase = blockIdx.x * 64;
#pragma unroll
  for (int s = 0; s < 8; ++s) {
    const int id = tid + s*256;
    const int fr = id >> 4, c16 = id & 15;
    const uint4 v = *(const uint4*)(wcb + (long)fr*128 + c16*8);
    *(uint4*)((char*)Ws + fr*256 + ((c16*16) ^ ((fr & 7) << 4))) = v;
  }
#pragma unroll
  for (int s = 0; s < 4; ++s) {
    const int id = tid + s*256;
    const int r = id >> 4, c16 = id & 15;
    const long base = (long)(nbase + r)*128 + c16*8;
    const float4 a0 = *(const float4*)(Y0 + base);
    const float4 a1 = *(const float4*)(Y0 + base + 4);
    const float4 b0 = *(const float4*)(Y1 + base);
    const float4 b1 = *(const float4*)(Y1 + base + 4);
    uint4 p;
    p.x = f2bf(a0.x + b0.x) | (f2bf(a0.y + b0.y) << 16);
    p.y = f2bf(a0.z + b0.z) | (f2bf(a0.w + b0.w) << 16);
    p.z = f2bf(a1.x + b1.x) | (f2bf(a1.y + b1.y) << 16);
    p.w = f2bf(a1.z + b1.z) | (f2bf(a1.w + b1.w) << 16);
    *(uint4*)((char*)Xs + r*256 + ((c16*16) ^ ((r & 7) << 4))) = p;
  }
  __syncthreads();
  const int w = tid >> 6, l = tid & 63, lq = l >> 4, lr = l & 15;
  f32x4 acc[2][4];
#pragma unroll
  for (int a = 0; a < 2; ++a)
#pragma unroll
    for (int m = 0; m < 4; ++m) acc[a][m] = (f32x4){0.f, 0.f, 0.f, 0.f};
#pragma unroll
  for (int ks = 0; ks < 4; ++ks) {
    const int bcol = ks*64 + lq*16;
    const bf16x8 a0 = ld_frag(Ws, (2*w  )*16 + lr, bcol);
    const bf16x8 a1 = ld_frag(Ws, (2*w+1)*16 + lr, bcol);
    const bf16x8 b0 = ld_frag(Xs, 0*16 + lr, bcol);
    const bf16x8 b1 = ld_frag(Xs, 1*16 + lr, bcol);
    const bf16x8 b2 = ld_frag(Xs, 2*16 + lr, bcol);
    const bf16x8 b3 = ld_frag(Xs, 3*16 + lr, bcol);
    acc[0][0] = __builtin_amdgcn_mfma_f32_16x16x32_bf16(a0, b0, acc[0][0], 0, 0, 0);
    acc[0][1] = __builtin_amdgcn_mfma_f32_16x16x32_bf16(a0, b1, acc[0][1], 0, 0, 0);
    acc[0][2] = __builtin_amdgcn_mfma_f32_16x16x32_bf16(a0, b2, acc[0][2], 0, 0, 0);
    acc[0][3] = __builtin_amdgcn_mfma_f32_16x16x32_bf16(a0, b3, acc[0][3], 0, 0, 0);
    acc[1][0] = __builtin_amdgcn_mfma_f32_16x16x32_bf16(a1, b0, acc[1][0], 0, 0, 0);
    acc[1][1] = __builtin_amdgcn_mfma_f32_16x16x32_bf16(a1, b1, acc[1][1], 0, 0, 0);
    acc[1][2] = __builtin_amdgcn_mfma_f32_16x16x32_bf16(a1, b2, acc[1][2], 0, 0, 0);
    acc[1][3] = __builtin_amdgcn_mfma_f32_16x16x32_bf16(a1, b3, acc[1][3], 0, 0, 0);
  }
#pragma unroll
  for (int obi = 0; obi < 2; ++obi) {
    const int o0 = (2*w + obi)*16 + lq*4;
#pragma unroll
    for (int mb = 0; mb < 4; ++mb) {
      const long n = nbase + mb*16 + lr;
      uint2 pp;
      pp.x = f2bf(acc[obi][mb][0]) | (f2bf(acc[obi][mb][1]) << 16);
      pp.y = f2bf(acc[obi][mb][2]) | (f2bf(acc[obi][mb][3]) << 16);
      *(uint2*)(mhb + n*128 + o0) = pp;
    }
  }
}

// ---------------- MFMA flash attention v5: FIXED-MAX softmax ---------------
// grid 1024: b = bid&31, h = (bid>>5)&7, qh = bid>>8; 512 thr, 8 waves.
// Scores bounded (~1e-2) and mask <= 0 => p = exp(s+mask) directly, no
// running max, no rescale, no cross-lane reduce in the loop. Iterations
// independent except MFMA-accumulated oacc and associative lsum.
__global__ __launch_bounds__(512, 8)
void k_attn(const unsigned short* __restrict__ Kb,
            const unsigned short* __restrict__ Vb,
            const float* __restrict__ ws, const float* __restrict__ cap,
            const float* __restrict__ mask, float* __restrict__ AO) {
  const int bid = blockIdx.x;
  const int b = bid & 31, h = (bid >> 5) & 7, qh = bid >> 8;
  __shared__ unsigned short Kbf[512*24];  // 24 KB
  __shared__ unsigned short Vt[16*536];   // 16.75 KB
  __shared__ unsigned short Ps[8*16*40];  // 10 KB
  const int tid = threadIdx.x;
#pragma unroll
  for (int it = 0; it < 2; ++it) {
    const int i = tid + it*512;           // 0..1023
    const int n = i >> 1, hf = i & 1;
    const long src = (long)(b*512 + n)*128 + h*16 + hf*8;
    const uint4 kv = *(const uint4*)(Kb + src);
    *(uint4*)(Kbf + n*24 + hf*8) = kv;
    const uint4 vv = *(const uint4*)(Vb + src);
    const unsigned short* sp = (const unsigned short*)&vv;
#pragma unroll
    for (int j = 0; j < 8; ++j) Vt[(hf*8 + j)*536 + n] = sp[j];
  }
  const int w = tid >> 6, l = tid & 63;
  const int lq = l >> 4, lr = l & 15;
  const int grow = qh*128 + w*16 + lr;    // this lane's q-row
  bf16x8 qf;
  {
    union { uint4 u; bf16x8 v; } cv;
    cv.u = make_uint4(0u, 0u, 0u, 0u);
    if (lq < 2) {
      const float* qbp = ws + OFF_QB + b*128 + h*16 + lq*8;
      const float* wlp = ws + OFF_WL + h*16 + lq*8;
      const float cp = cap[b*512 + grow];
      float qv[8];
#pragma unroll
      for (int j = 0; j < 8; ++j) qv[j] = (qbp[j] + cp*wlp[j]) * 0.25f;
      cv.u.x = f2bf(qv[0]) | (f2bf(qv[1]) << 16);
      cv.u.y = f2bf(qv[2]) | (f2bf(qv[3]) << 16);
      cv.u.z = f2bf(qv[4]) | (f2bf(qv[5]) << 16);
      cv.u.w = f2bf(qv[6]) | (f2bf(qv[7]) << 16);
    }
    qf = cv.v;
  }
  const int mf = ((const char*)(ws + OFF_MFLAG))[b*512 + grow];
  const bool usemask = __any(mf != 0);
  unsigned short* Pw = Ps + w*16*40;
  const int psw = (lr & 3) << 3;
  __syncthreads();
  float lsum = 0.f;
  f32x4 oacc = {0.f, 0.f, 0.f, 0.f};
  const float* mrow = mask + ((long)(b*512 + grow))*512 + lq*4;
  for (int qc = 0; qc < 16; ++qc) {       // 16 chunks of 32 n, independent
    const int n0 = qc*32;
    f32x4 s[2];
#pragma unroll
    for (int nb = 0; nb < 2; ++nb) {
      bf16x8 kf;
      {
        union { uint4 u; bf16x8 v; } cv;
        cv.u = make_uint4(0u, 0u, 0u, 0u);
        if (lq < 2) cv.u = *(const uint4*)(Kbf + (n0 + nb*16 + lr)*24 + lq*8);
        kf = cv.v;
      }
      s[nb] = __builtin_amdgcn_mfma_f32_16x16x32_bf16(
          kf, qf, (f32x4){0.f, 0.f, 0.f, 0.f}, 0, 0, 0);
      if (usemask) {
        const float4 mk = *(const float4*)(mrow + n0 + nb*16);
        s[nb][0] += mk.x; s[nb][1] += mk.y; s[nb][2] += mk.z; s[nb][3] += mk.w;
      }
    }
    // fixed-max: p = exp(s) directly (s bounded, mask <= 0 underflows to 0)
#pragma unroll
    for (int nb = 0; nb < 2; ++nb) {
      const float e0 = __expf(s[nb][0]);
      const float e1 = __expf(s[nb][1]);
      const float e2 = __expf(s[nb][2]);
      const float e3 = __expf(s[nb][3]);
      lsum += (e0 + e1) + (e2 + e3);
      uint2 pp;
      asm("v_cvt_pk_bf16_f32 %0, %1, %2" : "=v"(pp.x) : "v"(e0), "v"(e1));
      asm("v_cvt_pk_bf16_f32 %0, %1, %2" : "=v"(pp.y) : "v"(e2), "v"(e3));
      *(uint2*)(Pw + lr*40 + ((nb*16 + lq*4) ^ psw)) = pp;
    }
    const bf16x8 va = *(const bf16x8*)(Vt + lr*536 + n0 + lq*8);
    const bf16x8 pb = *(const bf16x8*)(Pw + lr*40 + (lq*8 ^ psw));
    oacc = __builtin_amdgcn_mfma_f32_16x16x32_bf16(va, pb, oacc, 0, 0, 0);
  }
  lsum += __shfl_xor(lsum, 16);
  lsum += __shfl_xor(lsum, 32);
  const float inv = 1.f / lsum;
  float4 o;
  o.x = oacc[0]*inv; o.y = oacc[1]*inv; o.z = oacc[2]*inv; o.w = oacc[3]*inv;
  *(float4*)(AO + (long)(b*512 + grow)*128 + h*16 + lq*4) = o;
}

// ---------------- gating: top-2 + expert lists (block-aggregated) ----------
__global__ __launch_bounds__(256)
void k_gate(const float* __restrict__ AO, const float* __restrict__ gw,
            float* __restrict__ ws) {
  const int tid = threadIdx.x;
  const int t = blockIdx.x*256 + tid;
  const float* x = AO + (long)t*128;
  float lg[8];
  {
    const float* pl = ws + OFF_PREFL;
#pragma unroll
    for (int e = 0; e < 8; ++e) lg[e] = pl[e];
  }
  for (int i = 0; i < 128; i += 4) {
    const float4 xv = *(const float4*)(x + i);
#pragma unroll
    for (int u = 0; u < 4; ++u) {
      const float xi = (&xv.x)[u];
      const float4 ga = *(const float4*)(gw + (i+u)*8);
      const float4 gb = *(const float4*)(gw + (i+u)*8 + 4);
      lg[0] = fmaf(xi, ga.x, lg[0]); lg[1] = fmaf(xi, ga.y, lg[1]);
      lg[2] = fmaf(xi, ga.z, lg[2]); lg[3] = fmaf(xi, ga.w, lg[3]);
      lg[4] = fmaf(xi, gb.x, lg[4]); lg[5] = fmaf(xi, gb.y, lg[5]);
      lg[6] = fmaf(xi, gb.z, lg[6]); lg[7] = fmaf(xi, gb.w, lg[7]);
    }
  }
  int i0 = 0; float v0 = lg[0];
#pragma unroll
  for (int e = 1; e < 8; ++e) if (lg[e] > v0) { v0 = lg[e]; i0 = e; }
  int i1 = -1; float v1 = -1e30f;
#pragma unroll
  for (int e = 0; e < 8; ++e) if (e != i0 && lg[e] > v1) { v1 = lg[e]; i1 = e; }
  const float e1 = __expf(v1 - v0);
  const float w0 = 1.f / (1.f + e1);
  const float w1 = 1.f - w0;
  __shared__ int bcnt[8];
  __shared__ int gbase[8];
  if (tid < 8) bcnt[tid] = 0;
  __syncthreads();
  const int p0 = atomicAdd(&bcnt[i0], 1);
  const int p1 = atomicAdd(&bcnt[i1], 1);
  __syncthreads();
  if (tid < 8) {
    int* cnt = (int*)(ws + OFF_CNT);
    gbase[tid] = (bcnt[tid] > 0) ? atomicAdd(&cnt[tid], bcnt[tid]) : 0;
  }
  __syncthreads();
  int* tokp = (int*)(ws + OFF_TOK);
  float* wgtp = ws + OFF_WGT;
  const int s0 = gbase[i0] + p0;
  tokp[i0*16384 + s0] = t;             // rank 0
  wgtp[i0*16384 + s0] = w0;
  const int s1 = gbase[i1] + p1;
  tokp[i1*16384 + s1] = t | (1 << 30); // rank 1
  wgtp[i1*16384 + s1] = w1;
}

// ---------------- MoE experts: bf16 MFMA, per (expert, 64-token chunk) -----
__global__ __launch_bounds__(256)
void k_moe(const float* __restrict__ AO,
           const unsigned short* __restrict__ w1b,
           const unsigned short* __restrict__ w2b,
           const float* __restrict__ eb1, const float* __restrict__ eb2,
           float* __restrict__ ws,
           float* __restrict__ Y0, float* __restrict__ Y1) {
  const int e = blockIdx.y;
  const int ce = ((const int*)(ws + OFF_CNT))[e];
  const int base = blockIdx.x * 64;
  if (base >= ce) return;
  const int nt = min(64, ce - base);

  __shared__ unsigned short Xs[64*128];
  __shared__ unsigned short Wts[128*128];
  __shared__ unsigned short Hs[64*128];
  __shared__ float seb1[512];
  __shared__ float seb2[128];
  __shared__ int   stok[64];
  __shared__ float swgt[64];

  const int tid = threadIdx.x;
  if (tid < 64) {
    if (tid < nt) {
      stok[tid] = ((const int*)(ws + OFF_TOK))[e*16384 + base + tid];
      swgt[tid] = (ws + OFF_WGT)[e*16384 + base + tid];
    } else { stok[tid] = -1; swgt[tid] = 0.f; }
  }
  for (int i = tid; i < 512; i += 256) seb1[i] = eb1[e*512 + i];
  if (tid < 128) seb2[tid] = eb2[e*128 + tid];
  __syncthreads();

#pragma unroll
  for (int r8 = 0; r8 < 8; ++r8) {
    const int id = tid + r8*256;
    const int r = id >> 5, c = id & 31;
    const int pk = stok[r];
    float4 xv = make_float4(0.f, 0.f, 0.f, 0.f);
    if (pk >= 0) xv = *(const float4*)(AO + (long)(pk & 0x3FFFFFFF)*128 + c*4);
    uint2 pkd;
    pkd.x = f2bf(xv.x) | (f2bf(xv.y) << 16);
    pkd.y = f2bf(xv.z) | (f2bf(xv.w) << 16);
    const int bc = (c*8) ^ ((r & 7) << 4);
    *(uint2*)((char*)Xs + r*256 + bc) = pkd;
  }

  const int w  = tid >> 6;
  const int l  = tid & 63;
  const int lq = l >> 4;
  const int lr = l & 15;

  f32x4 yacc[2][4];
#pragma unroll
  for (int a = 0; a < 2; ++a)
#pragma unroll
    for (int m = 0; m < 4; ++m) yacc[a][m] = (f32x4){0.f, 0.f, 0.f, 0.f};

  for (int fc = 0; fc < 4; ++fc) {
    __syncthreads();
    {
      const long wb = (long)(e*512 + fc*128) * 128;
#pragma unroll
      for (int s = 0; s < 8; ++s) {
        const int id = tid + s*256;
        const int fr = id >> 4, c16 = id & 15;
        const uint4 v = *(const uint4*)(w1b + wb + (long)fr*128 + c16*8);
        *(uint4*)((char*)Wts + fr*256 + ((c16*16) ^ ((fr & 7) << 4))) = v;
      }
    }
    __syncthreads();
    f32x4 hacc[2][4];
#pragma unroll
    for (int a = 0; a < 2; ++a)
#pragma unroll
      for (int m = 0; m < 4; ++m) hacc[a][m] = (f32x4){0.f, 0.f, 0.f, 0.f};
#pragma unroll
    for (int ks = 0; ks < 4; ++ks) {
      const int bcol = ks*64 + lq*16;
      const bf16x8 a0 = ld_frag(Wts, (2*w  )*16 + lr, bcol);
      const bf16x8 a1 = ld_frag(Wts, (2*w+1)*16 + lr, bcol);
      const bf16x8 b0 = ld_frag(Xs,  0*16 + lr, bcol);
      const bf16x8 b1 = ld_frag(Xs,  1*16 + lr, bcol);
      const bf16x8 b2 = ld_frag(Xs,  2*16 + lr, bcol);
      const bf16x8 b3 = ld_frag(Xs,  3*16 + lr, bcol);
      hacc[0][0] = __builtin_amdgcn_mfma_f32_16x16x32_bf16(a0, b0, hacc[0][0], 0, 0, 0);
      hacc[0][1] = __builtin_amdgcn_mfma_f32_16x16x32_bf16(a0, b1, hacc[0][1], 0, 0, 0);
      hacc[0][2] = __builtin_amdgcn_mfma_f32_16x16x32_bf16(a0, b2, hacc[0][2], 0, 0, 0);
      hacc[0][3] = __builtin_amdgcn_mfma_f32_16x16x32_bf16(a0, b3, hacc[0][3], 0, 0, 0);
      hacc[1][0] = __builtin_amdgcn_mfma_f32_16x16x32_bf16(a1, b0, hacc[1][0], 0, 0, 0);
      hacc[1][1] = __builtin_amdgcn_mfma_f32_16x16x32_bf16(a1, b1, hacc[1][1], 0, 0, 0);
      hacc[1][2] = __builtin_amdgcn_mfma_f32_16x16x32_bf16(a1, b2, hacc[1][2], 0, 0, 0);
      hacc[1][3] = __builtin_amdgcn_mfma_f32_16x16x32_bf16(a1, b3, hacc[1][3], 0, 0, 0);
    }
    __syncthreads();
#pragma unroll
    for (int fbi = 0; fbi < 2; ++fbi) {
      const int fb = (2*w + fbi)*16 + lq*4;
      const float4 bia = *(const float4*)&seb1[fc*128 + fb];
#pragma unroll
      for (int mb = 0; mb < 4; ++mb) {
        const int m = mb*16 + lr;
        const float h0 = fmaxf(hacc[fbi][mb][0] + bia.x, 0.f);
        const float h1 = fmaxf(hacc[fbi][mb][1] + bia.y, 0.f);
        const float h2 = fmaxf(hacc[fbi][mb][2] + bia.z, 0.f);
        const float h3 = fmaxf(hacc[fbi][mb][3] + bia.w, 0.f);
        uint2 p;
        p.x = f2bf(h0) | (f2bf(h1) << 16);
        p.y = f2bf(h2) | (f2bf(h3) << 16);
        const int bc = (fb*2) ^ ((m & 7) << 4);
        *(uint2*)((char*)Hs + m*256 + bc) = p;
      }
    }
    {
      const long wb = (long)(e*128) * 512 + fc*128;
#pragma unroll
      for (int s = 0; s < 8; ++s) {
        const int id = tid + s*256;
        const int orr = id >> 4, c16 = id & 15;
        const uint4 v = *(const uint4*)(w2b + wb + (long)orr*512 + c16*8);
        *(uint4*)((char*)Wts + orr*256 + ((c16*16) ^ ((orr & 7) << 4))) = v;
      }
    }
    __syncthreads();
#pragma unroll
    for (int ks = 0; ks < 4; ++ks) {
      const int bcol = ks*64 + lq*16;
      const bf16x8 a0 = ld_frag(Wts, (2*w  )*16 + lr, bcol);
      const bf16x8 a1 = ld_frag(Wts, (2*w+1)*16 + lr, bcol);
      const bf16x8 b0 = ld_frag(Hs,  0*16 + lr, bcol);
      const bf16x8 b1 = ld_frag(Hs,  1*16 + lr, bcol);
      const bf16x8 b2 = ld_frag(Hs,  2*16 + lr, bcol);
      const bf16x8 b3 = ld_frag(Hs,  3*16 + lr, bcol);
      yacc[0][0] = __builtin_amdgcn_mfma_f32_16x16x32_bf16(a0, b0, yacc[0][0], 0, 0, 0);
      yacc[0][1] = __builtin_amdgcn_mfma_f32_16x16x32_bf16(a0, b1, yacc[0][1], 0, 0, 0);
      yacc[0][2] = __builtin_amdgcn_mfma_f32_16x16x32_bf16(a0, b2, yacc[0][2], 0, 0, 0);
      yacc[0][3] = __builtin_amdgcn_mfma_f32_16x16x32_bf16(a0, b3, yacc[0][3], 0, 0, 0);
      yacc[1][0] = __builtin_amdgcn_mfma_f32_16x16x32_bf16(a1, b0, yacc[1][0], 0, 0, 0);
      yacc[1][1] = __builtin_amdgcn_mfma_f32_16x16x32_bf16(a1, b1, yacc[1][1], 0, 0, 0);
      yacc[1][2] = __builtin_amdgcn_mfma_f32_16x16x32_bf16(a1, b2, yacc[1][2], 0, 0, 0);
      yacc[1][3] = __builtin_amdgcn_mfma_f32_16x16x32_bf16(a1, b3, yacc[1][3], 0, 0, 0);
    }
  }
#pragma unroll
  for (int obi = 0; obi < 2; ++obi) {
    const int ob = (2*w + obi)*16 + lq*4;
    const float4 b2 = *(const float4*)&seb2[ob];
#pragma unroll
    for (int mb = 0; mb < 4; ++mb) {
      const int tl = mb*16 + lr;
      if (tl < nt) {
        const int pk = stok[tl];
        const int tk = pk & 0x3FFFFFFF;
        const float wgt = swgt[tl];
        float* Yp = ((pk >> 30) ? Y1 : Y0) + (long)tk*128 + ob;
        float4 o;
        o.x = (yacc[obi][mb][0] + b2.x) * wgt;
        o.y = (yacc[obi][mb][1] + b2.y) * wgt;
        o.z = (yacc[obi][mb][2] + b2.z) * wgt;
        o.w = (yacc[obi][mb][3] + b2.w) * wgt;
        *(float4*)Yp = o;
      }
    }
  }
}

// ---------------- fused sc GEMM + tanh + fixed-max softmax -----------------
__global__ __launch_bounds__(512)
void k_gemm2f(const unsigned short* __restrict__ mhb,
              const unsigned short* __restrict__ encb,
              const float* __restrict__ mask,
              float* __restrict__ out) {
  const int bid = blockIdx.x;
  const int b = bid & 31, rt = bid >> 5;
  __shared__ unsigned short Amh[64*128];
  __shared__ unsigned short Bch[512*32];
  __shared__ float red[64][9];
  const int tid = threadIdx.x;
  const int w = tid >> 6, l = tid & 63, lq = l >> 4, lr = l & 15;
  const long rowbase = (long)b*512 + rt*64;
#pragma unroll
  for (int s = 0; s < 2; ++s) {
    const int id = tid + s*512;
    const int r = id >> 4, c16 = id & 15;
    const uint4 v = *(const uint4*)(mhb + (rowbase + r)*128 + c16*8);
    *(uint4*)((char*)Amh + r*256 + ((c16*16) ^ ((r & 7) << 4))) = v;
  }
  f32x4 acc[4][4];
#pragma unroll
  for (int mi = 0; mi < 4; ++mi)
#pragma unroll
    for (int ni = 0; ni < 4; ++ni) acc[mi][ni] = (f32x4){0.f, 0.f, 0.f, 0.f};
  for (int kc = 0; kc < 4; ++kc) {
    __syncthreads();
#pragma unroll
    for (int s = 0; s < 4; ++s) {
      const int id = tid + s*512;
      const int n = id >> 2, sl = id & 3;
      const uint4 v = *(const uint4*)(encb + ((long)b*512 + n)*128 + kc*32 + sl*8);
      *(uint4*)((char*)Bch + n*64 + ((sl*16) ^ ((n & 3) << 4))) = v;
    }
    __syncthreads();
    bf16x8 af[4], bfr[4];
#pragma unroll
    for (int mi = 0; mi < 4; ++mi) {
      const int r = mi*16 + lr;
      af[mi] = *(const bf16x8*)((const char*)Amh + r*256 + ((kc*64 + lq*16) ^ ((r & 7) << 4)));
    }
#pragma unroll
    for (int ni = 0; ni < 4; ++ni) {
      const int n = w*64 + ni*16 + lr;
      bfr[ni] = *(const bf16x8*)((const char*)Bch + n*64 + ((lq*16) ^ ((n & 3) << 4)));
    }
#pragma unroll
    for (int mi = 0; mi < 4; ++mi)
#pragma unroll
      for (int ni = 0; ni < 4; ++ni)
        acc[mi][ni] = __builtin_amdgcn_mfma_f32_16x16x32_bf16(af[mi], bfr[ni], acc[mi][ni], 0, 0, 0);
  }
  const float ISC = 1.f/11.313708498984761f;
  float rsum[4][4];
#pragma unroll
  for (int mi = 0; mi < 4; ++mi)
#pragma unroll
    for (int j = 0; j < 4; ++j) rsum[mi][j] = 0.f;
#pragma unroll
  for (int mi = 0; mi < 4; ++mi) {
#pragma unroll
    for (int j = 0; j < 4; ++j) {
      const long row = rowbase + mi*16 + lq*4 + j;
      const float* mrow = mask + row*512 + w*64 + lr;
#pragma unroll
      for (int ni = 0; ni < 4; ++ni) {
        const float sc = acc[mi][ni][j] * ISC;
        const float li = 10.f*tanhf(sc) + mrow[ni*16];
        const float e = __expf(li - 10.f);
        acc[mi][ni][j] = e;
        rsum[mi][j] += e;
      }
    }
  }
#pragma unroll
  for (int mi = 0; mi < 4; ++mi)
#pragma unroll
    for (int j = 0; j < 4; ++j) {
#pragma unroll
      for (int o = 1; o < 16; o <<= 1) rsum[mi][j] += __shfl_xor(rsum[mi][j], o);
    }
  if (lr == 0) {
#pragma unroll
    for (int mi = 0; mi < 4; ++mi)
#pragma unroll
      for (int j = 0; j < 4; ++j) red[mi*16 + lq*4 + j][w] = rsum[mi][j];
  }
  __syncthreads();
  if (tid < 64) {
    float s = 0.f;
#pragma unroll
    for (int wv = 0; wv < 8; ++wv) s += red[tid][wv];
    red[tid][8] = 1.f / s;
  }
  __syncthreads();
#pragma unroll
  for (int mi = 0; mi < 4; ++mi) {
#pragma unroll
    for (int j = 0; j < 4; ++j) {
      const int rl = mi*16 + lq*4 + j;
      const float inv = red[rl][8];
      float* orow = out + (rowbase + rl)*512 + w*64 + lr;
#pragma unroll
      for (int ni = 0; ni < 4; ++ni) orow[ni*16] = acc[mi][ni][j] * inv;
    }
  }
}

// ---------------------------------------------------------------------------
extern "C" void kernel_launch(void* const* d_in, const int* in_sizes, int n_in,
                              void* d_out, int out_size, void* d_ws, size_t ws_size,
                              hipStream_t stream) {
  (void)in_sizes; (void)n_in; (void)out_size; (void)ws_size;
  const float* pref  = (const float*)d_in[0];
  const float* graph = (const float*)d_in[1];
  const float* cap   = (const float*)d_in[2];
  const float* enc   = (const float*)d_in[3];
  const float* mask  = (const float*)d_in[4];
  const float* fc1w  = (const float*)d_in[5];
  const float* fc1b  = (const float*)d_in[6];
  const float* fc2w  = (const float*)d_in[7];
  const float* fc2b  = (const float*)d_in[8];
  const float* fc3w  = (const float*)d_in[9];
  const float* fc3b  = (const float*)d_in[10];
  const float* hWq   = (const float*)d_in[11];
  const float* hWk   = (const float*)d_in[12];
  const float* hWv   = (const float*)d_in[13];
  const float* hWc   = (const float*)d_in[14];
  const float* gw    = (const float*)d_in[15];
  const float* gpw   = (const float*)d_in[16];
  const float* ew1   = (const float*)d_in[17];
  const float* eb1   = (const float*)d_in[18];
  const float* ew2   = (const float*)d_in[19];
  const float* eb2   = (const float*)d_in[20];
  float* ws  = (float*)d_ws;
  float* out = (float*)d_out;
  // d_out scratch: Kb/Vb bf16 [0,8MB) dead after attn; Y0 [0,8MB), Y1 [8,16MB);
  // ew1b [16,17MB), ew2b [17,18MB). k_gemm2f overwrites all of d_out.
  unsigned short* Kbuf = (unsigned short*)out;
  unsigned short* Vbuf = (unsigned short*)(out + 1048576);
  float* Y0 = out;
  float* Y1 = out + 2097152;
  unsigned short* ew1b = (unsigned short*)(out + 4194304);
  unsigned short* ew2b = (unsigned short*)(out + 4456448);
  unsigned short* mhb  = (unsigned short*)(ws + OFF_MH);
  unsigned short* encb = (unsigned short*)(ws + OFF_ENCB);
  unsigned short* wkb  = (unsigned short*)(ws + OFF_WKB);
  unsigned short* wvb  = (unsigned short*)(ws + OFF_WVB);
  unsigned short* wcb  = (unsigned short*)(ws + OFF_WCB);

  k_prep1<<<5121, 256, 0, stream>>>(pref, fc1w, fc1b, fc2w, fc2b, fc3w, fc3b,
                                    gpw, hWq, mask, ew1, ew2, enc,
                                    ew1b, ew2b, encb, ws);
  k_prep2<<<208, 256, 0, stream>>>(graph, hWq, hWk, hWv, hWc, ws);
  k_kv<<<dim3(256, 2), 256, 0, stream>>>(encb, wkb, wvb, Kbuf, Vbuf);
  k_attn<<<1024, 512, 0, stream>>>(Kbuf, Vbuf, ws, cap, mask, ws + OFF_AO);
  k_gate<<<64, 256, 0, stream>>>(ws + OFF_AO, gw, ws);
  k_moe<<<dim3(256, 8), 256, 0, stream>>>(ws + OFF_AO, ew1b, ew2b, eb1, eb2, ws, Y0, Y1);
  k_mh<<<256, 256, 0, stream>>>(Y0, Y1, wcb, mhb);
  k_gemm2f<<<256, 512, 0, stream>>>(mhb, encb, mask, out);
}